// Round 9
// baseline (37017.377 us; speedup 1.0000x reference)
//
#include <hip/hip_runtime.h>
#include <hip/hip_fp16.h>

typedef _Float16 f16;
typedef f16 f16x4 __attribute__((ext_vector_type(4)));
typedef f16 f16x8 __attribute__((ext_vector_type(8)));
typedef float f32x4 __attribute__((ext_vector_type(4)));
typedef unsigned uint2v __attribute__((ext_vector_type(2)));

#define DEVI static __device__ __forceinline__

DEVI void gload_lds16(const void* g, void* l) {
  __builtin_amdgcn_global_load_lds(
      (const __attribute__((address_space(1))) unsigned int*)g,
      (__attribute__((address_space(3))) unsigned int*)l, 16, 0, 0);
}

DEVI float wave_red_sum64(float v) {
#pragma unroll
  for (int m = 1; m < 64; m <<= 1) v += __shfl_xor(v, m, 64);
  return v;
}
DEVI float wave_red_max64(float v) {
#pragma unroll
  for (int m = 1; m < 64; m <<= 1) v = fmaxf(v, __shfl_xor(v, m, 64));
  return v;
}

// ---- cross-lane adds: DPP for xor1..8, permlane-swap for xor16/32 (r6-proven) ----
template <int CTRL>
DEVI float dpp_addf(float v) {
  int s = __builtin_amdgcn_update_dpp(0, __float_as_int(v), CTRL, 0xF, 0xF, true);
  return v + __int_as_float(s);
}
DEVI float xor16_add(float v) {
#if __has_builtin(__builtin_amdgcn_permlane16_swap)
  uint2v r = __builtin_amdgcn_permlane16_swap(__float_as_uint(v), __float_as_uint(v), false, false);
  return __uint_as_float(r.x) + __uint_as_float(r.y);
#else
  int s = __builtin_amdgcn_ds_swizzle(__float_as_int(v), 0x401F);
  return v + __int_as_float(s);
#endif
}
DEVI float xor32_add(float v) {
#if __has_builtin(__builtin_amdgcn_permlane32_swap)
  uint2v r = __builtin_amdgcn_permlane32_swap(__float_as_uint(v), __float_as_uint(v), false, false);
  return __uint_as_float(r.x) + __uint_as_float(r.y);
#else
  int s = __builtin_amdgcn_ds_bpermute(((threadIdx.x & 63) ^ 32) << 2, __float_as_int(v));
  return v + __int_as_float(s);
#endif
}
DEVI float allred64(float v) {
  v = dpp_addf<0xB1>(v);   // xor1
  v = dpp_addf<0x4E>(v);   // xor2
  v = dpp_addf<0x141>(v);  // xor4 (row_half_mirror, uniform bits0-1)
  v = dpp_addf<0x140>(v);  // xor8 (row_mirror, uniform bits0-2)
  v = xor16_add(v);
  return xor32_add(v);
}

// ------------------------------ fused f32 -> f16 cast of all 7 weights -------
__global__ void cvt_all_kernel(const float* __restrict__ s0, const float* __restrict__ s1,
                               const float* __restrict__ s2, const float* __restrict__ s3,
                               const float* __restrict__ s4, const float* __restrict__ s5,
                               const float* __restrict__ s6, f16* __restrict__ d) {
  const int blk = blockIdx.x;
  const float* s; long dofs; int local;
  if (blk < 256)       { s = s0; dofs = 0;       local = blk; }
  else if (blk < 512)  { s = s1; dofs = 262144;  local = blk - 256; }
  else if (blk < 768)  { s = s2; dofs = 524288;  local = blk - 512; }
  else if (blk < 1024) { s = s3; dofs = 786432;  local = blk - 768; }
  else if (blk < 1280) { s = s4; dofs = 1048576; local = blk - 1024; }
  else if (blk < 2304) { s = s5; dofs = 1310720; local = blk - 1280; }
  else                 { s = s6; dofs = 2359296; local = blk - 2304; }
  const long i = (long)local * 1024 + threadIdx.x * 4;
  float4 v = *(const float4*)(s + i);
  f16x4 o = {(f16)v.x, (f16)v.y, (f16)v.z, (f16)v.w};
  *(f16x4*)(d + dofs + i) = o;
}

// ------------------------------ LayerNorm D=512 ------------------------------
__global__ void ln_kernel(const float* __restrict__ in, const float* __restrict__ add,
                          const float* __restrict__ g, const float* __restrict__ b,
                          float* __restrict__ sumout, float* __restrict__ lnf,
                          f16* __restrict__ lnh) {
  const int row = blockIdx.x * 4 + (threadIdx.x >> 6);
  const int lane = threadIdx.x & 63;
  const long base = (long)row * 512;
  const int c0 = lane * 4, c1 = 256 + lane * 4;
  float4 a0 = *(const float4*)(in + base + c0);
  float4 a1 = *(const float4*)(in + base + c1);
  if (add) {
    float4 d0 = *(const float4*)(add + base + c0);
    float4 d1 = *(const float4*)(add + base + c1);
    a0.x += d0.x; a0.y += d0.y; a0.z += d0.z; a0.w += d0.w;
    a1.x += d1.x; a1.y += d1.y; a1.z += d1.z; a1.w += d1.w;
  }
  if (sumout) {
    *(float4*)(sumout + base + c0) = a0;
    *(float4*)(sumout + base + c1) = a1;
  }
  float v[8] = {a0.x, a0.y, a0.z, a0.w, a1.x, a1.y, a1.z, a1.w};
  float s = 0.f;
#pragma unroll
  for (int k = 0; k < 8; k++) s += v[k];
  s = wave_red_sum64(s);
  const float mean = s * (1.f / 512.f);
  float vs = 0.f;
#pragma unroll
  for (int k = 0; k < 8; k++) { float d = v[k] - mean; vs += d * d; }
  vs = wave_red_sum64(vs);
  const float rstd = rsqrtf(vs * (1.f / 512.f) + 1e-5f);
  float4 g0 = *(const float4*)(g + c0), g1 = *(const float4*)(g + c1);
  float4 p0 = *(const float4*)(b + c0), p1 = *(const float4*)(b + c1);
  const float gg[8] = {g0.x, g0.y, g0.z, g0.w, g1.x, g1.y, g1.z, g1.w};
  const float bv[8] = {p0.x, p0.y, p0.z, p0.w, p1.x, p1.y, p1.z, p1.w};
  float y[8];
#pragma unroll
  for (int k = 0; k < 8; k++) y[k] = (v[k] - mean) * rstd * gg[k] + bv[k];
  if (lnf) {
    float4 o0 = {y[0], y[1], y[2], y[3]}, o1 = {y[4], y[5], y[6], y[7]};
    *(float4*)(lnf + base + c0) = o0;
    *(float4*)(lnf + base + c1) = o1;
  }
  if (lnh) {
    f16x4 o0 = {(f16)y[0], (f16)y[1], (f16)y[2], (f16)y[3]};
    f16x4 o1 = {(f16)y[4], (f16)y[5], (f16)y[6], (f16)y[7]};
    *(f16x4*)(lnh + base + c0) = o0;
    *(f16x4*)(lnh + base + c1) = o1;
  }
}

// ------------------------------ generic fp16 MFMA GEMM, C = A(MxK) * W(NxK)^T
enum { EPI_QKV = 0, EPI_SCORES = 2, EPI_PV = 3, EPI_WO = 4, EPI_GELU = 5, EPI_OUT = 6 };

template <int EPI>
__launch_bounds__(256, 1) __global__
void gemm_bt(const f16* __restrict__ A, const f16* __restrict__ W, int lda, int ldw,
             long Az, long Wz, void* __restrict__ dst, const float* __restrict__ bias,
             const float* __restrict__ resid, int K, float scale, int zofs, int hcp) {
  if (EPI == EPI_SCORES && blockIdx.x > blockIdx.y) return;  // causal tile skip
  __shared__ f16 lA[128 * 64];
  __shared__ f16 lB[128 * 64];
  const int tid = threadIdx.x;
  const int wave = tid >> 6, lane = tid & 63;
  const int z = blockIdx.z;
  const f16* Ab;
  const f16* Wb;
  if (EPI == EPI_SCORES) {
    const int v_ = (z >= hcp) ? 1 : 0, head = z - v_ * hcp;
    Ab = A + (long)head * 32768 + (long)blockIdx.y * 128 * lda;
    Wb = W + (long)v_ * 524288 + (long)head * 32768 + (long)blockIdx.x * 128 * ldw;
  } else {
    Ab = A + (long)z * Az + (long)blockIdx.y * 128 * lda;
    Wb = W + (long)z * Wz + (long)blockIdx.x * 128 * ldw;
  }

  f32x4 acc[4][4];
#pragma unroll
  for (int a = 0; a < 4; a++)
#pragma unroll
    for (int q = 0; q < 4; q++) acc[a][q] = (f32x4){0.f, 0.f, 0.f, 0.f};

  int srow[4], scol[4];
#pragma unroll
  for (int i = 0; i < 4; i++) {
    int c = i * 256 + tid;
    int row = c >> 3;
    int colb = (c & 7) << 4;
    srow[i] = row;
    scol[i] = (colb ^ ((row & 7) << 4)) >> 1;
  }

  for (int k0 = 0; k0 < K; k0 += 64) {
    __syncthreads();
#pragma unroll
    for (int i = 0; i < 4; i++) {
      const int le = (i * 256 + wave * 64) * 8;
      gload_lds16(Ab + (long)srow[i] * lda + k0 + scol[i], lA + le);
      gload_lds16(Wb + (long)srow[i] * ldw + k0 + scol[i], lB + le);
    }
    __syncthreads();
    const int wm = (wave >> 1) * 64, wn = (wave & 1) * 64;
#pragma unroll
    for (int km = 0; km < 2; km++) {
      const int kb = km * 64 + ((lane >> 4) << 4);
      f16x8 af[4], bfv[4];
#pragma unroll
      for (int mf = 0; mf < 4; mf++) {
        int r = wm + mf * 16 + (lane & 15);
        af[mf] = *(const f16x8*)((const char*)lA + r * 128 + (kb ^ ((r & 7) << 4)));
      }
#pragma unroll
      for (int nf = 0; nf < 4; nf++) {
        int r = wn + nf * 16 + (lane & 15);
        bfv[nf] = *(const f16x8*)((const char*)lB + r * 128 + (kb ^ ((r & 7) << 4)));
      }
#pragma unroll
      for (int mf = 0; mf < 4; mf++)
#pragma unroll
        for (int nf = 0; nf < 4; nf++)
          acc[mf][nf] = __builtin_amdgcn_mfma_f32_16x16x32_f16(af[mf], bfv[nf], acc[mf][nf], 0, 0, 0);
    }
  }

  const int wm = (wave >> 1) * 64, wn = (wave & 1) * 64;
  const int rbase = blockIdx.y * 128 + wm + ((lane >> 4) << 2);
  const int cbase = blockIdx.x * 128 + wn + (lane & 15);
#pragma unroll
  for (int mf = 0; mf < 4; mf++)
#pragma unroll
    for (int nf = 0; nf < 4; nf++)
#pragma unroll
      for (int j = 0; j < 4; j++) {
        const int m = rbase + mf * 16 + j;
        const int n = cbase + nf * 16;
        const float v = acc[mf][nf][j];
        if (EPI == EPI_QKV) {
          // z<3: q/k1/k2 heads layout [B,H,T,64]; z==3: v transposed [B,H,64,T]
          f16* d = (f16*)dst + (long)z * 524288;
          if (z < 3)
            d[(long)((m >> 9) * 8 + (n >> 6)) * 32768 + (m & 511) * 64 + (n & 63)] = (f16)v;
          else
            d[(long)((m >> 9) * 8 + (n >> 6)) * 32768 + (n & 63) * 512 + (m & 511)] = (f16)v;
        } else if (EPI == EPI_SCORES) {
          ((float*)dst)[(long)z * 262144 + (long)m * 512 + n] = v * scale;
        } else if (EPI == EPI_PV) {
          if (n < 64) {
            const int hh = z + zofs;
            ((f16*)dst)[(long)((hh >> 3) * 512 + m) * 512 + (hh & 7) * 64 + n] = (f16)v;
          }
        } else if (EPI == EPI_WO) {
          ((float*)dst)[(long)m * 512 + n] = v + resid[(long)m * 512 + n];
        } else if (EPI == EPI_GELU) {
          const float u = v + bias[n];
          ((f16*)dst)[(long)m * 2048 + n] = (f16)(0.5f * u * (1.f + erff(u * 0.70710678118f)));
        } else {
          ((float*)dst)[(long)m * 512 + n] = v + bias[n] + resid[(long)m * 512 + n];
        }
      }
}

// ------------------------------ softmax-diff-L1, one wave per row ------------
__global__ void softmax_diff_kernel(const float* __restrict__ S1, const float* __restrict__ S2,
                                    const float* __restrict__ lamlog, f16* __restrict__ attn,
                                    int zofs) {
  const int rid = blockIdx.x * 4 + (threadIdx.x >> 6);
  const int lane = threadIdx.x & 63;
  const int z = rid >> 9, i = rid & 511;
  const float lam = 1.f / (1.f + __expf(-lamlog[(z + zofs) & 7]));
  const long base = (long)z * 262144 + (long)i * 512;
  const int c0 = lane * 4, c1 = 256 + lane * 4;
  float4 xa = *(const float4*)(S1 + base + c0);
  float4 xb = *(const float4*)(S1 + base + c1);
  float4 ya = *(const float4*)(S2 + base + c0);
  float4 yb = *(const float4*)(S2 + base + c1);
  float s1v[8] = {xa.x, xa.y, xa.z, xa.w, xb.x, xb.y, xb.z, xb.w};
  float s2v[8] = {ya.x, ya.y, ya.z, ya.w, yb.x, yb.y, yb.z, yb.w};
  int cols[8];
#pragma unroll
  for (int k = 0; k < 8; k++) cols[k] = (k < 4) ? (c0 + k) : (c1 + k - 4);
  float m1 = -3.0e38f, m2 = -3.0e38f;
#pragma unroll
  for (int k = 0; k < 8; k++)
    if (cols[k] <= i) { m1 = fmaxf(m1, s1v[k]); m2 = fmaxf(m2, s2v[k]); }
  m1 = wave_red_max64(m1);
  m2 = wave_red_max64(m2);
  float z1 = 0.f, z2 = 0.f, e1[8], e2[8];
#pragma unroll
  for (int k = 0; k < 8; k++) {
    const bool valid = cols[k] <= i;
    e1[k] = valid ? __expf(s1v[k] - m1) : 0.f;
    e2[k] = valid ? __expf(s2v[k] - m2) : 0.f;
    z1 += e1[k]; z2 += e2[k];
  }
  z1 = wave_red_sum64(z1);
  z2 = wave_red_sum64(z2);
  const float r1 = 1.f / z1, r2 = lam / z2;
  float p[8], l1 = 0.f;
#pragma unroll
  for (int k = 0; k < 8; k++) { p[k] = e1[k] * r1 - e2[k] * r2; l1 += fabsf(p[k]); }
  l1 = wave_red_sum64(l1);
  const float rn = 1.f / fmaxf(l1, 1e-6f);
  f16x4 o0 = {(f16)(p[0] * rn), (f16)(p[1] * rn), (f16)(p[2] * rn), (f16)(p[3] * rn)};
  f16x4 o1 = {(f16)(p[4] * rn), (f16)(p[5] * rn), (f16)(p[6] * rn), (f16)(p[7] * rn)};
  *(f16x4*)(attn + base + c0) = o0;
  *(f16x4*)(attn + base + c1) = o1;
}

// ---- inline-asm load + counted-wait primitives (vmcnt counts LOADS AND STORES) ----
#define ALD4(dst, p) asm volatile("global_load_dwordx4 %0, %1, off" : "=&v"(dst) : "v"(p) : "memory")
#define ALD4O(dst, p, OFS) asm volatile("global_load_dwordx4 %0, %1, off offset:" OFS : "=&v"(dst) : "v"(p) : "memory")
#define ALD1(dst, p) asm volatile("global_load_dword %0, %1, off" : "=&v"(dst) : "v"(p) : "memory")
#define ALD1O(dst, p, OFS) asm volatile("global_load_dword %0, %1, off offset:" OFS : "=&v"(dst) : "v"(p) : "memory")
#define VMWAIT(N)                                                             \
  {                                                                           \
    asm volatile("s_waitcnt vmcnt(" #N ")" ::: "memory");                     \
    __builtin_amdgcn_sched_barrier(0);                                        \
  }

// ------------------------------ eta precompute, 3 stages ---------------------
#define EISSUE(X)                                                             \
  {                                                                           \
    ALD1(X[0], pe);        ALD1(X[1], pe + 512);                              \
    ALD1(X[2], pe + 1024); ALD1(X[3], pe + 1536);                             \
    ALD1(X[4], pe + 2048); ALD1(X[5], pe + 2560);                             \
    ALD1(X[6], pe + 3072); ALD1(X[7], pe + 3584);                             \
    pe += 4096;                                                               \
  }
#define ESTEP(V, T)                                                           \
  {                                                                           \
    dp[(long)(T) * 512] = fabsf((V) - ema);                                   \
    ema = fmaf(0.95f, ema, 0.05f * (V));                                      \
  }

__launch_bounds__(64, 1) __global__
void eta_diff_kernel(const float* __restrict__ x2, float* __restrict__ diff) {
  const int blk = blockIdx.x;  // 16: b = blk>>3, col group = blk&7
  const int b = blk >> 3;
  const int col = (blk & 7) * 64 + threadIdx.x;
  const float* pe = x2 + (long)b * 262144 + col;
  float* dp = diff + (long)b * 262144 + col;
  float ema = 0.f;
  float EA[8], EB[8];
  EISSUE(EA);
  EISSUE(EB);
  VMWAIT(8);
#pragma unroll 1
  for (int t = 0; t < 512; t += 16) {
    ESTEP(EA[0], t + 0); ESTEP(EA[1], t + 1); ESTEP(EA[2], t + 2); ESTEP(EA[3], t + 3);
    ESTEP(EA[4], t + 4); ESTEP(EA[5], t + 5); ESTEP(EA[6], t + 6); ESTEP(EA[7], t + 7);
    EISSUE(EA);
    VMWAIT(16);
    ESTEP(EB[0], t + 8);  ESTEP(EB[1], t + 9);  ESTEP(EB[2], t + 10); ESTEP(EB[3], t + 11);
    ESTEP(EB[4], t + 12); ESTEP(EB[5], t + 13); ESTEP(EB[6], t + 14); ESTEP(EB[7], t + 15);
    EISSUE(EB);
    VMWAIT(16);
  }
  asm volatile("s_waitcnt vmcnt(0)" ::: "memory");
}

__global__ void eta_nov_kernel(const float* __restrict__ diff, float* __restrict__ nov) {
  const int row = blockIdx.x * 4 + (threadIdx.x >> 6);  // row = b*512+t
  const int lane = threadIdx.x & 63;
  const float* dp = diff + (long)row * 512 + lane * 4;
  float4 a0 = *(const float4*)dp;
  float4 a1 = *(const float4*)(dp + 256);
  float s = ((a0.x + a0.y) + (a0.z + a0.w)) + ((a1.x + a1.y) + (a1.z + a1.w));
  s = wave_red_sum64(s);
  if (lane == 0) nov[row] = s * (1.f / 512.f);
}

__global__ void eta_scan_kernel(const float* __restrict__ nov, const float* __restrict__ loglr,
                                float* __restrict__ eta) {
  if (threadIdx.x != 0) return;
  const int b = blockIdx.x;
  float ilr = expf(loglr[0]);
  ilr = fminf(fmaxf(ilr, 1e-5f), 1.f);
  float lrm = 1.f;
  const float* pb = nov + (long)b * 512;
#pragma unroll 8
  for (int t = 0; t < 512; t++) {
    const float ls = fminf(fmaxf(fmaf(3.f, pb[t], 1.f), 0.5f), 3.f);
    lrm = fmaf(0.95f, lrm, 0.05f * ls);
    eta[b * 512 + t] = ilr * lrm;
  }
}

// ------------------------------ G1[t] = x_{t-1} . x_t precompute -------------
__global__ void g1_kernel(const float* __restrict__ x2, float* __restrict__ g1) {
  const int row = blockIdx.x * 4 + (threadIdx.x >> 6);  // row = b*512+t
  const int lane = threadIdx.x & 63;
  const int t = row & 511;
  if (t == 0) { if (lane == 0) g1[row] = 0.f; return; }
  const float* pa = x2 + (long)row * 512 + lane * 4;
  const float* pb = pa - 512;
  float4 a0 = *(const float4*)pa, a1 = *(const float4*)(pa + 256);
  float4 b0 = *(const float4*)pb, b1 = *(const float4*)(pb + 256);
  float s = ((a0.x * b0.x + a0.y * b0.y) + (a0.z * b0.z + a0.w * b0.w)) +
            ((a1.x * b1.x + a1.y * b1.y) + (a1.z * b1.z + a1.w * b1.w));
  s = wave_red_sum64(s);
  if (lane == 0) g1[row] = s;
}

// ------------------------------ TTT fast path (1-step lookahead, EXACT) ------
// y_t = fw_{t-1}.x_t + b  =  v_t.x_t - 0.1*eta_{t-1}*G1[t]*err_{t-1} + b where
//   v_t = fw_{t-2} - 0.9*eta_{t-1}*mom_{t-2}  (built at step t-1, AFTER the dot
//   consumed v_{t-1}: single v buffer),  G1[t] = x_{t-1}.x_t (precomputed).
// Verified vs reference by scalar trace with VARYING eta (r8 post-mortem).
// Serial chain: err_{t-1} -> y_t -> err_t (~3 VALU); dot+reduce has 1-step slack.
// r8's failure attributed to allocator copies of in-flight asm dests under the
// transient pressure of 14 per-load address temps -> this version uses
// immediate-offset loads from 6 stable bases (zero temps) + single v buffer.
// vmcnt ledger (loads AND stores count): group = 14 loads; 4 scattered ys
// stores per phase. Prologue 3 params+14+14 -> VMWAIT(14). Loop: phase A ends
// [B14][4st][A'14] -> VMWAIT(18) drains B; phase B ends [4st][A'14][4st][B'14]
// -> VMWAIT(18) drains old stores + A'.
DEVI float dot8(const f32x4 F0, const f32x4 F1, const f32x4 X0, const f32x4 X1) {
  float a0 = F0.x * X0.x, a1 = F0.y * X0.y, a2 = F0.z * X0.z, a3 = F0.w * X0.w;
  a0 = fmaf(F1.x, X1.x, a0); a1 = fmaf(F1.y, X1.y, a1);
  a2 = fmaf(F1.z, X1.z, a2); a3 = fmaf(F1.w, X1.w, a3);
  return (a0 + a1) + (a2 + a3);
}
DEVI void upd8(f32x4& M0, f32x4& M1, f32x4& F0, f32x4& F1, float c1, float e,
               const f32x4 X0, const f32x4 X1, float& ns) {
  M0.x = fmaf(0.9f, M0.x, c1 * X0.x); F0.x = fmaf(-e, M0.x, F0.x); ns = fmaf(F0.x, F0.x, ns);
  M0.y = fmaf(0.9f, M0.y, c1 * X0.y); F0.y = fmaf(-e, M0.y, F0.y); ns = fmaf(F0.y, F0.y, ns);
  M0.z = fmaf(0.9f, M0.z, c1 * X0.z); F0.z = fmaf(-e, M0.z, F0.z); ns = fmaf(F0.z, F0.z, ns);
  M0.w = fmaf(0.9f, M0.w, c1 * X0.w); F0.w = fmaf(-e, M0.w, F0.w); ns = fmaf(F0.w, F0.w, ns);
  M1.x = fmaf(0.9f, M1.x, c1 * X1.x); F1.x = fmaf(-e, M1.x, F1.x); ns = fmaf(F1.x, F1.x, ns);
  M1.y = fmaf(0.9f, M1.y, c1 * X1.y); F1.y = fmaf(-e, M1.y, F1.y); ns = fmaf(F1.y, F1.y, ns);
  M1.z = fmaf(0.9f, M1.z, c1 * X1.z); F1.z = fmaf(-e, M1.z, F1.z); ns = fmaf(F1.z, F1.z, ns);
  M1.w = fmaf(0.9f, M1.w, c1 * X1.w); F1.w = fmaf(-e, M1.w, F1.w); ns = fmaf(F1.w, F1.w, ns);
}
DEVI void vbuild(f32x4& V0, f32x4& V1, const f32x4 F0, const f32x4 F1,
                 const f32x4 M0, const f32x4 M1, float c09) {
  V0.x = fmaf(-c09, M0.x, F0.x); V0.y = fmaf(-c09, M0.y, F0.y);
  V0.z = fmaf(-c09, M0.z, F0.z); V0.w = fmaf(-c09, M0.w, F0.w);
  V1.x = fmaf(-c09, M1.x, F1.x); V1.y = fmaf(-c09, M1.y, F1.y);
  V1.z = fmaf(-c09, M1.z, F1.z); V1.w = fmaf(-c09, M1.w, F1.w);
}

// 14 loads, all immediate-offset off stable bases (no address temps).
#define TISSUE(X, R, E, G)                                                    \
  {                                                                           \
    ALD4(X[0], pX0);                                                          \
    ALD4O(X[1], pX0, "16");                                                   \
    ALD4O(X[2], pX0, "2048");                                                 \
    ALD4O(X[3], pX0, "2064");                                                 \
    ALD4(X[4], pX2);                                                          \
    ALD4O(X[5], pX2, "16");                                                   \
    ALD4O(X[6], pX2, "2048");                                                 \
    ALD4O(X[7], pX2, "2064");                                                 \
    ALD1(R[0], pr0);                                                          \
    ALD1O(R[1], pr0, "2048");                                                 \
    ALD1(R[2], pr2);                                                          \
    ALD1O(R[3], pr2, "2048");                                                 \
    ALD4(E, per);                                                             \
    ALD4(G, pg);                                                              \
    pX0 += 2048; pX2 += 2048; pr0 += 2048; pr2 += 2048; per += 4; pg += 4;    \
  }

#define TSTEP(X0v, X1v, xrv, ev, gv, T)                                       \
  {                                                                           \
    const float e_ = (ev);                                                    \
    const float p_ = allred64(dot8(v0, v1, X0v, X1v));  /* v_t */             \
    vbuild(v0, v1, fw0, fw1, m0, m1, 0.9f * e_);        /* -> v_{t+1} */      \
    const float q_ = 0.1f * etaPrev * (gv);                                   \
    const float y_ = (p_ + biasr) - q_ * errPrev;                             \
    if (lane == 0) pys[(long)(T) * 512] = y_;                                 \
    const float err_ = (y_ - (xrv)) * (1.f / 512.f);                          \
    float ns_ = 0.f;                                                          \
    upd8(m0, m1, fw0, fw1, 0.1f * err_, e_, X0v, X1v, ns_);                   \
    nsmax = fmaxf(nsmax, ns_);                                                \
    errPrev = err_;                                                           \
    etaPrev = e_;                                                             \
  }

__launch_bounds__(64, 1) __global__
void ttt_fast_kernel(const float* __restrict__ x2, const float* __restrict__ base_w,
                     const float* __restrict__ tbias, const float* __restrict__ eta,
                     const float* __restrict__ g1, float* __restrict__ ys,
                     float* __restrict__ npB) {
  const int blk = blockIdx.x;   // 1024
  const int b = blk >> 9;
  const int row = blk & 511;
  const int lane = threadIdx.x;
  const float* xb = x2 + (long)b * 262144;

  f32x4 fw0, fw1;
  float biasr;
  {
    const float* pw = base_w + (long)row * 512 + lane * 8;
    ALD4(fw0, pw);
    ALD4O(fw1, pw, "16");
    ALD1(biasr, tbias + row);
  }

  f32x4 m0 = {0.f, 0.f, 0.f, 0.f}, m1 = m0;
  f32x4 v0, v1;
  float errPrev = 0.f, etaPrev = 0.f, nsmax = 0.f;

  const float* pX0 = xb + lane * 8;        // rows T,T+1 via offsets
  const float* pX2 = pX0 + 1024;           // rows T+2,T+3
  const float* pr0 = xb + row;             // xr rows T,T+1
  const float* pr2 = pr0 + 1024;           // xr rows T+2,T+3
  const float* per = eta + b * 512;
  const float* pg  = g1 + b * 512;
  float* pys = ys + (long)b * 262144 + row;

  f32x4 XA[8], XB[8], EA, EB, GA, GB;
  float RA[4], RB[4];
  TISSUE(XA, RA, EA, GA);
  TISSUE(XB, RB, EB, GB);
  VMWAIT(14);  // drains 3 param loads + group A's 14
  v0 = fw0; v1 = fw1;  // v_0 = base weights (mom_{-2}=0)

#pragma unroll 1
  for (int T = 0; T < 512; T += 8) {
    TSTEP(XA[0], XA[1], RA[0], EA.x, GA.x, T + 0);
    TSTEP(XA[2], XA[3], RA[1], EA.y, GA.y, T + 1);
    TSTEP(XA[4], XA[5], RA[2], EA.z, GA.z, T + 2);
    TSTEP(XA[6], XA[7], RA[3], EA.w, GA.w, T + 3);
    TISSUE(XA, RA, EA, GA);
    VMWAIT(18);  // drain group B; leave [4st][A'14]
    TSTEP(XB[0], XB[1], RB[0], EB.x, GB.x, T + 4);
    TSTEP(XB[2], XB[3], RB[1], EB.y, GB.y, T + 5);
    TSTEP(XB[4], XB[5], RB[2], EB.z, GB.z, T + 6);
    TSTEP(XB[6], XB[7], RB[3], EB.w, GB.w, T + 7);
    TISSUE(XB, RB, EB, GB);
    VMWAIT(18);  // drain old stores + A'; leave [4st][B'14]
  }
  asm volatile("s_waitcnt vmcnt(0)" ::: "memory");
  const float tot = allred64(nsmax);
  if (lane == 0) npB[blk] = tot;
}

// ------------------------------ verify: conservative norm check --------------
__global__ void verify_kernel(const float* __restrict__ npB, int* __restrict__ flag) {
  const int tid = threadIdx.x;  // 1024, one per ttt block (row)
  const int wave = tid >> 6, lane = tid & 63;
  float s = wave_red_sum64(npB[tid]);
  __shared__ float part[16];
  if (lane == 0) part[wave] = s;
  __syncthreads();
  if (tid == 0) {
    float s0 = 0.f, s1 = 0.f;
#pragma unroll
    for (int w = 0; w < 8; w++) { s0 += part[w]; s1 += part[8 + w]; }
    if (s0 > 1000.f || s1 > 1000.f) atomicOr(flag, 1);  // margin under 32^2=1024
  }
}

// ------------------------------ TTT fallback (exact, with clip) --------------
__launch_bounds__(1024, 1) __global__
void ttt_fallback_kernel(const int* __restrict__ flag, const float* __restrict__ x2,
                         const float* __restrict__ base_w, const float* __restrict__ tbias,
                         const float* __restrict__ eta, float* __restrict__ ys,
                         float* __restrict__ fwg, float* __restrict__ momg) {
  if (flag[0] == 0) return;
  const int b = blockIdx.x;
  const int tid = threadIdx.x;
  const int wave = tid >> 6, lane = tid & 63;
  float* fw = fwg + (long)b * 262144;
  float* mm = momg + (long)b * 262144;
  for (int e = tid; e < 262144; e += 1024) { fw[e] = base_w[e]; mm[e] = 0.f; }
  __shared__ float xs[512], errs[512], red[16];
  const float* xb = x2 + (long)b * 262144;
  for (int t = 0; t < 512; t++) {
    __syncthreads();
    if (tid < 512) xs[tid] = xb[t * 512 + tid];
    __syncthreads();
    if (tid < 512) {
      float acc = 0.f;
      for (int c = 0; c < 512; c++) acc = fmaf(fw[(long)tid * 512 + c], xs[c], acc);
      const float y = acc + tbias[tid];
      ys[((long)b * 512 + t) * 512 + tid] = y;
      errs[tid] = (y - xs[tid]) * (1.f / 512.f);
    }
    __syncthreads();
    const float eta_t = eta[b * 512 + t];
    float nsq = 0.f;
    for (int e = tid; e < 262144; e += 1024) {
      const int r = e >> 9, c = e & 511;
      const float m2 = fmaf(0.9f, mm[e], 0.1f * errs[r] * xs[c]);
      mm[e] = m2;
      const float f2 = fmaf(-eta_t, m2, fw[e]);
      fw[e] = f2;
      nsq = fmaf(f2, f2, nsq);
    }
    nsq = wave_red_sum64(nsq);
    if (lane == 0) red[wave] = nsq;
    __syncthreads();
    if (tid == 0) {
      float s = 0.f;
      for (int w = 0; w < 16; w++) s += red[w];
      red[0] = s;
    }
    __syncthreads();
    const float norm = fmaxf(sqrtf(red[0]), 1e-6f);
    const float sc = fminf(32.f / norm, 1.f);
    if (sc < 1.f)
      for (int e = tid; e < 262144; e += 1024) fw[e] *= sc;
  }
}

// ------------------------------ host launch ------------------------------
extern "C" void kernel_launch(void* const* d_in, const int* in_sizes, int n_in,
                              void* d_out, int out_size, void* d_ws, size_t ws_size,
                              hipStream_t stream) {
  (void)in_sizes; (void)n_in; (void)out_size;
  const float* x      = (const float*)d_in[0];
  const float* Wq     = (const float*)d_in[1];
  const float* Wk1    = (const float*)d_in[2];
  const float* Wk2    = (const float*)d_in[3];
  const float* Wv     = (const float*)d_in[4];
  const float* Wo     = (const float*)d_in[5];
  const float* lamlog = (const float*)d_in[6];
  const float* ln1g   = (const float*)d_in[7];
  const float* ln1b   = (const float*)d_in[8];
  const float* basew  = (const float*)d_in[9];
  const float* tttb   = (const float*)d_in[10];
  const float* loglr  = (const float*)d_in[11];
  const float* ln2g   = (const float*)d_in[12];
  const float* ln2b   = (const float*)d_in[13];
  const float* W1     = (const float*)d_in[14];
  const float* b1     = (const float*)d_in[15];
  const float* W2     = (const float*)d_in[16];
  const float* b2     = (const float*)d_in[17];
  const float* ln3g   = (const float*)d_in[18];
  const float* ln3b   = (const float*)d_in[19];
  float* out = (float*)d_out;

  char* ws = (char*)d_ws;
  size_t off = 0;
  auto alloc = [&](size_t bytes) {
    size_t o = off;
    off += (bytes + 255) & ~(size_t)255;
    return o;
  };
  f16* WqH   = (f16*)(ws + alloc(262144 * 2));
  f16* Wk1H  = (f16*)(ws + alloc(262144 * 2));
  f16* Wk2H  = (f16*)(ws + alloc(262144 * 2));
  f16* WvH   = (f16*)(ws + alloc(262144 * 2));
  f16* WoH   = (f16*)(ws + alloc(262144 * 2));
  f16* W1H   = (f16*)(ws + alloc(1048576 * 2));
  f16* W2H   = (f16*)(ws + alloc(1048576 * 2));
  (void)Wk1H; (void)Wk2H; (void)WvH; (void)W1H;
  f16* xlnH  = (f16*)(ws + alloc(524288 * 2));
  f16* qh    = (f16*)(ws + alloc(524288 * 2));
  f16* k1h   = (f16*)(ws + alloc(524288 * 2));
  f16* k2h   = (f16*)(ws + alloc(524288 * 2));
  f16* vTh   = (f16*)(ws + alloc(524288 * 2));
  (void)k2h;
  f16* obtd  = (f16*)(ws + alloc(524288 * 2));
  f16* x3h   = (f16*)(ws + alloc(524288 * 2));
  f16* zh    = (f16*)(ws + alloc(2097152 * 2));
  float* h1  = (float*)(ws + alloc(524288 * 4));
  float* x2  = (float*)(ws + alloc(524288 * 4));
  float* ysb = (float*)(ws + alloc(524288 * 4));   // ttt overreads land here (benign)
  float* h2  = (float*)(ws + alloc(524288 * 4));
  float* eta = (float*)(ws + alloc(1024 * 4));
  float* g1b = (float*)(ws + alloc(1024 * 4));     // eta overread lands here (benign)
  float* npB = (float*)(ws + alloc(1024 * 4));     // g1 overread lands here (benign)
  float* nvd = (float*)(ws + alloc(524288 * 4));   // eta diffs
  float* nov = (float*)(ws + alloc(1024 * 4));
  int* flag  = (int*)(ws + alloc(256));
  float* fwfb  = (float*)(ws + alloc(524288 * 4));
  float* momfb = (float*)(ws + alloc(524288 * 4));

  int hc = 16;
  while (hc > 1 && off + (size_t)hc * (262144ull * 4 * 2 + 262144ull * 2) > ws_size) hc >>= 1;
  float* S1  = (float*)(ws + alloc((size_t)hc * 262144 * 4));  // S2 = S1 + hc*262144
  float* S2  = (float*)(ws + alloc((size_t)hc * 262144 * 4));
  f16* attnb = (f16*)(ws + alloc((size_t)hc * 262144 * 2));
  (void)S2;

  // ---- all weight casts in one launch ----
  cvt_all_kernel<<<3328, 256, 0, stream>>>(Wq, Wk1, Wk2, Wv, Wo, W1, W2, WqH);

  // ---- LN1 -> xln (fp16) ----
  ln_kernel<<<256, 256, 0, stream>>>(x, nullptr, ln1g, ln1b, nullptr, nullptr, xlnH);

  // ---- q/k1/k2/vT in one launch (z selects weight + epilogue) ----
  gemm_bt<EPI_QKV><<<dim3(4, 8, 4), 256, 0, stream>>>(
      xlnH, WqH, 512, 512, 0, 262144, qh, nullptr, nullptr, 512, 1.f, 0, 0);

  // ---- attention ----
  const int nc = 16 / hc;
  for (int c = 0; c < nc; c++) {
    const int cs = c * hc;
    gemm_bt<EPI_SCORES><<<dim3(4, 4, 2 * hc), 256, 0, stream>>>(
        qh + (long)cs * 32768, k1h + (long)cs * 32768, 64, 64, 0, 0, S1,
        nullptr, nullptr, 64, 0.125f, 0, hc);
    softmax_diff_kernel<<<hc * 128, 256, 0, stream>>>(S1, S2, lamlog, attnb, cs);
    gemm_bt<EPI_PV><<<dim3(1, 4, hc), 256, 0, stream>>>(
        attnb, vTh + (long)cs * 32768, 512, 512, 262144, 32768, obtd,
        nullptr, nullptr, 512, 1.f, cs, 0);
  }

  // ---- Wo projection + residual -> h1 ----
  gemm_bt<EPI_WO><<<dim3(4, 8, 1), 256, 0, stream>>>(obtd, WoH, 512, 512, 0, 0, h1, nullptr, x, 512, 1.f, 0, 0);

  // ---- LN2 -> x2 (f32) ----
  ln_kernel<<<256, 256, 0, stream>>>(h1, nullptr, ln2g, ln2b, nullptr, x2, nullptr);

  // ---- TTT ----
  hipMemsetAsync(flag, 0, 4, stream);
  eta_diff_kernel<<<16, 64, 0, stream>>>(x2, nvd);
  eta_nov_kernel<<<256, 256, 0, stream>>>(nvd, nov);
  eta_scan_kernel<<<2, 64, 0, stream>>>(nov, loglr, eta);
  g1_kernel<<<256, 256, 0, stream>>>(x2, g1b);
  ttt_fast_kernel<<<1024, 64, 0, stream>>>(x2, basew, tttb, eta, g1b, ysb, npB);
  verify_kernel<<<1, 1024, 0, stream>>>(npB, flag);
  ttt_fallback_kernel<<<2, 1024, 0, stream>>>(flag, x2, basew, tttb, eta, ysb, fwfb, momfb);

  // ---- h2 = h1 + ys ; LN3 -> x3 (fp16) ----
  ln_kernel<<<256, 256, 0, stream>>>(h1, ysb, ln3g, ln3b, h2, nullptr, x3h);

  // ---- FFN ----
  gemm_bt<EPI_GELU><<<dim3(16, 8, 1), 256, 0, stream>>>(x3h, W1H, 512, 512, 0, 0, zh, b1, nullptr, 512, 1.f, 0, 0);
  gemm_bt<EPI_OUT><<<dim3(4, 8, 1), 256, 0, stream>>>(zh, W2H, 2048, 2048, 0, 0, out, b2, h2, 2048, 1.f, 0, 0);
}

// Round 10
// 290.937 us; speedup vs baseline: 127.2350x; 127.2350x over previous
//
#include <hip/hip_runtime.h>
#include <hip/hip_fp16.h>

typedef _Float16 f16;
typedef f16 f16x4 __attribute__((ext_vector_type(4)));
typedef f16 f16x8 __attribute__((ext_vector_type(8)));
typedef float f32x4 __attribute__((ext_vector_type(4)));
typedef unsigned uint2v __attribute__((ext_vector_type(2)));

#define DEVI static __device__ __forceinline__

DEVI void gload_lds16(const void* g, void* l) {
  __builtin_amdgcn_global_load_lds(
      (const __attribute__((address_space(1))) unsigned int*)g,
      (__attribute__((address_space(3))) unsigned int*)l, 16, 0, 0);
}

DEVI float wave_red_sum64(float v) {
#pragma unroll
  for (int m = 1; m < 64; m <<= 1) v += __shfl_xor(v, m, 64);
  return v;
}
DEVI float wave_red_max64(float v) {
#pragma unroll
  for (int m = 1; m < 64; m <<= 1) v = fmaxf(v, __shfl_xor(v, m, 64));
  return v;
}

// ---- cross-lane adds: DPP for xor1..8, permlane-swap for xor16/32 (r6-proven) ----
template <int CTRL>
DEVI float dpp_addf(float v) {
  int s = __builtin_amdgcn_update_dpp(0, __float_as_int(v), CTRL, 0xF, 0xF, true);
  return v + __int_as_float(s);
}
DEVI float xor16_add(float v) {
#if __has_builtin(__builtin_amdgcn_permlane16_swap)
  uint2v r = __builtin_amdgcn_permlane16_swap(__float_as_uint(v), __float_as_uint(v), false, false);
  return __uint_as_float(r.x) + __uint_as_float(r.y);
#else
  int s = __builtin_amdgcn_ds_swizzle(__float_as_int(v), 0x401F);
  return v + __int_as_float(s);
#endif
}
DEVI float xor32_add(float v) {
#if __has_builtin(__builtin_amdgcn_permlane32_swap)
  uint2v r = __builtin_amdgcn_permlane32_swap(__float_as_uint(v), __float_as_uint(v), false, false);
  return __uint_as_float(r.x) + __uint_as_float(r.y);
#else
  int s = __builtin_amdgcn_ds_bpermute(((threadIdx.x & 63) ^ 32) << 2, __float_as_int(v));
  return v + __int_as_float(s);
#endif
}
DEVI float allred64(float v) {
  v = dpp_addf<0xB1>(v);   // xor1
  v = dpp_addf<0x4E>(v);   // xor2
  v = dpp_addf<0x141>(v);  // xor4 (row_half_mirror, uniform bits0-1)
  v = dpp_addf<0x140>(v);  // xor8 (row_mirror, uniform bits0-2)
  v = xor16_add(v);
  return xor32_add(v);
}
DEVI float red16g(float v) {  // reduce within 16-lane groups
  v = dpp_addf<0xB1>(v);
  v = dpp_addf<0x4E>(v);
  v = dpp_addf<0x141>(v);
  v = dpp_addf<0x140>(v);
  return v;
}

// ------------------------------ fused f32 -> f16 cast of all 7 weights -------
__global__ void cvt_all_kernel(const float* __restrict__ s0, const float* __restrict__ s1,
                               const float* __restrict__ s2, const float* __restrict__ s3,
                               const float* __restrict__ s4, const float* __restrict__ s5,
                               const float* __restrict__ s6, f16* __restrict__ d) {
  const int blk = blockIdx.x;
  const float* s; long dofs; int local;
  if (blk < 256)       { s = s0; dofs = 0;       local = blk; }
  else if (blk < 512)  { s = s1; dofs = 262144;  local = blk - 256; }
  else if (blk < 768)  { s = s2; dofs = 524288;  local = blk - 512; }
  else if (blk < 1024) { s = s3; dofs = 786432;  local = blk - 768; }
  else if (blk < 1280) { s = s4; dofs = 1048576; local = blk - 1024; }
  else if (blk < 2304) { s = s5; dofs = 1310720; local = blk - 1280; }
  else                 { s = s6; dofs = 2359296; local = blk - 2304; }
  const long i = (long)local * 1024 + threadIdx.x * 4;
  float4 v = *(const float4*)(s + i);
  f16x4 o = {(f16)v.x, (f16)v.y, (f16)v.z, (f16)v.w};
  *(f16x4*)(d + dofs + i) = o;
}

// ------------------------------ LayerNorm D=512 ------------------------------
__global__ void ln_kernel(const float* __restrict__ in, const float* __restrict__ add,
                          const float* __restrict__ g, const float* __restrict__ b,
                          float* __restrict__ sumout, float* __restrict__ lnf,
                          f16* __restrict__ lnh) {
  const int row = blockIdx.x * 4 + (threadIdx.x >> 6);
  const int lane = threadIdx.x & 63;
  const long base = (long)row * 512;
  const int c0 = lane * 4, c1 = 256 + lane * 4;
  float4 a0 = *(const float4*)(in + base + c0);
  float4 a1 = *(const float4*)(in + base + c1);
  if (add) {
    float4 d0 = *(const float4*)(add + base + c0);
    float4 d1 = *(const float4*)(add + base + c1);
    a0.x += d0.x; a0.y += d0.y; a0.z += d0.z; a0.w += d0.w;
    a1.x += d1.x; a1.y += d1.y; a1.z += d1.z; a1.w += d1.w;
  }
  if (sumout) {
    *(float4*)(sumout + base + c0) = a0;
    *(float4*)(sumout + base + c1) = a1;
  }
  float v[8] = {a0.x, a0.y, a0.z, a0.w, a1.x, a1.y, a1.z, a1.w};
  float s = 0.f;
#pragma unroll
  for (int k = 0; k < 8; k++) s += v[k];
  s = wave_red_sum64(s);
  const float mean = s * (1.f / 512.f);
  float vs = 0.f;
#pragma unroll
  for (int k = 0; k < 8; k++) { float d = v[k] - mean; vs += d * d; }
  vs = wave_red_sum64(vs);
  const float rstd = rsqrtf(vs * (1.f / 512.f) + 1e-5f);
  float4 g0 = *(const float4*)(g + c0), g1 = *(const float4*)(g + c1);
  float4 p0 = *(const float4*)(b + c0), p1 = *(const float4*)(b + c1);
  const float gg[8] = {g0.x, g0.y, g0.z, g0.w, g1.x, g1.y, g1.z, g1.w};
  const float bv[8] = {p0.x, p0.y, p0.z, p0.w, p1.x, p1.y, p1.z, p1.w};
  float y[8];
#pragma unroll
  for (int k = 0; k < 8; k++) y[k] = (v[k] - mean) * rstd * gg[k] + bv[k];
  if (lnf) {
    float4 o0 = {y[0], y[1], y[2], y[3]}, o1 = {y[4], y[5], y[6], y[7]};
    *(float4*)(lnf + base + c0) = o0;
    *(float4*)(lnf + base + c1) = o1;
  }
  if (lnh) {
    f16x4 o0 = {(f16)y[0], (f16)y[1], (f16)y[2], (f16)y[3]};
    f16x4 o1 = {(f16)y[4], (f16)y[5], (f16)y[6], (f16)y[7]};
    *(f16x4*)(lnh + base + c0) = o0;
    *(f16x4*)(lnh + base + c1) = o1;
  }
}

// ------------------------------ generic fp16 MFMA GEMM, C = A(MxK) * W(NxK)^T
// EPI_PART: split-K partial — z indexes the K-chunk (Az/Wz = per-z k-offset),
// writes f32 partials [z][m][512+n] for a later deterministic reduce.
enum { EPI_QKV = 0, EPI_SCORES = 2, EPI_PV = 3, EPI_GELU = 5, EPI_PART = 7 };

template <int EPI>
__launch_bounds__(256, 1) __global__
void gemm_bt(const f16* __restrict__ A, const f16* __restrict__ W, int lda, int ldw,
             long Az, long Wz, void* __restrict__ dst, const float* __restrict__ bias,
             const float* __restrict__ resid, int K, float scale, int zofs, int hcp) {
  if (EPI == EPI_SCORES && blockIdx.x > blockIdx.y) return;  // causal tile skip
  __shared__ f16 lA[128 * 64];
  __shared__ f16 lB[128 * 64];
  const int tid = threadIdx.x;
  const int wave = tid >> 6, lane = tid & 63;
  const int z = blockIdx.z;
  const f16* Ab;
  const f16* Wb;
  if (EPI == EPI_SCORES) {
    const int v_ = (z >= hcp) ? 1 : 0, head = z - v_ * hcp;
    Ab = A + (long)head * 32768 + (long)blockIdx.y * 128 * lda;
    Wb = W + (long)v_ * 524288 + (long)head * 32768 + (long)blockIdx.x * 128 * ldw;
  } else {
    Ab = A + (long)z * Az + (long)blockIdx.y * 128 * lda;
    Wb = W + (long)z * Wz + (long)blockIdx.x * 128 * ldw;
  }

  f32x4 acc[4][4];
#pragma unroll
  for (int a = 0; a < 4; a++)
#pragma unroll
    for (int q = 0; q < 4; q++) acc[a][q] = (f32x4){0.f, 0.f, 0.f, 0.f};

  int srow[4], scol[4];
#pragma unroll
  for (int i = 0; i < 4; i++) {
    int c = i * 256 + tid;
    int row = c >> 3;
    int colb = (c & 7) << 4;
    srow[i] = row;
    scol[i] = (colb ^ ((row & 7) << 4)) >> 1;
  }

  for (int k0 = 0; k0 < K; k0 += 64) {
    __syncthreads();
#pragma unroll
    for (int i = 0; i < 4; i++) {
      const int le = (i * 256 + wave * 64) * 8;
      gload_lds16(Ab + (long)srow[i] * lda + k0 + scol[i], lA + le);
      gload_lds16(Wb + (long)srow[i] * ldw + k0 + scol[i], lB + le);
    }
    __syncthreads();
    const int wm = (wave >> 1) * 64, wn = (wave & 1) * 64;
#pragma unroll
    for (int km = 0; km < 2; km++) {
      const int kb = km * 64 + ((lane >> 4) << 4);
      f16x8 af[4], bfv[4];
#pragma unroll
      for (int mf = 0; mf < 4; mf++) {
        int r = wm + mf * 16 + (lane & 15);
        af[mf] = *(const f16x8*)((const char*)lA + r * 128 + (kb ^ ((r & 7) << 4)));
      }
#pragma unroll
      for (int nf = 0; nf < 4; nf++) {
        int r = wn + nf * 16 + (lane & 15);
        bfv[nf] = *(const f16x8*)((const char*)lB + r * 128 + (kb ^ ((r & 7) << 4)));
      }
#pragma unroll
      for (int mf = 0; mf < 4; mf++)
#pragma unroll
        for (int nf = 0; nf < 4; nf++)
          acc[mf][nf] = __builtin_amdgcn_mfma_f32_16x16x32_f16(af[mf], bfv[nf], acc[mf][nf], 0, 0, 0);
    }
  }

  const int wm = (wave >> 1) * 64, wn = (wave & 1) * 64;
  const int rbase = blockIdx.y * 128 + wm + ((lane >> 4) << 2);
  const int cbase = blockIdx.x * 128 + wn + (lane & 15);
#pragma unroll
  for (int mf = 0; mf < 4; mf++)
#pragma unroll
    for (int nf = 0; nf < 4; nf++)
#pragma unroll
      for (int j = 0; j < 4; j++) {
        const int m = rbase + mf * 16 + j;
        const int n = cbase + nf * 16;
        const float v = acc[mf][nf][j];
        if (EPI == EPI_QKV) {
          // z<3: q/k1/k2 heads layout [B,H,T,64]; z==3: v transposed [B,H,64,T]
          f16* d = (f16*)dst + (long)z * 524288;
          if (z < 3)
            d[(long)((m >> 9) * 8 + (n >> 6)) * 32768 + (m & 511) * 64 + (n & 63)] = (f16)v;
          else
            d[(long)((m >> 9) * 8 + (n >> 6)) * 32768 + (n & 63) * 512 + (m & 511)] = (f16)v;
        } else if (EPI == EPI_SCORES) {
          ((float*)dst)[(long)z * 262144 + (long)m * 512 + n] = v * scale;
        } else if (EPI == EPI_PV) {
          if (n < 64) {
            const int hh = z + zofs;
            ((f16*)dst)[(long)((hh >> 3) * 512 + m) * 512 + (hh & 7) * 64 + n] = (f16)v;
          }
        } else if (EPI == EPI_GELU) {
          const float u = v + bias[n];
          ((f16*)dst)[(long)m * 2048 + n] = (f16)(0.5f * u * (1.f + erff(u * 0.70710678118f)));
        } else {  // EPI_PART (N=512, M=1024)
          ((float*)dst)[(long)z * 524288 + (long)m * 512 + n] = v;
        }
      }
}

// ------------------------------ split-K reduce: 4 partials + resid (+bias) ---
__global__ void red4_kernel(const float* __restrict__ parts, const float* __restrict__ resid,
                            const float* __restrict__ bias, float* __restrict__ dst) {
  const long i = ((long)blockIdx.x * 256 + threadIdx.x) * 4;  // over 1024*512
  float4 s0 = *(const float4*)(parts + i);
  float4 s1 = *(const float4*)(parts + 524288 + i);
  float4 s2 = *(const float4*)(parts + 1048576 + i);
  float4 s3 = *(const float4*)(parts + 1572864 + i);
  float4 r  = *(const float4*)(resid + i);
  float4 o;
  o.x = ((s0.x + s1.x) + (s2.x + s3.x)) + r.x;
  o.y = ((s0.y + s1.y) + (s2.y + s3.y)) + r.y;
  o.z = ((s0.z + s1.z) + (s2.z + s3.z)) + r.z;
  o.w = ((s0.w + s1.w) + (s2.w + s3.w)) + r.w;
  if (bias) {
    const int n = (int)(i & 511);
    float4 b = *(const float4*)(bias + n);
    o.x += b.x; o.y += b.y; o.z += b.z; o.w += b.w;
  }
  *(float4*)(dst + i) = o;
}

// ------------------------------ softmax-diff-L1, one wave per row ------------
__global__ void softmax_diff_kernel(const float* __restrict__ S1, const float* __restrict__ S2,
                                    const float* __restrict__ lamlog, f16* __restrict__ attn,
                                    int zofs) {
  const int rid = blockIdx.x * 4 + (threadIdx.x >> 6);
  const int lane = threadIdx.x & 63;
  const int z = rid >> 9, i = rid & 511;
  const float lam = 1.f / (1.f + __expf(-lamlog[(z + zofs) & 7]));
  const long base = (long)z * 262144 + (long)i * 512;
  const int c0 = lane * 4, c1 = 256 + lane * 4;
  float4 xa = *(const float4*)(S1 + base + c0);
  float4 xb = *(const float4*)(S1 + base + c1);
  float4 ya = *(const float4*)(S2 + base + c0);
  float4 yb = *(const float4*)(S2 + base + c1);
  float s1v[8] = {xa.x, xa.y, xa.z, xa.w, xb.x, xb.y, xb.z, xb.w};
  float s2v[8] = {ya.x, ya.y, ya.z, ya.w, yb.x, yb.y, yb.z, yb.w};
  int cols[8];
#pragma unroll
  for (int k = 0; k < 8; k++) cols[k] = (k < 4) ? (c0 + k) : (c1 + k - 4);
  float m1 = -3.0e38f, m2 = -3.0e38f;
#pragma unroll
  for (int k = 0; k < 8; k++)
    if (cols[k] <= i) { m1 = fmaxf(m1, s1v[k]); m2 = fmaxf(m2, s2v[k]); }
  m1 = wave_red_max64(m1);
  m2 = wave_red_max64(m2);
  float z1 = 0.f, z2 = 0.f, e1[8], e2[8];
#pragma unroll
  for (int k = 0; k < 8; k++) {
    const bool valid = cols[k] <= i;
    e1[k] = valid ? __expf(s1v[k] - m1) : 0.f;
    e2[k] = valid ? __expf(s2v[k] - m2) : 0.f;
    z1 += e1[k]; z2 += e2[k];
  }
  z1 = wave_red_sum64(z1);
  z2 = wave_red_sum64(z2);
  const float r1 = 1.f / z1, r2 = lam / z2;
  float p[8], l1 = 0.f;
#pragma unroll
  for (int k = 0; k < 8; k++) { p[k] = e1[k] * r1 - e2[k] * r2; l1 += fabsf(p[k]); }
  l1 = wave_red_sum64(l1);
  const float rn = 1.f / fmaxf(l1, 1e-6f);
  f16x4 o0 = {(f16)(p[0] * rn), (f16)(p[1] * rn), (f16)(p[2] * rn), (f16)(p[3] * rn)};
  f16x4 o1 = {(f16)(p[4] * rn), (f16)(p[5] * rn), (f16)(p[6] * rn), (f16)(p[7] * rn)};
  *(f16x4*)(attn + base + c0) = o0;
  *(f16x4*)(attn + base + c1) = o1;
}

// ---- inline-asm load + counted-wait primitives (vmcnt counts LOADS AND STORES) ----
#define ALD4(dst, p) asm volatile("global_load_dwordx4 %0, %1, off" : "=&v"(dst) : "v"(p) : "memory")
#define ALD1(dst, p) asm volatile("global_load_dword %0, %1, off" : "=&v"(dst) : "v"(p) : "memory")
#define VMWAIT(N)                                                             \
  {                                                                           \
    asm volatile("s_waitcnt vmcnt(" #N ")" ::: "memory");                     \
    __builtin_amdgcn_sched_barrier(0);                                        \
  }

// ------------------------------ eta precompute, 3 stages ---------------------
#define EISSUE(X)                                                             \
  {                                                                           \
    ALD1(X[0], pe);        ALD1(X[1], pe + 512);                              \
    ALD1(X[2], pe + 1024); ALD1(X[3], pe + 1536);                             \
    ALD1(X[4], pe + 2048); ALD1(X[5], pe + 2560);                             \
    ALD1(X[6], pe + 3072); ALD1(X[7], pe + 3584);                             \
    pe += 4096;                                                               \
  }
#define ESTEP(V, T)                                                           \
  {                                                                           \
    dp[(long)(T) * 512] = fabsf((V) - ema);                                   \
    ema = fmaf(0.95f, ema, 0.05f * (V));                                      \
  }

__launch_bounds__(64, 1) __global__
void eta_diff_kernel(const float* __restrict__ x2, float* __restrict__ diff) {
  const int blk = blockIdx.x;  // 16: b = blk>>3, col group = blk&7
  const int b = blk >> 3;
  const int col = (blk & 7) * 64 + threadIdx.x;
  const float* pe = x2 + (long)b * 262144 + col;
  float* dp = diff + (long)b * 262144 + col;
  float ema = 0.f;
  float EA[8], EB[8];
  EISSUE(EA);
  EISSUE(EB);
  VMWAIT(8);
#pragma unroll 1
  for (int t = 0; t < 512; t += 16) {
    ESTEP(EA[0], t + 0); ESTEP(EA[1], t + 1); ESTEP(EA[2], t + 2); ESTEP(EA[3], t + 3);
    ESTEP(EA[4], t + 4); ESTEP(EA[5], t + 5); ESTEP(EA[6], t + 6); ESTEP(EA[7], t + 7);
    EISSUE(EA);
    VMWAIT(16);
    ESTEP(EB[0], t + 8);  ESTEP(EB[1], t + 9);  ESTEP(EB[2], t + 10); ESTEP(EB[3], t + 11);
    ESTEP(EB[4], t + 12); ESTEP(EB[5], t + 13); ESTEP(EB[6], t + 14); ESTEP(EB[7], t + 15);
    EISSUE(EB);
    VMWAIT(16);
  }
  asm volatile("s_waitcnt vmcnt(0)" ::: "memory");
}

__global__ void eta_nov_kernel(const float* __restrict__ diff, float* __restrict__ nov) {
  const int row = blockIdx.x * 4 + (threadIdx.x >> 6);  // row = b*512+t
  const int lane = threadIdx.x & 63;
  const float* dp = diff + (long)row * 512 + lane * 4;
  float4 a0 = *(const float4*)dp;
  float4 a1 = *(const float4*)(dp + 256);
  float s = ((a0.x + a0.y) + (a0.z + a0.w)) + ((a1.x + a1.y) + (a1.z + a1.w));
  s = wave_red_sum64(s);
  if (lane == 0) nov[row] = s * (1.f / 512.f);
}

__global__ void eta_scan_kernel(const float* __restrict__ nov, const float* __restrict__ loglr,
                                float* __restrict__ eta) {
  if (threadIdx.x != 0) return;
  const int b = blockIdx.x;
  float ilr = expf(loglr[0]);
  ilr = fminf(fmaxf(ilr, 1e-5f), 1.f);
  float lrm = 1.f;
  const float* pb = nov + (long)b * 512;
#pragma unroll 8
  for (int t = 0; t < 512; t++) {
    const float ls = fminf(fmaxf(fmaf(3.f, pb[t], 1.f), 0.5f), 3.f);
    lrm = fmaf(0.95f, lrm, 0.05f * ls);
    eta[b * 512 + t] = ilr * lrm;
  }
}

// ------------------------------ TTT fast path (r6 dual-row, EXACT) -----------
DEVI float dot8(const f32x4 F0, const f32x4 F1, const f32x4 X0, const f32x4 X1) {
  float a0 = F0.x * X0.x, a1 = F0.y * X0.y, a2 = F0.z * X0.z, a3 = F0.w * X0.w;
  a0 = fmaf(F1.x, X1.x, a0); a1 = fmaf(F1.y, X1.y, a1);
  a2 = fmaf(F1.z, X1.z, a2); a3 = fmaf(F1.w, X1.w, a3);
  return (a0 + a1) + (a2 + a3);
}
DEVI void upd8(f32x4& M0, f32x4& M1, f32x4& F0, f32x4& F1, float c1, float e,
               const f32x4 X0, const f32x4 X1, float& ns) {
  M0.x = fmaf(0.9f, M0.x, c1 * X0.x); F0.x = fmaf(-e, M0.x, F0.x); ns = fmaf(F0.x, F0.x, ns);
  M0.y = fmaf(0.9f, M0.y, c1 * X0.y); F0.y = fmaf(-e, M0.y, F0.y); ns = fmaf(F0.y, F0.y, ns);
  M0.z = fmaf(0.9f, M0.z, c1 * X0.z); F0.z = fmaf(-e, M0.z, F0.z); ns = fmaf(F0.z, F0.z, ns);
  M0.w = fmaf(0.9f, M0.w, c1 * X0.w); F0.w = fmaf(-e, M0.w, F0.w); ns = fmaf(F0.w, F0.w, ns);
  M1.x = fmaf(0.9f, M1.x, c1 * X1.x); F1.x = fmaf(-e, M1.x, F1.x); ns = fmaf(F1.x, F1.x, ns);
  M1.y = fmaf(0.9f, M1.y, c1 * X1.y); F1.y = fmaf(-e, M1.y, F1.y); ns = fmaf(F1.y, F1.y, ns);
  M1.z = fmaf(0.9f, M1.z, c1 * X1.z); F1.z = fmaf(-e, M1.z, F1.z); ns = fmaf(F1.z, F1.z, ns);
  M1.w = fmaf(0.9f, M1.w, c1 * X1.w); F1.w = fmaf(-e, M1.w, F1.w); ns = fmaf(F1.w, F1.w, ns);
}

#define TISSUE2(X, RA, RB, ET)                                                \
  {                                                                           \
    ALD4(X[0], pxc);        ALD4(X[1], pxc + 4);                              \
    ALD4(X[2], pxc + 512);  ALD4(X[3], pxc + 516);                            \
    ALD4(X[4], pxc + 1024); ALD4(X[5], pxc + 1028);                           \
    ALD4(X[6], pxc + 1536); ALD4(X[7], pxc + 1540);                           \
    ALD1(RA[0], pxra);        ALD1(RA[1], pxra + 512);                        \
    ALD1(RA[2], pxra + 1024); ALD1(RA[3], pxra + 1536);                       \
    ALD1(RB[0], pxrb);        ALD1(RB[1], pxrb + 512);                        \
    ALD1(RB[2], pxrb + 1024); ALD1(RB[3], pxrb + 1536);                       \
    ALD4(ET, per);                                                            \
    pxc += 2048; pxra += 2048; pxrb += 2048; per += 4;                        \
  }

#define TSTEP2(X0v, X1v, rAv, rBv, ev, K)                                     \
  {                                                                           \
    const float pA_ = allred64(dot8(fA0, fA1, X0v, X1v));                     \
    const float pB_ = allred64(dot8(fB0, fB1, X0v, X1v));                     \
    const float yA_ = pA_ + biasA, yB_ = pB_ + biasB;                         \
    ysA[K] = yA_; ysB[K] = yB_;                                               \
    const float c1A_ = (yA_ - (rAv)) * (0.1f / 512.f);                        \
    const float c1B_ = (yB_ - (rBv)) * (0.1f / 512.f);                        \
    const float e_ = (ev);                                                    \
    float ns_ = 0.f;                                                          \
    upd8(mA0, mA1, fA0, fA1, c1A_, e_, X0v, X1v, ns_);                        \
    upd8(mB0, mB1, fB0, fB1, c1B_, e_, X0v, X1v, ns_);                        \
    np8[K] = allred64(ns_);                                                   \
  }

__launch_bounds__(64, 1) __global__
void ttt_fast_kernel(const float* __restrict__ x2, const float* __restrict__ base_w,
                     const float* __restrict__ tbias, const float* __restrict__ eta,
                     float* __restrict__ yT, float* __restrict__ npT) {
  const int blk = blockIdx.x;   // 512
  const int b = blk >> 8;
  const int rA = blk & 255;     // row A; row B = rA + 256
  const int lane = threadIdx.x;
  const float* xb = x2 + (long)b * 262144;

  f32x4 fA0, fA1, fB0, fB1;
  float biasA, biasB;
  ALD4(fA0, base_w + (long)rA * 512 + lane * 8);
  ALD4(fA1, base_w + (long)rA * 512 + lane * 8 + 4);
  ALD4(fB0, base_w + (long)(rA + 256) * 512 + lane * 8);
  ALD4(fB1, base_w + (long)(rA + 256) * 512 + lane * 8 + 4);
  ALD1(biasA, tbias + rA);
  ALD1(biasB, tbias + rA + 256);

  f32x4 mA0 = {0.f, 0.f, 0.f, 0.f}, mA1 = mA0, mB0 = mA0, mB1 = mA0;
  float ysA[8], ysB[8], np8[8];

  const float* pxc = xb + lane * 8;
  const float* pxra = xb + rA;
  const float* pxrb = xb + rA + 256;
  const float* per = eta + b * 512;
  float* pyA = yT + (long)(b * 512 + rA) * 512;
  float* pyB = yT + (long)(b * 512 + rA + 256) * 512;
  float* pnp = npT + (long)blk * 512;

  f32x4 XA[8], XB[8], EA, EB;
  float RA0[4], RB0[4], RA1[4], RB1[4];
  TISSUE2(XA, RA0, RB0, EA);
  TISSUE2(XB, RA1, RB1, EB);
  VMWAIT(17);  // drains 6 param loads + group A's 17

#pragma unroll 1
  for (int T = 0; T < 512; T += 8) {
    TSTEP2(XA[0], XA[1], RA0[0], RB0[0], EA.x, 0);
    TSTEP2(XA[2], XA[3], RA0[1], RB0[1], EA.y, 1);
    TSTEP2(XA[4], XA[5], RA0[2], RB0[2], EA.z, 2);
    TSTEP2(XA[6], XA[7], RA0[3], RB0[3], EA.w, 3);
    TISSUE2(XA, RA0, RB0, EA);
    VMWAIT(17);  // drain group B (+ any stale stores, long retired)
    TSTEP2(XB[0], XB[1], RA1[0], RB1[0], EB.x, 4);
    TSTEP2(XB[2], XB[3], RA1[1], RB1[1], EB.y, 5);
    TSTEP2(XB[4], XB[5], RA1[2], RB1[2], EB.z, 6);
    TSTEP2(XB[6], XB[7], RA1[3], RB1[3], EB.w, 7);
    if (lane == 0) {
      *(float4*)(pyA + T)     = (float4){ysA[0], ysA[1], ysA[2], ysA[3]};
      *(float4*)(pyA + T + 4) = (float4){ysA[4], ysA[5], ysA[6], ysA[7]};
      *(float4*)(pyB + T)     = (float4){ysB[0], ysB[1], ysB[2], ysB[3]};
      *(float4*)(pyB + T + 4) = (float4){ysB[4], ysB[5], ysB[6], ysB[7]};
      *(float4*)(pnp + T)     = (float4){np8[0], np8[1], np8[2], np8[3]};
      *(float4*)(pnp + T + 4) = (float4){np8[4], np8[5], np8[6], np8[7]};
    }
    TISSUE2(XB, RA1, RB1, EB);
    VMWAIT(23);  // queue = [A'17][6st][B'17]; drain A' only
  }
  asm volatile("s_waitcnt vmcnt(0)" ::: "memory");
}

// ------------------------------ 3-slice 512x512 f32 transpose ----------------
__global__ void transpose3_kernel(const float* __restrict__ yT, const float* __restrict__ npT,
                                  float* __restrict__ ysb, float* __restrict__ npv) {
  __shared__ float tile[64][65];
  const int s = blockIdx.z;
  const float* src = (s < 2) ? (yT + (long)s * 262144) : npT;
  float* dst = (s < 2) ? (ysb + (long)s * 262144) : npv;
  const int ti = blockIdx.y, tj = blockIdx.x;
  const int tr = threadIdx.x >> 4;
  const int tc = (threadIdx.x & 15) * 4;
#pragma unroll
  for (int p = 0; p < 4; p++) {
    const int r = tr + p * 16;
    float4 v = *(const float4*)(src + (long)(ti * 64 + r) * 512 + tj * 64 + tc);
    tile[r][tc] = v.x; tile[r][tc + 1] = v.y; tile[r][tc + 2] = v.z; tile[r][tc + 3] = v.w;
  }
  __syncthreads();
#pragma unroll
  for (int p = 0; p < 4; p++) {
    const int j = tr + p * 16;
    float4 v = {tile[tc][j], tile[tc + 1][j], tile[tc + 2][j], tile[tc + 3][j]};
    *(float4*)(dst + (long)(tj * 64 + j) * 512 + ti * 64 + tc) = v;
  }
}

// ------------------------------ verify: norm ever > 32? ----------------------
__global__ void verify_kernel(const float* __restrict__ npv, int* __restrict__ flag) {
  const int t = blockIdx.x;        // 512 blocks, one per step
  const int tid = threadIdx.x;     // 512 threads, one per ttt wave
  const int wave = tid >> 6, lane = tid & 63;
  float s = npv[(long)t * 512 + tid];
  s = wave_red_sum64(s);
  __shared__ float part[8];
  if (lane == 0) part[wave] = s;
  __syncthreads();
  if (tid == 0) {
    const float s0 = (part[0] + part[1]) + (part[2] + part[3]);  // batch 0
    const float s1 = (part[4] + part[5]) + (part[6] + part[7]);  // batch 1
    if (s0 > 1020.f || s1 > 1020.f) atomicOr(flag, 1);  // margin under 32^2=1024
  }
}

// ------------------------------ TTT fallback (exact, with clip) --------------
__launch_bounds__(1024, 1) __global__
void ttt_fallback_kernel(const int* __restrict__ flag, const float* __restrict__ x2,
                         const float* __restrict__ base_w, const float* __restrict__ tbias,
                         const float* __restrict__ eta, float* __restrict__ ys,
                         float* __restrict__ fwg, float* __restrict__ momg) {
  if (flag[0] == 0) return;
  const int b = blockIdx.x;
  const int tid = threadIdx.x;
  const int wave = tid >> 6, lane = tid & 63;
  float* fw = fwg + (long)b * 262144;
  float* mm = momg + (long)b * 262144;
  for (int e = tid; e < 262144; e += 1024) { fw[e] = base_w[e]; mm[e] = 0.f; }
  __shared__ float xs[512], errs[512], red[16];
  const float* xb = x2 + (long)b * 262144;
  for (int t = 0; t < 512; t++) {
    __syncthreads();
    if (tid < 512) xs[tid] = xb[t * 512 + tid];
    __syncthreads();
    if (tid < 512) {
      float acc = 0.f;
      for (int c = 0; c < 512; c++) acc = fmaf(fw[(long)tid * 512 + c], xs[c], acc);
      const float y = acc + tbias[tid];
      ys[((long)b * 512 + t) * 512 + tid] = y;
      errs[tid] = (y - xs[tid]) * (1.f / 512.f);
    }
    __syncthreads();
    const float eta_t = eta[b * 512 + t];
    float nsq = 0.f;
    for (int e = tid; e < 262144; e += 1024) {
      const int r = e >> 9, c = e & 511;
      const float m2 = fmaf(0.9f, mm[e], 0.1f * errs[r] * xs[c]);
      mm[e] = m2;
      const float f2 = fmaf(-eta_t, m2, fw[e]);
      fw[e] = f2;
      nsq = fmaf(f2, f2, nsq);
    }
    nsq = wave_red_sum64(nsq);
    if (lane == 0) red[wave] = nsq;
    __syncthreads();
    if (tid == 0) {
      float s = 0.f;
      for (int w = 0; w < 16; w++) s += red[w];
      red[0] = s;
    }
    __syncthreads();
    const float norm = fmaxf(sqrtf(red[0]), 1e-6f);
    const float sc = fminf(32.f / norm, 1.f);
    if (sc < 1.f)
      for (int e = tid; e < 262144; e += 1024) fw[e] *= sc;
  }
}

// ------------------------------ host launch ------------------------------
extern "C" void kernel_launch(void* const* d_in, const int* in_sizes, int n_in,
                              void* d_out, int out_size, void* d_ws, size_t ws_size,
                              hipStream_t stream) {
  (void)in_sizes; (void)n_in; (void)out_size;
  const float* x      = (const float*)d_in[0];
  const float* Wq     = (const float*)d_in[1];
  const float* Wk1    = (const float*)d_in[2];
  const float* Wk2    = (const float*)d_in[3];
  const float* Wv     = (const float*)d_in[4];
  const float* Wo     = (const float*)d_in[5];
  const float* lamlog = (const float*)d_in[6];
  const float* ln1g   = (const float*)d_in[7];
  const float* ln1b   = (const float*)d_in[8];
  const float* basew  = (const float*)d_in[9];
  const float* tttb   = (const float*)d_in[10];
  const float* loglr  = (const float*)d_in[11];
  const float* ln2g   = (const float*)d_in[12];
  const float* ln2b   = (const float*)d_in[13];
  const float* W1     = (const float*)d_in[14];
  const float* b1     = (const float*)d_in[15];
  const float* W2     = (const float*)d_in[16];
  const float* b2     = (const float*)d_in[17];
  const float* ln3g   = (const float*)d_in[18];
  const float* ln3b   = (const float*)d_in[19];
  float* out = (float*)d_out;

  char* ws = (char*)d_ws;
  size_t off = 0;
  auto alloc = [&](size_t bytes) {
    size_t o = off;
    off += (bytes + 255) & ~(size_t)255;
    return o;
  };
  f16* WqH   = (f16*)(ws + alloc(262144 * 2));
  f16* Wk1H  = (f16*)(ws + alloc(262144 * 2));
  f16* Wk2H  = (f16*)(ws + alloc(262144 * 2));
  f16* WvH   = (f16*)(ws + alloc(262144 * 2));
  f16* WoH   = (f16*)(ws + alloc(262144 * 2));
  f16* W1H   = (f16*)(ws + alloc(1048576 * 2));
  f16* W2H   = (f16*)(ws + alloc(1048576 * 2));
  (void)Wk1H; (void)Wk2H; (void)WvH; (void)W1H;
  f16* xlnH  = (f16*)(ws + alloc(524288 * 2));
  f16* qh    = (f16*)(ws + alloc(524288 * 2));
  f16* k1h   = (f16*)(ws + alloc(524288 * 2));
  f16* k2h   = (f16*)(ws + alloc(524288 * 2));
  f16* vTh   = (f16*)(ws + alloc(524288 * 2));
  (void)k2h;
  f16* obtd  = (f16*)(ws + alloc(524288 * 2));
  f16* x3h   = (f16*)(ws + alloc(524288 * 2));
  f16* zh    = (f16*)(ws + alloc(2097152 * 2));
  float* h1  = (float*)(ws + alloc(524288 * 4));
  float* x2  = (float*)(ws + alloc(524288 * 4));
  float* ysb = (float*)(ws + alloc(524288 * 4));
  float* h2  = (float*)(ws + alloc(524288 * 4));
  float* eta = (float*)(ws + alloc(1024 * 4));
  float* yT  = (float*)(ws + alloc(524288 * 4));  // ys transposed [b][row][t]
  float* npT = (float*)(ws + alloc(262144 * 4));  // norm partials [blk][t]
  float* npv = (float*)(ws + alloc(262144 * 4));  // norm partials [t][blk]
  float* nvd = (float*)(ws + alloc(524288 * 4));  // eta diffs
  float* nov = (float*)(ws + alloc(1024 * 4));
  int* flag  = (int*)(ws + alloc(256));
  float* fwfb  = (float*)(ws + alloc(524288 * 4));
  float* momfb = (float*)(ws + alloc(524288 * 4));
  float* parts = (float*)(ws + alloc((size_t)4 * 524288 * 4));  // split-K partials (8MB)

  int hc = 16;
  while (hc > 1 && off + (size_t)hc * (262144ull * 4 * 2 + 262144ull * 2) > ws_size) hc >>= 1;
  float* S1  = (float*)(ws + alloc((size_t)hc * 262144 * 4));  // S2 = S1 + hc*262144
  float* S2  = (float*)(ws + alloc((size_t)hc * 262144 * 4));
  f16* attnb = (f16*)(ws + alloc((size_t)hc * 262144 * 2));
  (void)S2;

  // ---- all weight casts in one launch ----
  cvt_all_kernel<<<3328, 256, 0, stream>>>(Wq, Wk1, Wk2, Wv, Wo, W1, W2, WqH);

  // ---- LN1 -> xln (fp16) ----
  ln_kernel<<<256, 256, 0, stream>>>(x, nullptr, ln1g, ln1b, nullptr, nullptr, xlnH);

  // ---- q/k1/k2/vT in one launch (z selects weight + epilogue) ----
  gemm_bt<EPI_QKV><<<dim3(4, 8, 4), 256, 0, stream>>>(
      xlnH, WqH, 512, 512, 0, 262144, qh, nullptr, nullptr, 512, 1.f, 0, 0);

  // ---- attention ----
  const int nc = 16 / hc;
  for (int c = 0; c < nc; c++) {
    const int cs = c * hc;
    gemm_bt<EPI_SCORES><<<dim3(4, 4, 2 * hc), 256, 0, stream>>>(
        qh + (long)cs * 32768, k1h + (long)cs * 32768, 64, 64, 0, 0, S1,
        nullptr, nullptr, 64, 0.125f, 0, hc);
    softmax_diff_kernel<<<hc * 128, 256, 0, stream>>>(S1, S2, lamlog, attnb, cs);
    gemm_bt<EPI_PV><<<dim3(1, 4, hc), 256, 0, stream>>>(
        attnb, vTh + (long)cs * 32768, 512, 512, 262144, 32768, obtd,
        nullptr, nullptr, 512, 1.f, cs, 0);
  }

  // ---- Wo projection (split-K x4: 128 blocks) + reduce w/ residual -> h1 ----
  gemm_bt<EPI_PART><<<dim3(4, 8, 4), 256, 0, stream>>>(
      obtd, WoH, 512, 512, 128, 128, parts, nullptr, nullptr, 128, 1.f, 0, 0);
  red4_kernel<<<512, 256, 0, stream>>>(parts, x, nullptr, h1);

  // ---- LN2 -> x2 (f32) ----
  ln_kernel<<<256, 256, 0, stream>>>(h1, nullptr, ln2g, ln2b, nullptr, x2, nullptr);

  // ---- TTT (r6-proven cluster) ----
  hipMemsetAsync(flag, 0, 4, stream);
  eta_diff_kernel<<<16, 64, 0, stream>>>(x2, nvd);
  eta_nov_kernel<<<256, 256, 0, stream>>>(nvd, nov);
  eta_scan_kernel<<<2, 64, 0, stream>>>(nov, loglr, eta);
  ttt_fast_kernel<<<512, 64, 0, stream>>>(x2, basew, tttb, eta, yT, npT);
  transpose3_kernel<<<dim3(8, 8, 3), 256, 0, stream>>>(yT, npT, ysb, npv);
  verify_kernel<<<512, 512, 0, stream>>>(npv, flag);
  ttt_fallback_kernel<<<2, 1024, 0, stream>>>(flag, x2, basew, tttb, eta, ysb, fwfb, momfb);

  // ---- h2 = h1 + ys ; LN3 -> x3 (fp16) ----
  ln_kernel<<<256, 256, 0, stream>>>(h1, ysb, ln3g, ln3b, h2, nullptr, x3h);

  // ---- FFN: GELU gemm; then W2 split-K x4 (128 blocks) + reduce -> out ----
  gemm_bt<EPI_GELU><<<dim3(16, 8, 1), 256, 0, stream>>>(x3h, W1H, 512, 512, 0, 0, zh, b1, nullptr, 512, 1.f, 0, 0);
  gemm_bt<EPI_PART><<<dim3(4, 8, 4), 256, 0, stream>>>(
      zh, W2H, 2048, 2048, 512, 512, parts, nullptr, nullptr, 512, 1.f, 0, 0);
  red4_kernel<<<512, 256, 0, stream>>>(parts, h2, b2, out);
}

// Round 11
// 283.251 us; speedup vs baseline: 130.6877x; 1.0271x over previous
//
#include <hip/hip_runtime.h>
#include <hip/hip_fp16.h>

typedef _Float16 f16;
typedef f16 f16x4 __attribute__((ext_vector_type(4)));
typedef f16 f16x8 __attribute__((ext_vector_type(8)));
typedef float f32x4 __attribute__((ext_vector_type(4)));

#define DEVI static __device__ __forceinline__

DEVI void gload_lds16(const void* g, void* l) {
  __builtin_amdgcn_global_load_lds(
      (const __attribute__((address_space(1))) unsigned int*)g,
      (__attribute__((address_space(3))) unsigned int*)l, 16, 0, 0);
}

DEVI float wave_red_sum64(float v) {
#pragma unroll
  for (int m = 1; m < 64; m <<= 1) v += __shfl_xor(v, m, 64);
  return v;
}
DEVI float wave_red_max64(float v) {
#pragma unroll
  for (int m = 1; m < 64; m <<= 1) v = fmaxf(v, __shfl_xor(v, m, 64));
  return v;
}

// ---- all-DPP wave64 sum: 4 xor stages (proven r5-r10) + ROW_BCAST15/31 ----
// Every op is a VALU v_add_f32 with DPP — no LDS pipe, no permlane builtins.
// After xor stages each 16-group g holds S_g in all lanes. bcast15 (rows 1,3):
// row1=S0+S1, row3=S2+S3. bcast31 (rows 2,3): lane31 holds S0+S1 -> row3 =
// total. readlane(63) broadcasts via SGPR.
template <int CTRL>
DEVI float dpp_addf(float v) {
  int s = __builtin_amdgcn_update_dpp(0, __float_as_int(v), CTRL, 0xF, 0xF, true);
  return v + __int_as_float(s);
}
DEVI float redsum64(float v) {
  v = dpp_addf<0xB1>(v);   // xor1  (quad_perm 1,0,3,2)
  v = dpp_addf<0x4E>(v);   // xor2  (quad_perm 2,3,0,1)
  v = dpp_addf<0x141>(v);  // xor4  (row_half_mirror)
  v = dpp_addf<0x140>(v);  // xor8  (row_mirror)
  int t = __builtin_amdgcn_update_dpp(0, __float_as_int(v), 0x142, 0xA, 0xF, true);  // ROW_BCAST15, rows 1&3
  v += __int_as_float(t);
  t = __builtin_amdgcn_update_dpp(0, __float_as_int(v), 0x143, 0xC, 0xF, true);      // ROW_BCAST31, rows 2&3
  v += __int_as_float(t);
  return __int_as_float(__builtin_amdgcn_readlane(__float_as_int(v), 63));
}

// ------------------------------ fused f32 -> f16 cast of all 7 weights -------
__global__ void cvt_all_kernel(const float* __restrict__ s0, const float* __restrict__ s1,
                               const float* __restrict__ s2, const float* __restrict__ s3,
                               const float* __restrict__ s4, const float* __restrict__ s5,
                               const float* __restrict__ s6, f16* __restrict__ d) {
  const int blk = blockIdx.x;
  const float* s; long dofs; int local;
  if (blk < 256)       { s = s0; dofs = 0;       local = blk; }
  else if (blk < 512)  { s = s1; dofs = 262144;  local = blk - 256; }
  else if (blk < 768)  { s = s2; dofs = 524288;  local = blk - 512; }
  else if (blk < 1024) { s = s3; dofs = 786432;  local = blk - 768; }
  else if (blk < 1280) { s = s4; dofs = 1048576; local = blk - 1024; }
  else if (blk < 2304) { s = s5; dofs = 1310720; local = blk - 1280; }
  else                 { s = s6; dofs = 2359296; local = blk - 2304; }
  const long i = (long)local * 1024 + threadIdx.x * 4;
  float4 v = *(const float4*)(s + i);
  f16x4 o = {(f16)v.x, (f16)v.y, (f16)v.z, (f16)v.w};
  *(f16x4*)(d + dofs + i) = o;
}

// ------------------------------ LayerNorm D=512 ------------------------------
__global__ void ln_kernel(const float* __restrict__ in, const float* __restrict__ add,
                          const float* __restrict__ g, const float* __restrict__ b,
                          float* __restrict__ sumout, float* __restrict__ lnf,
                          f16* __restrict__ lnh) {
  const int row = blockIdx.x * 4 + (threadIdx.x >> 6);
  const int lane = threadIdx.x & 63;
  const long base = (long)row * 512;
  const int c0 = lane * 4, c1 = 256 + lane * 4;
  float4 a0 = *(const float4*)(in + base + c0);
  float4 a1 = *(const float4*)(in + base + c1);
  if (add) {
    float4 d0 = *(const float4*)(add + base + c0);
    float4 d1 = *(const float4*)(add + base + c1);
    a0.x += d0.x; a0.y += d0.y; a0.z += d0.z; a0.w += d0.w;
    a1.x += d1.x; a1.y += d1.y; a1.z += d1.z; a1.w += d1.w;
  }
  if (sumout) {
    *(float4*)(sumout + base + c0) = a0;
    *(float4*)(sumout + base + c1) = a1;
  }
  float v[8] = {a0.x, a0.y, a0.z, a0.w, a1.x, a1.y, a1.z, a1.w};
  float s = 0.f;
#pragma unroll
  for (int k = 0; k < 8; k++) s += v[k];
  s = wave_red_sum64(s);
  const float mean = s * (1.f / 512.f);
  float vs = 0.f;
#pragma unroll
  for (int k = 0; k < 8; k++) { float d = v[k] - mean; vs += d * d; }
  vs = wave_red_sum64(vs);
  const float rstd = rsqrtf(vs * (1.f / 512.f) + 1e-5f);
  float4 g0 = *(const float4*)(g + c0), g1 = *(const float4*)(g + c1);
  float4 p0 = *(const float4*)(b + c0), p1 = *(const float4*)(b + c1);
  const float gg[8] = {g0.x, g0.y, g0.z, g0.w, g1.x, g1.y, g1.z, g1.w};
  const float bv[8] = {p0.x, p0.y, p0.z, p0.w, p1.x, p1.y, p1.z, p1.w};
  float y[8];
#pragma unroll
  for (int k = 0; k < 8; k++) y[k] = (v[k] - mean) * rstd * gg[k] + bv[k];
  if (lnf) {
    float4 o0 = {y[0], y[1], y[2], y[3]}, o1 = {y[4], y[5], y[6], y[7]};
    *(float4*)(lnf + base + c0) = o0;
    *(float4*)(lnf + base + c1) = o1;
  }
  if (lnh) {
    f16x4 o0 = {(f16)y[0], (f16)y[1], (f16)y[2], (f16)y[3]};
    f16x4 o1 = {(f16)y[4], (f16)y[5], (f16)y[6], (f16)y[7]};
    *(f16x4*)(lnh + base + c0) = o0;
    *(f16x4*)(lnh + base + c1) = o1;
  }
}

// ------------------------------ generic fp16 MFMA GEMM, C = A(MxK) * W(NxK)^T
enum { EPI_QKV = 0, EPI_SCORES = 2, EPI_PV = 3, EPI_GELU = 5, EPI_PART = 7 };

template <int EPI>
__launch_bounds__(256, 1) __global__
void gemm_bt(const f16* __restrict__ A, const f16* __restrict__ W, int lda, int ldw,
             long Az, long Wz, void* __restrict__ dst, const float* __restrict__ bias,
             const float* __restrict__ resid, int K, float scale, int zofs, int hcp) {
  if (EPI == EPI_SCORES && blockIdx.x > blockIdx.y) return;  // causal tile skip
  __shared__ f16 lA[128 * 64];
  __shared__ f16 lB[128 * 64];
  const int tid = threadIdx.x;
  const int wave = tid >> 6, lane = tid & 63;
  const int z = blockIdx.z;
  const f16* Ab;
  const f16* Wb;
  if (EPI == EPI_SCORES) {
    const int v_ = (z >= hcp) ? 1 : 0, head = z - v_ * hcp;
    Ab = A + (long)head * 32768 + (long)blockIdx.y * 128 * lda;
    Wb = W + (long)v_ * 524288 + (long)head * 32768 + (long)blockIdx.x * 128 * ldw;
  } else {
    Ab = A + (long)z * Az + (long)blockIdx.y * 128 * lda;
    Wb = W + (long)z * Wz + (long)blockIdx.x * 128 * ldw;
  }

  f32x4 acc[4][4];
#pragma unroll
  for (int a = 0; a < 4; a++)
#pragma unroll
    for (int q = 0; q < 4; q++) acc[a][q] = (f32x4){0.f, 0.f, 0.f, 0.f};

  int srow[4], scol[4];
#pragma unroll
  for (int i = 0; i < 4; i++) {
    int c = i * 256 + tid;
    int row = c >> 3;
    int colb = (c & 7) << 4;
    srow[i] = row;
    scol[i] = (colb ^ ((row & 7) << 4)) >> 1;
  }

  for (int k0 = 0; k0 < K; k0 += 64) {
    __syncthreads();
#pragma unroll
    for (int i = 0; i < 4; i++) {
      const int le = (i * 256 + wave * 64) * 8;
      gload_lds16(Ab + (long)srow[i] * lda + k0 + scol[i], lA + le);
      gload_lds16(Wb + (long)srow[i] * ldw + k0 + scol[i], lB + le);
    }
    __syncthreads();
    const int wm = (wave >> 1) * 64, wn = (wave & 1) * 64;
#pragma unroll
    for (int km = 0; km < 2; km++) {
      const int kb = km * 64 + ((lane >> 4) << 4);
      f16x8 af[4], bfv[4];
#pragma unroll
      for (int mf = 0; mf < 4; mf++) {
        int r = wm + mf * 16 + (lane & 15);
        af[mf] = *(const f16x8*)((const char*)lA + r * 128 + (kb ^ ((r & 7) << 4)));
      }
#pragma unroll
      for (int nf = 0; nf < 4; nf++) {
        int r = wn + nf * 16 + (lane & 15);
        bfv[nf] = *(const f16x8*)((const char*)lB + r * 128 + (kb ^ ((r & 7) << 4)));
      }
#pragma unroll
      for (int mf = 0; mf < 4; mf++)
#pragma unroll
        for (int nf = 0; nf < 4; nf++)
          acc[mf][nf] = __builtin_amdgcn_mfma_f32_16x16x32_f16(af[mf], bfv[nf], acc[mf][nf], 0, 0, 0);
    }
  }

  const int wm = (wave >> 1) * 64, wn = (wave & 1) * 64;
  const int rbase = blockIdx.y * 128 + wm + ((lane >> 4) << 2);
  const int cbase = blockIdx.x * 128 + wn + (lane & 15);
#pragma unroll
  for (int mf = 0; mf < 4; mf++)
#pragma unroll
    for (int nf = 0; nf < 4; nf++)
#pragma unroll
      for (int j = 0; j < 4; j++) {
        const int m = rbase + mf * 16 + j;
        const int n = cbase + nf * 16;
        const float v = acc[mf][nf][j];
        if (EPI == EPI_QKV) {
          f16* d = (f16*)dst + (long)z * 524288;
          if (z < 3)
            d[(long)((m >> 9) * 8 + (n >> 6)) * 32768 + (m & 511) * 64 + (n & 63)] = (f16)v;
          else
            d[(long)((m >> 9) * 8 + (n >> 6)) * 32768 + (n & 63) * 512 + (m & 511)] = (f16)v;
        } else if (EPI == EPI_SCORES) {
          ((float*)dst)[(long)z * 262144 + (long)m * 512 + n] = v * scale;
        } else if (EPI == EPI_PV) {
          if (n < 64) {
            const int hh = z + zofs;
            ((f16*)dst)[(long)((hh >> 3) * 512 + m) * 512 + (hh & 7) * 64 + n] = (f16)v;
          }
        } else if (EPI == EPI_GELU) {
          const float u = v + bias[n];
          ((f16*)dst)[(long)m * 2048 + n] = (f16)(0.5f * u * (1.f + erff(u * 0.70710678118f)));
        } else {  // EPI_PART (N=512, M=1024)
          ((float*)dst)[(long)z * 524288 + (long)m * 512 + n] = v;
        }
      }
}

// ------------------------------ split-K reduce: 4 partials + resid (+bias) ---
__global__ void red4_kernel(const float* __restrict__ parts, const float* __restrict__ resid,
                            const float* __restrict__ bias, float* __restrict__ dst) {
  const long i = ((long)blockIdx.x * 256 + threadIdx.x) * 4;  // over 1024*512
  float4 s0 = *(const float4*)(parts + i);
  float4 s1 = *(const float4*)(parts + 524288 + i);
  float4 s2 = *(const float4*)(parts + 1048576 + i);
  float4 s3 = *(const float4*)(parts + 1572864 + i);
  float4 r  = *(const float4*)(resid + i);
  float4 o;
  o.x = ((s0.x + s1.x) + (s2.x + s3.x)) + r.x;
  o.y = ((s0.y + s1.y) + (s2.y + s3.y)) + r.y;
  o.z = ((s0.z + s1.z) + (s2.z + s3.z)) + r.z;
  o.w = ((s0.w + s1.w) + (s2.w + s3.w)) + r.w;
  if (bias) {
    const int n = (int)(i & 511);
    float4 b = *(const float4*)(bias + n);
    o.x += b.x; o.y += b.y; o.z += b.z; o.w += b.w;
  }
  *(float4*)(dst + i) = o;
}

// ------------------------------ softmax-diff-L1, one wave per row ------------
__global__ void softmax_diff_kernel(const float* __restrict__ S1, const float* __restrict__ S2,
                                    const float* __restrict__ lamlog, f16* __restrict__ attn,
                                    int zofs) {
  const int rid = blockIdx.x * 4 + (threadIdx.x >> 6);
  const int lane = threadIdx.x & 63;
  const int z = rid >> 9, i = rid & 511;
  const float lam = 1.f / (1.f + __expf(-lamlog[(z + zofs) & 7]));
  const long base = (long)z * 262144 + (long)i * 512;
  const int c0 = lane * 4, c1 = 256 + lane * 4;
  float4 xa = *(const float4*)(S1 + base + c0);
  float4 xb = *(const float4*)(S1 + base + c1);
  float4 ya = *(const float4*)(S2 + base + c0);
  float4 yb = *(const float4*)(S2 + base + c1);
  float s1v[8] = {xa.x, xa.y, xa.z, xa.w, xb.x, xb.y, xb.z, xb.w};
  float s2v[8] = {ya.x, ya.y, ya.z, ya.w, yb.x, yb.y, yb.z, yb.w};
  int cols[8];
#pragma unroll
  for (int k = 0; k < 8; k++) cols[k] = (k < 4) ? (c0 + k) : (c1 + k - 4);
  float m1 = -3.0e38f, m2 = -3.0e38f;
#pragma unroll
  for (int k = 0; k < 8; k++)
    if (cols[k] <= i) { m1 = fmaxf(m1, s1v[k]); m2 = fmaxf(m2, s2v[k]); }
  m1 = wave_red_max64(m1);
  m2 = wave_red_max64(m2);
  float z1 = 0.f, z2 = 0.f, e1[8], e2[8];
#pragma unroll
  for (int k = 0; k < 8; k++) {
    const bool valid = cols[k] <= i;
    e1[k] = valid ? __expf(s1v[k] - m1) : 0.f;
    e2[k] = valid ? __expf(s2v[k] - m2) : 0.f;
    z1 += e1[k]; z2 += e2[k];
  }
  z1 = wave_red_sum64(z1);
  z2 = wave_red_sum64(z2);
  const float r1 = 1.f / z1, r2 = lam / z2;
  float p[8], l1 = 0.f;
#pragma unroll
  for (int k = 0; k < 8; k++) { p[k] = e1[k] * r1 - e2[k] * r2; l1 += fabsf(p[k]); }
  l1 = wave_red_sum64(l1);
  const float rn = 1.f / fmaxf(l1, 1e-6f);
  f16x4 o0 = {(f16)(p[0] * rn), (f16)(p[1] * rn), (f16)(p[2] * rn), (f16)(p[3] * rn)};
  f16x4 o1 = {(f16)(p[4] * rn), (f16)(p[5] * rn), (f16)(p[6] * rn), (f16)(p[7] * rn)};
  *(f16x4*)(attn + base + c0) = o0;
  *(f16x4*)(attn + base + c1) = o1;
}

// ---- inline-asm load + counted-wait primitives (vmcnt counts LOADS AND STORES) ----
#define ALD4(dst, p) asm volatile("global_load_dwordx4 %0, %1, off" : "=&v"(dst) : "v"(p) : "memory")
#define ALD1(dst, p) asm volatile("global_load_dword %0, %1, off" : "=&v"(dst) : "v"(p) : "memory")
#define VMWAIT(N)                                                             \
  {                                                                           \
    asm volatile("s_waitcnt vmcnt(" #N ")" ::: "memory");                     \
    __builtin_amdgcn_sched_barrier(0);                                        \
  }

// ------------------------------ eta precompute, 3 stages ---------------------
#define EISSUE(X)                                                             \
  {                                                                           \
    ALD1(X[0], pe);        ALD1(X[1], pe + 512);                              \
    ALD1(X[2], pe + 1024); ALD1(X[3], pe + 1536);                             \
    ALD1(X[4], pe + 2048); ALD1(X[5], pe + 2560);                             \
    ALD1(X[6], pe + 3072); ALD1(X[7], pe + 3584);                             \
    pe += 4096;                                                               \
  }
#define ESTEP(V, T)                                                           \
  {                                                                           \
    dp[(long)(T) * 512] = fabsf((V) - ema);                                   \
    ema = fmaf(0.95f, ema, 0.05f * (V));                                      \
  }

__launch_bounds__(64, 1) __global__
void eta_diff_kernel(const float* __restrict__ x2, float* __restrict__ diff) {
  const int blk = blockIdx.x;  // 16: b = blk>>3, col group = blk&7
  const int b = blk >> 3;
  const int col = (blk & 7) * 64 + threadIdx.x;
  const float* pe = x2 + (long)b * 262144 + col;
  float* dp = diff + (long)b * 262144 + col;
  float ema = 0.f;
  float EA[8], EB[8];
  EISSUE(EA);
  EISSUE(EB);
  VMWAIT(8);
#pragma unroll 1
  for (int t = 0; t < 512; t += 16) {
    ESTEP(EA[0], t + 0); ESTEP(EA[1], t + 1); ESTEP(EA[2], t + 2); ESTEP(EA[3], t + 3);
    ESTEP(EA[4], t + 4); ESTEP(EA[5], t + 5); ESTEP(EA[6], t + 6); ESTEP(EA[7], t + 7);
    EISSUE(EA);
    VMWAIT(16);
    ESTEP(EB[0], t + 8);  ESTEP(EB[1], t + 9);  ESTEP(EB[2], t + 10); ESTEP(EB[3], t + 11);
    ESTEP(EB[4], t + 12); ESTEP(EB[5], t + 13); ESTEP(EB[6], t + 14); ESTEP(EB[7], t + 15);
    EISSUE(EB);
    VMWAIT(16);
  }
  asm volatile("s_waitcnt vmcnt(0)" ::: "memory");
}

__global__ void eta_nov_kernel(const float* __restrict__ diff, float* __restrict__ nov) {
  const int row = blockIdx.x * 4 + (threadIdx.x >> 6);  // row = b*512+t
  const int lane = threadIdx.x & 63;
  const float* dp = diff + (long)row * 512 + lane * 4;
  float4 a0 = *(const float4*)dp;
  float4 a1 = *(const float4*)(dp + 256);
  float s = ((a0.x + a0.y) + (a0.z + a0.w)) + ((a1.x + a1.y) + (a1.z + a1.w));
  s = wave_red_sum64(s);
  if (lane == 0) nov[row] = s * (1.f / 512.f);
}

__global__ void eta_scan_kernel(const float* __restrict__ nov, const float* __restrict__ loglr,
                                float* __restrict__ eta) {
  if (threadIdx.x != 0) return;
  const int b = blockIdx.x;
  float ilr = expf(loglr[0]);
  ilr = fminf(fmaxf(ilr, 1e-5f), 1.f);
  float lrm = 1.f;
  const float* pb = nov + (long)b * 512;
#pragma unroll 8
  for (int t = 0; t < 512; t++) {
    const float ls = fminf(fmaxf(fmaf(3.f, pb[t], 1.f), 0.5f), 3.f);
    lrm = fmaf(0.95f, lrm, 0.05f * ls);
    eta[b * 512 + t] = ilr * lrm;
  }
}

// ------------------------------ TTT fast path (r6 dual-row + all-DPP reduce) -
// Exact per-step math (r6-proven); reduce = redsum64 (all-VALU DPP + readlane,
// no LDS-pipe ops on the serial chain). Norm check: per-lane max_t of local
// fw^2 sum, ONE reduce at end (conservative sum-of-max >= max-of-sum; spurious
// trigger -> exact fallback). vmcnt ledger: group = 17 loads; 4 float4 ys
// stores per 8 steps. Prologue 6 params+17+17 -> VMWAIT(17). Loop: phase A
// ISSUE -> WAIT(17) drains B; phase B + 4 stores + ISSUE -> queue
// [A'17][4st][B'17] -> WAIT(21) drains A' exactly.
DEVI float dot8(const f32x4 F0, const f32x4 F1, const f32x4 X0, const f32x4 X1) {
  float a0 = F0.x * X0.x, a1 = F0.y * X0.y, a2 = F0.z * X0.z, a3 = F0.w * X0.w;
  a0 = fmaf(F1.x, X1.x, a0); a1 = fmaf(F1.y, X1.y, a1);
  a2 = fmaf(F1.z, X1.z, a2); a3 = fmaf(F1.w, X1.w, a3);
  return (a0 + a1) + (a2 + a3);
}
DEVI void upd8(f32x4& M0, f32x4& M1, f32x4& F0, f32x4& F1, float c1, float e,
               const f32x4 X0, const f32x4 X1, float& ns) {
  M0.x = fmaf(0.9f, M0.x, c1 * X0.x); F0.x = fmaf(-e, M0.x, F0.x); ns = fmaf(F0.x, F0.x, ns);
  M0.y = fmaf(0.9f, M0.y, c1 * X0.y); F0.y = fmaf(-e, M0.y, F0.y); ns = fmaf(F0.y, F0.y, ns);
  M0.z = fmaf(0.9f, M0.z, c1 * X0.z); F0.z = fmaf(-e, M0.z, F0.z); ns = fmaf(F0.z, F0.z, ns);
  M0.w = fmaf(0.9f, M0.w, c1 * X0.w); F0.w = fmaf(-e, M0.w, F0.w); ns = fmaf(F0.w, F0.w, ns);
  M1.x = fmaf(0.9f, M1.x, c1 * X1.x); F1.x = fmaf(-e, M1.x, F1.x); ns = fmaf(F1.x, F1.x, ns);
  M1.y = fmaf(0.9f, M1.y, c1 * X1.y); F1.y = fmaf(-e, M1.y, F1.y); ns = fmaf(F1.y, F1.y, ns);
  M1.z = fmaf(0.9f, M1.z, c1 * X1.z); F1.z = fmaf(-e, M1.z, F1.z); ns = fmaf(F1.z, F1.z, ns);
  M1.w = fmaf(0.9f, M1.w, c1 * X1.w); F1.w = fmaf(-e, M1.w, F1.w); ns = fmaf(F1.w, F1.w, ns);
}

#define TISSUE2(X, RA, RB, ET)                                                \
  {                                                                           \
    ALD4(X[0], pxc);        ALD4(X[1], pxc + 4);                              \
    ALD4(X[2], pxc + 512);  ALD4(X[3], pxc + 516);                            \
    ALD4(X[4], pxc + 1024); ALD4(X[5], pxc + 1028);                           \
    ALD4(X[6], pxc + 1536); ALD4(X[7], pxc + 1540);                           \
    ALD1(RA[0], pxra);        ALD1(RA[1], pxra + 512);                        \
    ALD1(RA[2], pxra + 1024); ALD1(RA[3], pxra + 1536);                       \
    ALD1(RB[0], pxrb);        ALD1(RB[1], pxrb + 512);                        \
    ALD1(RB[2], pxrb + 1024); ALD1(RB[3], pxrb + 1536);                       \
    ALD4(ET, per);                                                            \
    pxc += 2048; pxra += 2048; pxrb += 2048; per += 4;                        \
  }

#define TSTEP2(X0v, X1v, rAv, rBv, ev, K)                                     \
  {                                                                           \
    const float pA_ = redsum64(dot8(fA0, fA1, X0v, X1v));                     \
    const float pB_ = redsum64(dot8(fB0, fB1, X0v, X1v));                     \
    const float yA_ = pA_ + biasA, yB_ = pB_ + biasB;                         \
    ysA[K] = yA_; ysB[K] = yB_;                                               \
    const float c1A_ = (yA_ - (rAv)) * (0.1f / 512.f);                        \
    const float c1B_ = (yB_ - (rBv)) * (0.1f / 512.f);                        \
    const float e_ = (ev);                                                    \
    float ns_ = 0.f;                                                          \
    upd8(mA0, mA1, fA0, fA1, c1A_, e_, X0v, X1v, ns_);                        \
    upd8(mB0, mB1, fB0, fB1, c1B_, e_, X0v, X1v, ns_);                        \
    nsmax = fmaxf(nsmax, ns_);                                                \
  }

__launch_bounds__(64, 1) __global__
void ttt_fast_kernel(const float* __restrict__ x2, const float* __restrict__ base_w,
                     const float* __restrict__ tbias, const float* __restrict__ eta,
                     float* __restrict__ yT, float* __restrict__ npB) {
  const int blk = blockIdx.x;   // 512
  const int b = blk >> 8;
  const int rA = blk & 255;     // row A; row B = rA + 256
  const int lane = threadIdx.x;
  const float* xb = x2 + (long)b * 262144;

  f32x4 fA0, fA1, fB0, fB1;
  float biasA, biasB;
  ALD4(fA0, base_w + (long)rA * 512 + lane * 8);
  ALD4(fA1, base_w + (long)rA * 512 + lane * 8 + 4);
  ALD4(fB0, base_w + (long)(rA + 256) * 512 + lane * 8);
  ALD4(fB1, base_w + (long)(rA + 256) * 512 + lane * 8 + 4);
  ALD1(biasA, tbias + rA);
  ALD1(biasB, tbias + rA + 256);

  f32x4 mA0 = {0.f, 0.f, 0.f, 0.f}, mA1 = mA0, mB0 = mA0, mB1 = mA0;
  float ysA[8], ysB[8];
  float nsmax = 0.f;

  const float* pxc = xb + lane * 8;
  const float* pxra = xb + rA;
  const float* pxrb = xb + rA + 256;
  const float* per = eta + b * 512;
  float* pyA = yT + (long)(b * 512 + rA) * 512;
  float* pyB = yT + (long)(b * 512 + rA + 256) * 512;

  f32x4 XA[8], XB[8], EA, EB;
  float RA0[4], RB0[4], RA1[4], RB1[4];
  TISSUE2(XA, RA0, RB0, EA);
  TISSUE2(XB, RA1, RB1, EB);
  VMWAIT(17);  // drains 6 param loads + group A's 17

#pragma unroll 1
  for (int T = 0; T < 512; T += 8) {
    TSTEP2(XA[0], XA[1], RA0[0], RB0[0], EA.x, 0);
    TSTEP2(XA[2], XA[3], RA0[1], RB0[1], EA.y, 1);
    TSTEP2(XA[4], XA[5], RA0[2], RB0[2], EA.z, 2);
    TSTEP2(XA[6], XA[7], RA0[3], RB0[3], EA.w, 3);
    TISSUE2(XA, RA0, RB0, EA);
    VMWAIT(17);  // drain group B (stores long retired)
    TSTEP2(XB[0], XB[1], RA1[0], RB1[0], EB.x, 4);
    TSTEP2(XB[2], XB[3], RA1[1], RB1[1], EB.y, 5);
    TSTEP2(XB[4], XB[5], RA1[2], RB1[2], EB.z, 6);
    TSTEP2(XB[6], XB[7], RA1[3], RB1[3], EB.w, 7);
    if (lane == 0) {
      *(float4*)(pyA + T)     = (float4){ysA[0], ysA[1], ysA[2], ysA[3]};
      *(float4*)(pyA + T + 4) = (float4){ysA[4], ysA[5], ysA[6], ysA[7]};
      *(float4*)(pyB + T)     = (float4){ysB[0], ysB[1], ysB[2], ysB[3]};
      *(float4*)(pyB + T + 4) = (float4){ysB[4], ysB[5], ysB[6], ysB[7]};
    }
    TISSUE2(XB, RA1, RB1, EB);
    VMWAIT(21);  // queue = [A'17][4st][B'17]; drain A' only
  }
  asm volatile("s_waitcnt vmcnt(0)" ::: "memory");
  const float tot = redsum64(nsmax);
  if (lane == 0) npB[blk] = tot;
}

// ------------------------------ 2-slice 512x512 f32 transpose ----------------
// yT[b][row][t] -> ysb[b][t][row]
__global__ void transpose2_kernel(const float* __restrict__ yT, float* __restrict__ ysb) {
  __shared__ float tile[64][65];
  const int s = blockIdx.z;
  const float* src = yT + (long)s * 262144;
  float* dst = ysb + (long)s * 262144;
  const int ti = blockIdx.y, tj = blockIdx.x;
  const int tr = threadIdx.x >> 4;
  const int tc = (threadIdx.x & 15) * 4;
#pragma unroll
  for (int p = 0; p < 4; p++) {
    const int r = tr + p * 16;
    float4 v = *(const float4*)(src + (long)(ti * 64 + r) * 512 + tj * 64 + tc);
    tile[r][tc] = v.x; tile[r][tc + 1] = v.y; tile[r][tc + 2] = v.z; tile[r][tc + 3] = v.w;
  }
  __syncthreads();
#pragma unroll
  for (int p = 0; p < 4; p++) {
    const int j = tr + p * 16;
    float4 v = {tile[tc][j], tile[tc + 1][j], tile[tc + 2][j], tile[tc + 3][j]};
    *(float4*)(dst + (long)(tj * 64 + j) * 512 + ti * 64 + tc) = v;
  }
}

// ------------------------------ verify: conservative norm check --------------
__global__ void verify_kernel(const float* __restrict__ npB, int* __restrict__ flag) {
  const int tid = threadIdx.x;  // 512, one per ttt block
  const int wave = tid >> 6, lane = tid & 63;
  float s = wave_red_sum64(npB[tid]);
  __shared__ float part[8];
  if (lane == 0) part[wave] = s;
  __syncthreads();
  if (tid == 0) {
    const float s0 = (part[0] + part[1]) + (part[2] + part[3]);  // batch 0 (blocks 0-255)
    const float s1 = (part[4] + part[5]) + (part[6] + part[7]);  // batch 1
    if (s0 > 1000.f || s1 > 1000.f) atomicOr(flag, 1);  // margin under 32^2=1024
  }
}

// ------------------------------ TTT fallback (exact, with clip) --------------
__launch_bounds__(1024, 1) __global__
void ttt_fallback_kernel(const int* __restrict__ flag, const float* __restrict__ x2,
                         const float* __restrict__ base_w, const float* __restrict__ tbias,
                         const float* __restrict__ eta, float* __restrict__ ys,
                         float* __restrict__ fwg, float* __restrict__ momg) {
  if (flag[0] == 0) return;
  const int b = blockIdx.x;
  const int tid = threadIdx.x;
  const int wave = tid >> 6, lane = tid & 63;
  float* fw = fwg + (long)b * 262144;
  float* mm = momg + (long)b * 262144;
  for (int e = tid; e < 262144; e += 1024) { fw[e] = base_w[e]; mm[e] = 0.f; }
  __shared__ float xs[512], errs[512], red[16];
  const float* xb = x2 + (long)b * 262144;
  for (int t = 0; t < 512; t++) {
    __syncthreads();
    if (tid < 512) xs[tid] = xb[t * 512 + tid];
    __syncthreads();
    if (tid < 512) {
      float acc = 0.f;
      for (int c = 0; c < 512; c++) acc = fmaf(fw[(long)tid * 512 + c], xs[c], acc);
      const float y = acc + tbias[tid];
      ys[((long)b * 512 + t) * 512 + tid] = y;
      errs[tid] = (y - xs[tid]) * (1.f / 512.f);
    }
    __syncthreads();
    const float eta_t = eta[b * 512 + t];
    float nsq = 0.f;
    for (int e = tid; e < 262144; e += 1024) {
      const int r = e >> 9, c = e & 511;
      const float m2 = fmaf(0.9f, mm[e], 0.1f * errs[r] * xs[c]);
      mm[e] = m2;
      const float f2 = fmaf(-eta_t, m2, fw[e]);
      fw[e] = f2;
      nsq = fmaf(f2, f2, nsq);
    }
    nsq = wave_red_sum64(nsq);
    if (lane == 0) red[wave] = nsq;
    __syncthreads();
    if (tid == 0) {
      float s = 0.f;
      for (int w = 0; w < 16; w++) s += red[w];
      red[0] = s;
    }
    __syncthreads();
    const float norm = fmaxf(sqrtf(red[0]), 1e-6f);
    const float sc = fminf(32.f / norm, 1.f);
    if (sc < 1.f)
      for (int e = tid; e < 262144; e += 1024) fw[e] *= sc;
  }
}

// ------------------------------ host launch ------------------------------
extern "C" void kernel_launch(void* const* d_in, const int* in_sizes, int n_in,
                              void* d_out, int out_size, void* d_ws, size_t ws_size,
                              hipStream_t stream) {
  (void)in_sizes; (void)n_in; (void)out_size;
  const float* x      = (const float*)d_in[0];
  const float* Wq     = (const float*)d_in[1];
  const float* Wk1    = (const float*)d_in[2];
  const float* Wk2    = (const float*)d_in[3];
  const float* Wv     = (const float*)d_in[4];
  const float* Wo     = (const float*)d_in[5];
  const float* lamlog = (const float*)d_in[6];
  const float* ln1g   = (const float*)d_in[7];
  const float* ln1b   = (const float*)d_in[8];
  const float* basew  = (const float*)d_in[9];
  const float* tttb   = (const float*)d_in[10];
  const float* loglr  = (const float*)d_in[11];
  const float* ln2g   = (const float*)d_in[12];
  const float* ln2b   = (const float*)d_in[13];
  const float* W1     = (const float*)d_in[14];
  const float* b1     = (const float*)d_in[15];
  const float* W2     = (const float*)d_in[16];
  const float* b2     = (const float*)d_in[17];
  const float* ln3g   = (const float*)d_in[18];
  const float* ln3b   = (const float*)d_in[19];
  float* out = (float*)d_out;

  char* ws = (char*)d_ws;
  size_t off = 0;
  auto alloc = [&](size_t bytes) {
    size_t o = off;
    off += (bytes + 255) & ~(size_t)255;
    return o;
  };
  f16* WqH   = (f16*)(ws + alloc(262144 * 2));
  f16* Wk1H  = (f16*)(ws + alloc(262144 * 2));
  f16* Wk2H  = (f16*)(ws + alloc(262144 * 2));
  f16* WvH   = (f16*)(ws + alloc(262144 * 2));
  f16* WoH   = (f16*)(ws + alloc(262144 * 2));
  f16* W1H   = (f16*)(ws + alloc(1048576 * 2));
  f16* W2H   = (f16*)(ws + alloc(1048576 * 2));
  (void)Wk1H; (void)Wk2H; (void)WvH; (void)W1H;
  f16* xlnH  = (f16*)(ws + alloc(524288 * 2));
  f16* qh    = (f16*)(ws + alloc(524288 * 2));
  f16* k1h   = (f16*)(ws + alloc(524288 * 2));
  f16* k2h   = (f16*)(ws + alloc(524288 * 2));
  f16* vTh   = (f16*)(ws + alloc(524288 * 2));
  (void)k2h;
  f16* obtd  = (f16*)(ws + alloc(524288 * 2));
  f16* x3h   = (f16*)(ws + alloc(524288 * 2));
  f16* zh    = (f16*)(ws + alloc(2097152 * 2));
  float* h1  = (float*)(ws + alloc(524288 * 4));
  float* x2  = (float*)(ws + alloc(524288 * 4));
  float* ysb = (float*)(ws + alloc(524288 * 4));
  float* h2  = (float*)(ws + alloc(524288 * 4));
  float* eta = (float*)(ws + alloc(1024 * 4));
  float* yT  = (float*)(ws + alloc(524288 * 4));  // ys transposed [b][row][t]
  float* npB = (float*)(ws + alloc(512 * 4));     // per-block conservative norm
  float* nvd = (float*)(ws + alloc(524288 * 4));  // eta diffs
  float* nov = (float*)(ws + alloc(1024 * 4));
  int* flag  = (int*)(ws + alloc(256));
  float* fwfb  = (float*)(ws + alloc(524288 * 4));
  float* momfb = (float*)(ws + alloc(524288 * 4));
  float* parts = (float*)(ws + alloc((size_t)4 * 524288 * 4));  // split-K partials (8MB)

  int hc = 16;
  while (hc > 1 && off + (size_t)hc * (262144ull * 4 * 2 + 262144ull * 2) > ws_size) hc >>= 1;
  float* S1  = (float*)(ws + alloc((size_t)hc * 262144 * 4));  // S2 = S1 + hc*262144
  float* S2  = (float*)(ws + alloc((size_t)hc * 262144 * 4));
  f16* attnb = (f16*)(ws + alloc((size_t)hc * 262144 * 2));
  (void)S2;

  // ---- all weight casts in one launch ----
  cvt_all_kernel<<<3328, 256, 0, stream>>>(Wq, Wk1, Wk2, Wv, Wo, W1, W2, WqH);

  // ---- LN1 -> xln (fp16) ----
  ln_kernel<<<256, 256, 0, stream>>>(x, nullptr, ln1g, ln1b, nullptr, nullptr, xlnH);

  // ---- q/k1/k2/vT in one launch (z selects weight + epilogue) ----
  gemm_bt<EPI_QKV><<<dim3(4, 8, 4), 256, 0, stream>>>(
      xlnH, WqH, 512, 512, 0, 262144, qh, nullptr, nullptr, 512, 1.f, 0, 0);

  // ---- attention ----
  const int nc = 16 / hc;
  for (int c = 0; c < nc; c++) {
    const int cs = c * hc;
    gemm_bt<EPI_SCORES><<<dim3(4, 4, 2 * hc), 256, 0, stream>>>(
        qh + (long)cs * 32768, k1h + (long)cs * 32768, 64, 64, 0, 0, S1,
        nullptr, nullptr, 64, 0.125f, 0, hc);
    softmax_diff_kernel<<<hc * 128, 256, 0, stream>>>(S1, S2, lamlog, attnb, cs);
    gemm_bt<EPI_PV><<<dim3(1, 4, hc), 256, 0, stream>>>(
        attnb, vTh + (long)cs * 32768, 512, 512, 262144, 32768, obtd,
        nullptr, nullptr, 512, 1.f, cs, 0);
  }

  // ---- Wo projection (split-K x4) + reduce w/ residual -> h1 ----
  gemm_bt<EPI_PART><<<dim3(4, 8, 4), 256, 0, stream>>>(
      obtd, WoH, 512, 512, 128, 128, parts, nullptr, nullptr, 128, 1.f, 0, 0);
  red4_kernel<<<512, 256, 0, stream>>>(parts, x, nullptr, h1);

  // ---- LN2 -> x2 (f32) ----
  ln_kernel<<<256, 256, 0, stream>>>(h1, nullptr, ln2g, ln2b, nullptr, x2, nullptr);

  // ---- TTT ----
  hipMemsetAsync(flag, 0, 4, stream);
  eta_diff_kernel<<<16, 64, 0, stream>>>(x2, nvd);
  eta_nov_kernel<<<256, 256, 0, stream>>>(nvd, nov);
  eta_scan_kernel<<<2, 64, 0, stream>>>(nov, loglr, eta);
  ttt_fast_kernel<<<512, 64, 0, stream>>>(x2, basew, tttb, eta, yT, npB);
  transpose2_kernel<<<dim3(8, 8, 2), 256, 0, stream>>>(yT, ysb);
  verify_kernel<<<1, 512, 0, stream>>>(npB, flag);
  ttt_fallback_kernel<<<2, 1024, 0, stream>>>(flag, x2, basew, tttb, eta, ysb, fwfb, momfb);

  // ---- h2 = h1 + ys ; LN3 -> x3 (fp16) ----
  ln_kernel<<<256, 256, 0, stream>>>(h1, ysb, ln3g, ln3b, h2, nullptr, x3h);

  // ---- FFN: GELU gemm; then W2 split-K x4 + reduce -> out ----
  gemm_bt<EPI_GELU><<<dim3(16, 8, 1), 256, 0, stream>>>(x3h, W1H, 512, 512, 0, 0, zh, b1, nullptr, 512, 1.f, 0, 0);
  gemm_bt<EPI_PART><<<dim3(4, 8, 4), 256, 0, stream>>>(
      zh, W2H, 2048, 2048, 512, 512, parts, nullptr, nullptr, 512, 1.f, 0, 0);
  red4_kernel<<<512, 256, 0, stream>>>(parts, h2, b2, out);
}

// Round 13
// 277.670 us; speedup vs baseline: 133.3145x; 1.0201x over previous
//
#include <hip/hip_runtime.h>
#include <hip/hip_fp16.h>

typedef _Float16 f16;
typedef f16 f16x4 __attribute__((ext_vector_type(4)));
typedef f16 f16x8 __attribute__((ext_vector_type(8)));
typedef float f32x4 __attribute__((ext_vector_type(4)));

#define DEVI static __device__ __forceinline__

DEVI void gload_lds16(const void* g, void* l) {
  __builtin_amdgcn_global_load_lds(
      (const __attribute__((address_space(1))) unsigned int*)g,
      (__attribute__((address_space(3))) unsigned int*)l, 16, 0, 0);
}

DEVI float wave_red_sum64(float v) {
#pragma unroll
  for (int m = 1; m < 64; m <<= 1) v += __shfl_xor(v, m, 64);
  return v;
}
DEVI float wave_red_max64(float v) {
#pragma unroll
  for (int m = 1; m < 64; m <<= 1) v = fmaxf(v, __shfl_xor(v, m, 64));
  return v;
}

// ---- all-DPP wave64 sum (r11-proven): 4 xor stages + ROW_BCAST15/31 + readlane ----
template <int CTRL>
DEVI float dpp_addf(float v) {
  int s = __builtin_amdgcn_update_dpp(0, __float_as_int(v), CTRL, 0xF, 0xF, true);
  return v + __int_as_float(s);
}
DEVI float redsum64(float v) {
  v = dpp_addf<0xB1>(v);   // xor1
  v = dpp_addf<0x4E>(v);   // xor2
  v = dpp_addf<0x141>(v);  // xor4 (row_half_mirror)
  v = dpp_addf<0x140>(v);  // xor8 (row_mirror)
  int t = __builtin_amdgcn_update_dpp(0, __float_as_int(v), 0x142, 0xA, 0xF, true);  // ROW_BCAST15
  v += __int_as_float(t);
  t = __builtin_amdgcn_update_dpp(0, __float_as_int(v), 0x143, 0xC, 0xF, true);      // ROW_BCAST31
  v += __int_as_float(t);
  return __int_as_float(__builtin_amdgcn_readlane(__float_as_int(v), 63));
}

// ------------------------------ fused f32 -> f16 cast of all 7 weights -------
__global__ void cvt_all_kernel(const float* __restrict__ s0, const float* __restrict__ s1,
                               const float* __restrict__ s2, const float* __restrict__ s3,
                               const float* __restrict__ s4, const float* __restrict__ s5,
                               const float* __restrict__ s6, f16* __restrict__ d) {
  const int blk = blockIdx.x;
  const float* s; long dofs; int local;
  if (blk < 256)       { s = s0; dofs = 0;       local = blk; }
  else if (blk < 512)  { s = s1; dofs = 262144;  local = blk - 256; }
  else if (blk < 768)  { s = s2; dofs = 524288;  local = blk - 512; }
  else if (blk < 1024) { s = s3; dofs = 786432;  local = blk - 768; }
  else if (blk < 1280) { s = s4; dofs = 1048576; local = blk - 1024; }
  else if (blk < 2304) { s = s5; dofs = 1310720; local = blk - 1280; }
  else                 { s = s6; dofs = 2359296; local = blk - 2304; }
  const long i = (long)local * 1024 + threadIdx.x * 4;
  float4 v = *(const float4*)(s + i);
  f16x4 o = {(f16)v.x, (f16)v.y, (f16)v.z, (f16)v.w};
  *(f16x4*)(d + dofs + i) = o;
}

// ------------------------------ LayerNorm D=512 ------------------------------
__global__ void ln_kernel(const float* __restrict__ in, const float* __restrict__ add,
                          const float* __restrict__ g, const float* __restrict__ b,
                          float* __restrict__ sumout, float* __restrict__ lnf,
                          f16* __restrict__ lnh) {
  const int row = blockIdx.x * 4 + (threadIdx.x >> 6);
  const int lane = threadIdx.x & 63;
  const long base = (long)row * 512;
  const int c0 = lane * 4, c1 = 256 + lane * 4;
  float4 a0 = *(const float4*)(in + base + c0);
  float4 a1 = *(const float4*)(in + base + c1);
  if (add) {
    float4 d0 = *(const float4*)(add + base + c0);
    float4 d1 = *(const float4*)(add + base + c1);
    a0.x += d0.x; a0.y += d0.y; a0.z += d0.z; a0.w += d0.w;
    a1.x += d1.x; a1.y += d1.y; a1.z += d1.z; a1.w += d1.w;
  }
  if (sumout) {
    *(float4*)(sumout + base + c0) = a0;
    *(float4*)(sumout + base + c1) = a1;
  }
  float v[8] = {a0.x, a0.y, a0.z, a0.w, a1.x, a1.y, a1.z, a1.w};
  float s = 0.f;
#pragma unroll
  for (int k = 0; k < 8; k++) s += v[k];
  s = wave_red_sum64(s);
  const float mean = s * (1.f / 512.f);
  float vs = 0.f;
#pragma unroll
  for (int k = 0; k < 8; k++) { float d = v[k] - mean; vs += d * d; }
  vs = wave_red_sum64(vs);
  const float rstd = rsqrtf(vs * (1.f / 512.f) + 1e-5f);
  float4 g0 = *(const float4*)(g + c0), g1 = *(const float4*)(g + c1);
  float4 p0 = *(const float4*)(b + c0), p1 = *(const float4*)(b + c1);
  const float gg[8] = {g0.x, g0.y, g0.z, g0.w, g1.x, g1.y, g1.z, g1.w};
  const float bv[8] = {p0.x, p0.y, p0.z, p0.w, p1.x, p1.y, p1.z, p1.w};
  float y[8];
#pragma unroll
  for (int k = 0; k < 8; k++) y[k] = (v[k] - mean) * rstd * gg[k] + bv[k];
  if (lnf) {
    float4 o0 = {y[0], y[1], y[2], y[3]}, o1 = {y[4], y[5], y[6], y[7]};
    *(float4*)(lnf + base + c0) = o0;
    *(float4*)(lnf + base + c1) = o1;
  }
  if (lnh) {
    f16x4 o0 = {(f16)y[0], (f16)y[1], (f16)y[2], (f16)y[3]};
    f16x4 o1 = {(f16)y[4], (f16)y[5], (f16)y[6], (f16)y[7]};
    *(f16x4*)(lnh + base + c0) = o0;
    *(f16x4*)(lnh + base + c1) = o1;
  }
}

// ---------- fused split-K reduce + residual + LayerNorm (WO path) ----------
// h1 = sum(parts[0..3]) + xres ; write h1 ; LN(h1) -> x2 (f32)
__global__ void red4ln_kernel(const float* __restrict__ parts, const float* __restrict__ xres,
                              const float* __restrict__ g, const float* __restrict__ b,
                              float* __restrict__ h1, float* __restrict__ x2out) {
  const int row = blockIdx.x * 4 + (threadIdx.x >> 6);
  const int lane = threadIdx.x & 63;
  const long base = (long)row * 512;
  const int c0 = lane * 4, c1 = 256 + lane * 4;
  float4 a0, a1;
  {
    float4 s0 = *(const float4*)(parts + base + c0);
    float4 s1 = *(const float4*)(parts + 524288 + base + c0);
    float4 s2 = *(const float4*)(parts + 1048576 + base + c0);
    float4 s3 = *(const float4*)(parts + 1572864 + base + c0);
    float4 r  = *(const float4*)(xres + base + c0);
    a0.x = ((s0.x + s1.x) + (s2.x + s3.x)) + r.x;
    a0.y = ((s0.y + s1.y) + (s2.y + s3.y)) + r.y;
    a0.z = ((s0.z + s1.z) + (s2.z + s3.z)) + r.z;
    a0.w = ((s0.w + s1.w) + (s2.w + s3.w)) + r.w;
  }
  {
    float4 s0 = *(const float4*)(parts + base + c1);
    float4 s1 = *(const float4*)(parts + 524288 + base + c1);
    float4 s2 = *(const float4*)(parts + 1048576 + base + c1);
    float4 s3 = *(const float4*)(parts + 1572864 + base + c1);
    float4 r  = *(const float4*)(xres + base + c1);
    a1.x = ((s0.x + s1.x) + (s2.x + s3.x)) + r.x;
    a1.y = ((s0.y + s1.y) + (s2.y + s3.y)) + r.y;
    a1.z = ((s0.z + s1.z) + (s2.z + s3.z)) + r.z;
    a1.w = ((s0.w + s1.w) + (s2.w + s3.w)) + r.w;
  }
  *(float4*)(h1 + base + c0) = a0;
  *(float4*)(h1 + base + c1) = a1;
  float v[8] = {a0.x, a0.y, a0.z, a0.w, a1.x, a1.y, a1.z, a1.w};
  float s = 0.f;
#pragma unroll
  for (int k = 0; k < 8; k++) s += v[k];
  s = wave_red_sum64(s);
  const float mean = s * (1.f / 512.f);
  float vs = 0.f;
#pragma unroll
  for (int k = 0; k < 8; k++) { float d = v[k] - mean; vs += d * d; }
  vs = wave_red_sum64(vs);
  const float rstd = rsqrtf(vs * (1.f / 512.f) + 1e-5f);
  float4 g0 = *(const float4*)(g + c0), g1 = *(const float4*)(g + c1);
  float4 p0 = *(const float4*)(b + c0), p1 = *(const float4*)(b + c1);
  const float gg[8] = {g0.x, g0.y, g0.z, g0.w, g1.x, g1.y, g1.z, g1.w};
  const float bv[8] = {p0.x, p0.y, p0.z, p0.w, p1.x, p1.y, p1.z, p1.w};
  float y[8];
#pragma unroll
  for (int k = 0; k < 8; k++) y[k] = (v[k] - mean) * rstd * gg[k] + bv[k];
  float4 o0 = {y[0], y[1], y[2], y[3]}, o1 = {y[4], y[5], y[6], y[7]};
  *(float4*)(x2out + base + c0) = o0;
  *(float4*)(x2out + base + c1) = o1;
}

// ------------------------------ generic fp16 MFMA GEMM, C = A(MxK) * W(NxK)^T
enum { EPI_QKV = 0, EPI_SCORES = 2, EPI_PV = 3, EPI_GELU = 5, EPI_PART = 7 };

template <int EPI>
__launch_bounds__(256, 1) __global__
void gemm_bt(const f16* __restrict__ A, const f16* __restrict__ W, int lda, int ldw,
             long Az, long Wz, void* __restrict__ dst, const float* __restrict__ bias,
             const float* __restrict__ resid, int K, float scale, int zofs, int hcp) {
  if (EPI == EPI_SCORES && blockIdx.x > blockIdx.y) return;  // causal tile skip
  __shared__ f16 lA[128 * 64];
  __shared__ f16 lB[128 * 64];
  const int tid = threadIdx.x;
  const int wave = tid >> 6, lane = tid & 63;
  const int z = blockIdx.z;
  const f16* Ab;
  const f16* Wb;
  if (EPI == EPI_SCORES) {
    const int v_ = (z >= hcp) ? 1 : 0, head = z - v_ * hcp;
    Ab = A + (long)head * 32768 + (long)blockIdx.y * 128 * lda;
    Wb = W + (long)v_ * 524288 + (long)head * 32768 + (long)blockIdx.x * 128 * ldw;
  } else {
    Ab = A + (long)z * Az + (long)blockIdx.y * 128 * lda;
    Wb = W + (long)z * Wz + (long)blockIdx.x * 128 * ldw;
  }

  f32x4 acc[4][4];
#pragma unroll
  for (int a = 0; a < 4; a++)
#pragma unroll
    for (int q = 0; q < 4; q++) acc[a][q] = (f32x4){0.f, 0.f, 0.f, 0.f};

  int srow[4], scol[4];
#pragma unroll
  for (int i = 0; i < 4; i++) {
    int c = i * 256 + tid;
    int row = c >> 3;
    int colb = (c & 7) << 4;
    srow[i] = row;
    scol[i] = (colb ^ ((row & 7) << 4)) >> 1;
  }

  for (int k0 = 0; k0 < K; k0 += 64) {
    __syncthreads();
#pragma unroll
    for (int i = 0; i < 4; i++) {
      const int le = (i * 256 + wave * 64) * 8;
      gload_lds16(Ab + (long)srow[i] * lda + k0 + scol[i], lA + le);
      gload_lds16(Wb + (long)srow[i] * ldw + k0 + scol[i], lB + le);
    }
    __syncthreads();
    const int wm = (wave >> 1) * 64, wn = (wave & 1) * 64;
#pragma unroll
    for (int km = 0; km < 2; km++) {
      const int kb = km * 64 + ((lane >> 4) << 4);
      f16x8 af[4], bfv[4];
#pragma unroll
      for (int mf = 0; mf < 4; mf++) {
        int r = wm + mf * 16 + (lane & 15);
        af[mf] = *(const f16x8*)((const char*)lA + r * 128 + (kb ^ ((r & 7) << 4)));
      }
#pragma unroll
      for (int nf = 0; nf < 4; nf++) {
        int r = wn + nf * 16 + (lane & 15);
        bfv[nf] = *(const f16x8*)((const char*)lB + r * 128 + (kb ^ ((r & 7) << 4)));
      }
#pragma unroll
      for (int mf = 0; mf < 4; mf++)
#pragma unroll
        for (int nf = 0; nf < 4; nf++)
          acc[mf][nf] = __builtin_amdgcn_mfma_f32_16x16x32_f16(af[mf], bfv[nf], acc[mf][nf], 0, 0, 0);
    }
  }

  const int wm = (wave >> 1) * 64, wn = (wave & 1) * 64;
  const int rbase = blockIdx.y * 128 + wm + ((lane >> 4) << 2);
  const int cbase = blockIdx.x * 128 + wn + (lane & 15);
#pragma unroll
  for (int mf = 0; mf < 4; mf++)
#pragma unroll
    for (int nf = 0; nf < 4; nf++)
#pragma unroll
      for (int j = 0; j < 4; j++) {
        const int m = rbase + mf * 16 + j;
        const int n = cbase + nf * 16;
        const float v = acc[mf][nf][j];
        if (EPI == EPI_QKV) {
          f16* d = (f16*)dst + (long)z * 524288;
          if (z < 3)
            d[(long)((m >> 9) * 8 + (n >> 6)) * 32768 + (m & 511) * 64 + (n & 63)] = (f16)v;
          else
            d[(long)((m >> 9) * 8 + (n >> 6)) * 32768 + (n & 63) * 512 + (m & 511)] = (f16)v;
        } else if (EPI == EPI_SCORES) {
          ((float*)dst)[(long)z * 262144 + (long)m * 512 + n] = v * scale;
        } else if (EPI == EPI_PV) {
          if (n < 64) {
            const int hh = z + zofs;
            ((f16*)dst)[(long)((hh >> 3) * 512 + m) * 512 + (hh & 7) * 64 + n] = (f16)v;
          }
        } else if (EPI == EPI_GELU) {
          const float u = v + bias[n];
          ((f16*)dst)[(long)m * 2048 + n] = (f16)(0.5f * u * (1.f + erff(u * 0.70710678118f)));
        } else {  // EPI_PART (N=512, M=1024)
          ((float*)dst)[(long)z * 524288 + (long)m * 512 + n] = v;
        }
      }
}

// ------------------------------ split-K reduce: 4 partials + resid (+bias) ---
__global__ void red4_kernel(const float* __restrict__ parts, const float* __restrict__ resid,
                            const float* __restrict__ bias, float* __restrict__ dst) {
  const long i = ((long)blockIdx.x * 256 + threadIdx.x) * 4;  // over 1024*512
  float4 s0 = *(const float4*)(parts + i);
  float4 s1 = *(const float4*)(parts + 524288 + i);
  float4 s2 = *(const float4*)(parts + 1048576 + i);
  float4 s3 = *(const float4*)(parts + 1572864 + i);
  float4 r  = *(const float4*)(resid + i);
  float4 o;
  o.x = ((s0.x + s1.x) + (s2.x + s3.x)) + r.x;
  o.y = ((s0.y + s1.y) + (s2.y + s3.y)) + r.y;
  o.z = ((s0.z + s1.z) + (s2.z + s3.z)) + r.z;
  o.w = ((s0.w + s1.w) + (s2.w + s3.w)) + r.w;
  if (bias) {
    const int n = (int)(i & 511);
    float4 b = *(const float4*)(bias + n);
    o.x += b.x; o.y += b.y; o.z += b.z; o.w += b.w;
  }
  *(float4*)(dst + i) = o;
}

// ------------------------------ softmax-diff-L1, one wave per row ------------
__global__ void softmax_diff_kernel(const float* __restrict__ S1, const float* __restrict__ S2,
                                    const float* __restrict__ lamlog, f16* __restrict__ attn,
                                    int zofs) {
  const int rid = blockIdx.x * 4 + (threadIdx.x >> 6);
  const int lane = threadIdx.x & 63;
  const int z = rid >> 9, i = rid & 511;
  const float lam = 1.f / (1.f + __expf(-lamlog[(z + zofs) & 7]));
  const long base = (long)z * 262144 + (long)i * 512;
  const int c0 = lane * 4, c1 = 256 + lane * 4;
  float4 xa = *(const float4*)(S1 + base + c0);
  float4 xb = *(const float4*)(S1 + base + c1);
  float4 ya = *(const float4*)(S2 + base + c0);
  float4 yb = *(const float4*)(S2 + base + c1);
  float s1v[8] = {xa.x, xa.y, xa.z, xa.w, xb.x, xb.y, xb.z, xb.w};
  float s2v[8] = {ya.x, ya.y, ya.z, ya.w, yb.x, yb.y, yb.z, yb.w};
  int cols[8];
#pragma unroll
  for (int k = 0; k < 8; k++) cols[k] = (k < 4) ? (c0 + k) : (c1 + k - 4);
  float m1 = -3.0e38f, m2 = -3.0e38f;
#pragma unroll
  for (int k = 0; k < 8; k++)
    if (cols[k] <= i) { m1 = fmaxf(m1, s1v[k]); m2 = fmaxf(m2, s2v[k]); }
  m1 = wave_red_max64(m1);
  m2 = wave_red_max64(m2);
  float z1 = 0.f, z2 = 0.f, e1[8], e2[8];
#pragma unroll
  for (int k = 0; k < 8; k++) {
    const bool valid = cols[k] <= i;
    e1[k] = valid ? __expf(s1v[k] - m1) : 0.f;
    e2[k] = valid ? __expf(s2v[k] - m2) : 0.f;
    z1 += e1[k]; z2 += e2[k];
  }
  z1 = wave_red_sum64(z1);
  z2 = wave_red_sum64(z2);
  const float r1 = 1.f / z1, r2 = lam / z2;
  float p[8], l1 = 0.f;
#pragma unroll
  for (int k = 0; k < 8; k++) { p[k] = e1[k] * r1 - e2[k] * r2; l1 += fabsf(p[k]); }
  l1 = wave_red_sum64(l1);
  const float rn = 1.f / fmaxf(l1, 1e-6f);
  f16x4 o0 = {(f16)(p[0] * rn), (f16)(p[1] * rn), (f16)(p[2] * rn), (f16)(p[3] * rn)};
  f16x4 o1 = {(f16)(p[4] * rn), (f16)(p[5] * rn), (f16)(p[6] * rn), (f16)(p[7] * rn)};
  *(f16x4*)(attn + base + c0) = o0;
  *(f16x4*)(attn + base + c1) = o1;
}

// ---- inline-asm load + counted-wait primitives (vmcnt counts LOADS AND STORES) ----
#define ALD4(dst, p) asm volatile("global_load_dwordx4 %0, %1, off" : "=&v"(dst) : "v"(p) : "memory")
#define ALD1(dst, p) asm volatile("global_load_dword %0, %1, off" : "=&v"(dst) : "v"(p) : "memory")
#define VMWAIT(N)                                                             \
  {                                                                           \
    asm volatile("s_waitcnt vmcnt(" #N ")" ::: "memory");                     \
    __builtin_amdgcn_sched_barrier(0);                                        \
  }

// ------------------------------ eta precompute, 3 stages ---------------------
#define EISSUE(X)                                                             \
  {                                                                           \
    ALD1(X[0], pe);        ALD1(X[1], pe + 512);                              \
    ALD1(X[2], pe + 1024); ALD1(X[3], pe + 1536);                             \
    ALD1(X[4], pe + 2048); ALD1(X[5], pe + 2560);                             \
    ALD1(X[6], pe + 3072); ALD1(X[7], pe + 3584);                             \
    pe += 4096;                                                               \
  }
#define ESTEP(V, T)                                                           \
  {                                                                           \
    dp[(long)(T) * 512] = fabsf((V) - ema);                                   \
    ema = fmaf(0.95f, ema, 0.05f * (V));                                      \
  }

__launch_bounds__(64, 1) __global__
void eta_diff_kernel(const float* __restrict__ x2, float* __restrict__ diff) {
  const int blk = blockIdx.x;  // 16: b = blk>>3, col group = blk&7
  const int b = blk >> 3;
  const int col = (blk & 7) * 64 + threadIdx.x;
  const float* pe = x2 + (long)b * 262144 + col;
  float* dp = diff + (long)b * 262144 + col;
  float ema = 0.f;
  float EA[8], EB[8];
  EISSUE(EA);
  EISSUE(EB);
  VMWAIT(8);
#pragma unroll 1
  for (int t = 0; t < 512; t += 16) {
    ESTEP(EA[0], t + 0); ESTEP(EA[1], t + 1); ESTEP(EA[2], t + 2); ESTEP(EA[3], t + 3);
    ESTEP(EA[4], t + 4); ESTEP(EA[5], t + 5); ESTEP(EA[6], t + 6); ESTEP(EA[7], t + 7);
    EISSUE(EA);
    VMWAIT(16);
    ESTEP(EB[0], t + 8);  ESTEP(EB[1], t + 9);  ESTEP(EB[2], t + 10); ESTEP(EB[3], t + 11);
    ESTEP(EB[4], t + 12); ESTEP(EB[5], t + 13); ESTEP(EB[6], t + 14); ESTEP(EB[7], t + 15);
    EISSUE(EB);
    VMWAIT(16);
  }
  asm volatile("s_waitcnt vmcnt(0)" ::: "memory");
}

// also zeroes the fallback flag (replaces a hipMemsetAsync dispatch)
__global__ void eta_nov_kernel(const float* __restrict__ diff, float* __restrict__ nov,
                               int* __restrict__ flag) {
  if (blockIdx.x == 0 && threadIdx.x == 0) flag[0] = 0;
  const int row = blockIdx.x * 4 + (threadIdx.x >> 6);  // row = b*512+t
  const int lane = threadIdx.x & 63;
  const float* dp = diff + (long)row * 512 + lane * 4;
  float4 a0 = *(const float4*)dp;
  float4 a1 = *(const float4*)(dp + 256);
  float s = ((a0.x + a0.y) + (a0.z + a0.w)) + ((a1.x + a1.y) + (a1.z + a1.w));
  s = wave_red_sum64(s);
  if (lane == 0) nov[row] = s * (1.f / 512.f);
}

__global__ void eta_scan_kernel(const float* __restrict__ nov, const float* __restrict__ loglr,
                                float* __restrict__ eta) {
  if (threadIdx.x != 0) return;
  const int b = blockIdx.x;
  float ilr = expf(loglr[0]);
  ilr = fminf(fmaxf(ilr, 1e-5f), 1.f);
  float lrm = 1.f;
  const float* pb = nov + (long)b * 512;
#pragma unroll 8
  for (int t = 0; t < 512; t++) {
    const float ls = fminf(fmaxf(fmaf(3.f, pb[t], 1.f), 0.5f), 3.f);
    lrm = fmaf(0.95f, lrm, 0.05f * ls);
    eta[b * 512 + t] = ilr * lrm;
  }
}

// ------------------------------ TTT fast path (r11-proven, EXACT) ------------
DEVI float dot8(const f32x4 F0, const f32x4 F1, const f32x4 X0, const f32x4 X1) {
  float a0 = F0.x * X0.x, a1 = F0.y * X0.y, a2 = F0.z * X0.z, a3 = F0.w * X0.w;
  a0 = fmaf(F1.x, X1.x, a0); a1 = fmaf(F1.y, X1.y, a1);
  a2 = fmaf(F1.z, X1.z, a2); a3 = fmaf(F1.w, X1.w, a3);
  return (a0 + a1) + (a2 + a3);
}
DEVI void upd8(f32x4& M0, f32x4& M1, f32x4& F0, f32x4& F1, float c1, float e,
               const f32x4 X0, const f32x4 X1, float& ns) {
  M0.x = fmaf(0.9f, M0.x, c1 * X0.x); F0.x = fmaf(-e, M0.x, F0.x); ns = fmaf(F0.x, F0.x, ns);
  M0.y = fmaf(0.9f, M0.y, c1 * X0.y); F0.y = fmaf(-e, M0.y, F0.y); ns = fmaf(F0.y, F0.y, ns);
  M0.z = fmaf(0.9f, M0.z, c1 * X0.z); F0.z = fmaf(-e, M0.z, F0.z); ns = fmaf(F0.z, F0.z, ns);
  M0.w = fmaf(0.9f, M0.w, c1 * X0.w); F0.w = fmaf(-e, M0.w, F0.w); ns = fmaf(F0.w, F0.w, ns);
  M1.x = fmaf(0.9f, M1.x, c1 * X1.x); F1.x = fmaf(-e, M1.x, F1.x); ns = fmaf(F1.x, F1.x, ns);
  M1.y = fmaf(0.9f, M1.y, c1 * X1.y); F1.y = fmaf(-e, M1.y, F1.y); ns = fmaf(F1.y, F1.y, ns);
  M1.z = fmaf(0.9f, M1.z, c1 * X1.z); F1.z = fmaf(-e, M1.z, F1.z); ns = fmaf(F1.z, F1.z, ns);
  M1.w = fmaf(0.9f, M1.w, c1 * X1.w); F1.w = fmaf(-e, M1.w, F1.w); ns = fmaf(F1.w, F1.w, ns);
}

#define TISSUE2(X, RA, RB, ET)                                                \
  {                                                                           \
    ALD4(X[0], pxc);        ALD4(X[1], pxc + 4);                              \
    ALD4(X[2], pxc + 512);  ALD4(X[3], pxc + 516);                            \
    ALD4(X[4], pxc + 1024); ALD4(X[5], pxc + 1028);                           \
    ALD4(X[6], pxc + 1536); ALD4(X[7], pxc + 1540);                           \
    ALD1(RA[0], pxra);        ALD1(RA[1], pxra + 512);                        \
    ALD1(RA[2], pxra + 1024); ALD1(RA[3], pxra + 1536);                       \
    ALD1(RB[0], pxrb);        ALD1(RB[1], pxrb + 512);                        \
    ALD1(RB[2], pxrb + 1024); ALD1(RB[3], pxrb + 1536);                       \
    ALD4(ET, per);                                                            \
    pxc += 2048; pxra += 2048; pxrb += 2048; per += 4;                        \
  }

#define TSTEP2(X0v, X1v, rAv, rBv, ev, K)                                     \
  {                                                                           \
    const float pA_ = redsum64(dot8(fA0, fA1, X0v, X1v));                     \
    const float pB_ = redsum64(dot8(fB0, fB1, X0v, X1v));                     \
    const float yA_ = pA_ + biasA, yB_ = pB_ + biasB;                         \
    ysA[K] = yA_; ysB[K] = yB_;                                               \
    const float c1A_ = (yA_ - (rAv)) * (0.1f / 512.f);                        \
    const float c1B_ = (yB_ - (rBv)) * (0.1f / 512.f);                        \
    const float e_ = (ev);                                                    \
    float ns_ = 0.f;                                                          \
    upd8(mA0, mA1, fA0, fA1, c1A_, e_, X0v, X1v, ns_);                        \
    upd8(mB0, mB1, fB0, fB1, c1B_, e_, X0v, X1v, ns_);                        \
    nsmax = fmaxf(nsmax, ns_);                                                \
  }

__launch_bounds__(64, 1) __global__
void ttt_fast_kernel(const float* __restrict__ x2, const float* __restrict__ base_w,
                     const float* __restrict__ tbias, const float* __restrict__ eta,
                     float* __restrict__ yT, float* __restrict__ npB) {
  const int blk = blockIdx.x;   // 512
  const int b = blk >> 8;
  const int rA = blk & 255;     // row A; row B = rA + 256
  const int lane = threadIdx.x;
  const float* xb = x2 + (long)b * 262144;

  f32x4 fA0, fA1, fB0, fB1;
  float biasA, biasB;
  ALD4(fA0, base_w + (long)rA * 512 + lane * 8);
  ALD4(fA1, base_w + (long)rA * 512 + lane * 8 + 4);
  ALD4(fB0, base_w + (long)(rA + 256) * 512 + lane * 8);
  ALD4(fB1, base_w + (long)(rA + 256) * 512 + lane * 8 + 4);
  ALD1(biasA, tbias + rA);
  ALD1(biasB, tbias + rA + 256);

  f32x4 mA0 = {0.f, 0.f, 0.f, 0.f}, mA1 = mA0, mB0 = mA0, mB1 = mA0;
  float ysA[8], ysB[8];
  float nsmax = 0.f;

  const float* pxc = xb + lane * 8;
  const float* pxra = xb + rA;
  const float* pxrb = xb + rA + 256;
  const float* per = eta + b * 512;
  float* pyA = yT + (long)(b * 512 + rA) * 512;
  float* pyB = yT + (long)(b * 512 + rA + 256) * 512;

  f32x4 XA[8], XB[8], EA, EB;
  float RA0[4], RB0[4], RA1[4], RB1[4];
  TISSUE2(XA, RA0, RB0, EA);
  TISSUE2(XB, RA1, RB1, EB);
  VMWAIT(17);  // drains 6 param loads + group A's 17

#pragma unroll 1
  for (int T = 0; T < 512; T += 8) {
    TSTEP2(XA[0], XA[1], RA0[0], RB0[0], EA.x, 0);
    TSTEP2(XA[2], XA[3], RA0[1], RB0[1], EA.y, 1);
    TSTEP2(XA[4], XA[5], RA0[2], RB0[2], EA.z, 2);
    TSTEP2(XA[6], XA[7], RA0[3], RB0[3], EA.w, 3);
    TISSUE2(XA, RA0, RB0, EA);
    VMWAIT(17);  // drain group B (stores long retired)
    TSTEP2(XB[0], XB[1], RA1[0], RB1[0], EB.x, 4);
    TSTEP2(XB[2], XB[3], RA1[1], RB1[1], EB.y, 5);
    TSTEP2(XB[4], XB[5], RA1[2], RB1[2], EB.z, 6);
    TSTEP2(XB[6], XB[7], RA1[3], RB1[3], EB.w, 7);
    if (lane == 0) {
      *(float4*)(pyA + T)     = (float4){ysA[0], ysA[1], ysA[2], ysA[3]};
      *(float4*)(pyA + T + 4) = (float4){ysA[4], ysA[5], ysA[6], ysA[7]};
      *(float4*)(pyB + T)     = (float4){ysB[0], ysB[1], ysB[2], ysB[3]};
      *(float4*)(pyB + T + 4) = (float4){ysB[4], ysB[5], ysB[6], ysB[7]};
    }
    TISSUE2(XB, RA1, RB1, EB);
    VMWAIT(21);  // queue = [A'17][4st][B'17]; drain A' only
  }
  asm volatile("s_waitcnt vmcnt(0)" ::: "memory");
  const float tot = redsum64(nsmax);
  if (lane == 0) npB[blk] = tot;
}

// -------- 2-slice 512x512 f32 transpose + fused conservative norm check -----
// z=0,1: yT[b][row][t] -> ysb[b][t][row]; z=2 (block (0,0) only): verify npB.
__global__ void transpose2v_kernel(const float* __restrict__ yT, float* __restrict__ ysb,
                                   const float* __restrict__ npB, int* __restrict__ flag) {
  const int s = blockIdx.z;
  if (s == 2) {
    if (blockIdx.x != 0 || blockIdx.y != 0) return;
    const int tid = threadIdx.x;  // 256
    const int wave = tid >> 6, lane = tid & 63;
    float a = npB[tid];        // batch 0: blocks 0..255
    float c = npB[tid + 256];  // batch 1: blocks 256..511
    a = wave_red_sum64(a);
    c = wave_red_sum64(c);
    __shared__ float pa[4], pc[4];
    if (lane == 0) { pa[wave] = a; pc[wave] = c; }
    __syncthreads();
    if (tid == 0) {
      const float s0 = (pa[0] + pa[1]) + (pa[2] + pa[3]);
      const float s1 = (pc[0] + pc[1]) + (pc[2] + pc[3]);
      if (s0 > 1000.f || s1 > 1000.f) atomicOr(flag, 1);  // margin under 32^2=1024
    }
    return;
  }
  __shared__ float tile[64][65];
  const float* src = yT + (long)s * 262144;
  float* dst = ysb + (long)s * 262144;
  const int ti = blockIdx.y, tj = blockIdx.x;
  const int tr = threadIdx.x >> 4;
  const int tc = (threadIdx.x & 15) * 4;
#pragma unroll
  for (int p = 0; p < 4; p++) {
    const int r = tr + p * 16;
    float4 v = *(const float4*)(src + (long)(ti * 64 + r) * 512 + tj * 64 + tc);
    tile[r][tc] = v.x; tile[r][tc + 1] = v.y; tile[r][tc + 2] = v.z; tile[r][tc + 3] = v.w;
  }
  __syncthreads();
#pragma unroll
  for (int p = 0; p < 4; p++) {
    const int j = tr + p * 16;
    float4 v = {tile[tc][j], tile[tc + 1][j], tile[tc + 2][j], tile[tc + 3][j]};
    *(float4*)(dst + (long)(tj * 64 + j) * 512 + ti * 64 + tc) = v;
  }
}

// ------------------------------ TTT fallback (exact, with clip) --------------
__launch_bounds__(1024, 1) __global__
void ttt_fallback_kernel(const int* __restrict__ flag, const float* __restrict__ x2,
                         const float* __restrict__ base_w, const float* __restrict__ tbias,
                         const float* __restrict__ eta, float* __restrict__ ys,
                         float* __restrict__ fwg, float* __restrict__ momg) {
  if (flag[0] == 0) return;
  const int b = blockIdx.x;
  const int tid = threadIdx.x;
  const int wave = tid >> 6, lane = tid & 63;
  float* fw = fwg + (long)b * 262144;
  float* mm = momg + (long)b * 262144;
  for (int e = tid; e < 262144; e += 1024) { fw[e] = base_w[e]; mm[e] = 0.f; }
  __shared__ float xs[512], errs[512], red[16];
  const float* xb = x2 + (long)b * 262144;
  for (int t = 0; t < 512; t++) {
    __syncthreads();
    if (tid < 512) xs[tid] = xb[t * 512 + tid];
    __syncthreads();
    if (tid < 512) {
      float acc = 0.f;
      for (int c = 0; c < 512; c++) acc = fmaf(fw[(long)tid * 512 + c], xs[c], acc);
      const float y = acc + tbias[tid];
      ys[((long)b * 512 + t) * 512 + tid] = y;
      errs[tid] = (y - xs[tid]) * (1.f / 512.f);
    }
    __syncthreads();
    const float eta_t = eta[b * 512 + t];
    float nsq = 0.f;
    for (int e = tid; e < 262144; e += 1024) {
      const int r = e >> 9, c = e & 511;
      const float m2 = fmaf(0.9f, mm[e], 0.1f * errs[r] * xs[c]);
      mm[e] = m2;
      const float f2 = fmaf(-eta_t, m2, fw[e]);
      fw[e] = f2;
      nsq = fmaf(f2, f2, nsq);
    }
    nsq = wave_red_sum64(nsq);
    if (lane == 0) red[wave] = nsq;
    __syncthreads();
    if (tid == 0) {
      float s = 0.f;
      for (int w = 0; w < 16; w++) s += red[w];
      red[0] = s;
    }
    __syncthreads();
    const float norm = fmaxf(sqrtf(red[0]), 1e-6f);
    const float sc = fminf(32.f / norm, 1.f);
    if (sc < 1.f)
      for (int e = tid; e < 262144; e += 1024) fw[e] *= sc;
  }
}

// ------------------------------ host launch ------------------------------
extern "C" void kernel_launch(void* const* d_in, const int* in_sizes, int n_in,
                              void* d_out, int out_size, void* d_ws, size_t ws_size,
                              hipStream_t stream) {
  (void)in_sizes; (void)n_in; (void)out_size;
  const float* x      = (const float*)d_in[0];
  const float* Wq     = (const float*)d_in[1];
  const float* Wk1    = (const float*)d_in[2];
  const float* Wk2    = (const float*)d_in[3];
  const float* Wv     = (const float*)d_in[4];
  const float* Wo     = (const float*)d_in[5];
  const float* lamlog = (const float*)d_in[6];
  const float* ln1g   = (const float*)d_in[7];
  const float* ln1b   = (const float*)d_in[8];
  const float* basew  = (const float*)d_in[9];
  const float* tttb   = (const float*)d_in[10];
  const float* loglr  = (const float*)d_in[11];
  const float* ln2g   = (const float*)d_in[12];
  const float* ln2b   = (const float*)d_in[13];
  const float* W1     = (const float*)d_in[14];
  const float* b1     = (const float*)d_in[15];
  const float* W2     = (const float*)d_in[16];
  const float* b2     = (const float*)d_in[17];
  const float* ln3g   = (const float*)d_in[18];
  const float* ln3b   = (const float*)d_in[19];
  float* out = (float*)d_out;

  char* ws = (char*)d_ws;
  size_t off = 0;
  auto alloc = [&](size_t bytes) {
    size_t o = off;
    off += (bytes + 255) & ~(size_t)255;
    return o;
  };
  f16* WqH   = (f16*)(ws + alloc(262144 * 2));
  f16* Wk1H  = (f16*)(ws + alloc(262144 * 2));
  f16* Wk2H  = (f16*)(ws + alloc(262144 * 2));
  f16* WvH   = (f16*)(ws + alloc(262144 * 2));
  f16* WoH   = (f16*)(ws + alloc(262144 * 2));
  f16* W1H   = (f16*)(ws + alloc(1048576 * 2));
  f16* W2H   = (f16*)(ws + alloc(1048576 * 2));
  (void)Wk1H; (void)Wk2H; (void)WvH; (void)W1H;
  f16* xlnH  = (f16*)(ws + alloc(524288 * 2));
  f16* qh    = (f16*)(ws + alloc(524288 * 2));
  f16* k1h   = (f16*)(ws + alloc(524288 * 2));
  f16* k2h   = (f16*)(ws + alloc(524288 * 2));
  f16* vTh   = (f16*)(ws + alloc(524288 * 2));
  (void)k2h;
  f16* obtd  = (f16*)(ws + alloc(524288 * 2));
  f16* x3h   = (f16*)(ws + alloc(524288 * 2));
  f16* zh    = (f16*)(ws + alloc(2097152 * 2));
  float* h1  = (float*)(ws + alloc(524288 * 4));
  float* x2  = (float*)(ws + alloc(524288 * 4));
  float* ysb = (float*)(ws + alloc(524288 * 4));  // ttt x-overread lands here (benign)
  float* h2  = (float*)(ws + alloc(524288 * 4));
  float* eta = (float*)(ws + alloc(1024 * 4));
  float* yT  = (float*)(ws + alloc(524288 * 4));  // ys transposed [b][row][t]
  float* npB = (float*)(ws + alloc(512 * 4));     // per-block conservative norm
  float* nvd = (float*)(ws + alloc(524288 * 4));  // eta diffs
  float* nov = (float*)(ws + alloc(1024 * 4));
  int* flag  = (int*)(ws + alloc(256));
  float* fwfb  = (float*)(ws + alloc(524288 * 4));
  float* momfb = (float*)(ws + alloc(524288 * 4));
  float* parts = (float*)(ws + alloc((size_t)4 * 524288 * 4));  // split-K partials (8MB)

  int hc = 16;
  while (hc > 1 && off + (size_t)hc * (262144ull * 4 * 2 + 262144ull * 2) > ws_size) hc >>= 1;
  float* S1  = (float*)(ws + alloc((size_t)hc * 262144 * 4));  // S2 = S1 + hc*262144
  float* S2  = (float*)(ws + alloc((size_t)hc * 262144 * 4));
  f16* attnb = (f16*)(ws + alloc((size_t)hc * 262144 * 2));
  (void)S2;

  // ---- all weight casts in one launch ----
  cvt_all_kernel<<<3328, 256, 0, stream>>>(Wq, Wk1, Wk2, Wv, Wo, W1, W2, WqH);

  // ---- LN1 -> xln (fp16) ----
  ln_kernel<<<256, 256, 0, stream>>>(x, nullptr, ln1g, ln1b, nullptr, nullptr, xlnH);

  // ---- q/k1/k2/vT in one launch ----
  gemm_bt<EPI_QKV><<<dim3(4, 8, 4), 256, 0, stream>>>(
      xlnH, WqH, 512, 512, 0, 262144, qh, nullptr, nullptr, 512, 1.f, 0, 0);

  // ---- attention ----
  const int nc = 16 / hc;
  for (int c = 0; c < nc; c++) {
    const int cs = c * hc;
    gemm_bt<EPI_SCORES><<<dim3(4, 4, 2 * hc), 256, 0, stream>>>(
        qh + (long)cs * 32768, k1h + (long)cs * 32768, 64, 64, 0, 0, S1,
        nullptr, nullptr, 64, 0.125f, 0, hc);
    softmax_diff_kernel<<<hc * 128, 256, 0, stream>>>(S1, S2, lamlog, attnb, cs);
    gemm_bt<EPI_PV><<<dim3(1, 4, hc), 256, 0, stream>>>(
        attnb, vTh + (long)cs * 32768, 512, 512, 262144, 32768, obtd,
        nullptr, nullptr, 512, 1.f, cs, 0);
  }

  // ---- Wo projection (split-K x4) + fused reduce+resid+LN2 -> h1, x2 ----
  gemm_bt<EPI_PART><<<dim3(4, 8, 4), 256, 0, stream>>>(
      obtd, WoH, 512, 512, 128, 128, parts, nullptr, nullptr, 128, 1.f, 0, 0);
  red4ln_kernel<<<256, 256, 0, stream>>>(parts, x, ln2g, ln2b, h1, x2);

  // ---- TTT (r11-proven cluster) ----
  eta_diff_kernel<<<16, 64, 0, stream>>>(x2, nvd);
  eta_nov_kernel<<<256, 256, 0, stream>>>(nvd, nov, flag);
  eta_scan_kernel<<<2, 64, 0, stream>>>(nov, loglr, eta);
  ttt_fast_kernel<<<512, 64, 0, stream>>>(x2, basew, tttb, eta, yT, npB);
  transpose2v_kernel<<<dim3(8, 8, 3), 256, 0, stream>>>(yT, ysb, npB, flag);
  ttt_fallback_kernel<<<2, 1024, 0, stream>>>(flag, x2, basew, tttb, eta, ysb, fwfb, momfb);

  // ---- h2 = h1 + ys ; LN3 -> x3 (fp16) ----
  ln_kernel<<<256, 256, 0, stream>>>(h1, ysb, ln3g, ln3b, h2, nullptr, x3h);

  // ---- FFN: GELU gemm; then W2 split-K x4 + reduce -> out ----
  gemm_bt<EPI_GELU><<<dim3(16, 8, 1), 256, 0, stream>>>(x3h, W1H, 512, 512, 0, 0, zh, b1, nullptr, 512, 1.f, 0, 0);
  gemm_bt<EPI_PART><<<dim3(4, 8, 4), 256, 0, stream>>>(
      zh, W2H, 2048, 2048, 512, 512, parts, nullptr, nullptr, 512, 1.f, 0, 0);
  red4_kernel<<<512, 256, 0, stream>>>(parts, h2, b2, out);
}

// Round 14
// 273.121 us; speedup vs baseline: 135.5347x; 1.0167x over previous
//
#include <hip/hip_runtime.h>
#include <hip/hip_fp16.h>

typedef _Float16 f16;
typedef f16 f16x4 __attribute__((ext_vector_type(4)));
typedef f16 f16x8 __attribute__((ext_vector_type(8)));
typedef float f32x4 __attribute__((ext_vector_type(4)));

#define DEVI static __device__ __forceinline__

DEVI void gload_lds16(const void* g, void* l) {
  __builtin_amdgcn_global_load_lds(
      (const __attribute__((address_space(1))) unsigned int*)g,
      (__attribute__((address_space(3))) unsigned int*)l, 16, 0, 0);
}

DEVI float wave_red_sum64(float v) {
#pragma unroll
  for (int m = 1; m < 64; m <<= 1) v += __shfl_xor(v, m, 64);
  return v;
}
DEVI float wave_red_max64(float v) {
#pragma unroll
  for (int m = 1; m < 64; m <<= 1) v = fmaxf(v, __shfl_xor(v, m, 64));
  return v;
}

// ---- all-DPP wave64 sum (r11-proven): 4 xor stages + ROW_BCAST15/31 + readlane ----
template <int CTRL>
DEVI float dpp_addf(float v) {
  int s = __builtin_amdgcn_update_dpp(0, __float_as_int(v), CTRL, 0xF, 0xF, true);
  return v + __int_as_float(s);
}
DEVI float redsum64(float v) {
  v = dpp_addf<0xB1>(v);   // xor1
  v = dpp_addf<0x4E>(v);   // xor2
  v = dpp_addf<0x141>(v);  // xor4 (row_half_mirror)
  v = dpp_addf<0x140>(v);  // xor8 (row_mirror)
  int t = __builtin_amdgcn_update_dpp(0, __float_as_int(v), 0x142, 0xA, 0xF, true);  // ROW_BCAST15
  v += __int_as_float(t);
  t = __builtin_amdgcn_update_dpp(0, __float_as_int(v), 0x143, 0xC, 0xF, true);      // ROW_BCAST31
  v += __int_as_float(t);
  return __int_as_float(__builtin_amdgcn_readlane(__float_as_int(v), 63));
}

// -------- fused f32 -> f16 cast of all 7 weights + LN1 (blocks 3328..3583) ---
__global__ void cvt_all_kernel(const float* __restrict__ s0, const float* __restrict__ s1,
                               const float* __restrict__ s2, const float* __restrict__ s3,
                               const float* __restrict__ s4, const float* __restrict__ s5,
                               const float* __restrict__ s6, f16* __restrict__ d,
                               const float* __restrict__ x, const float* __restrict__ ln1g,
                               const float* __restrict__ ln1b, f16* __restrict__ xlnH) {
  const int blk = blockIdx.x;
  if (blk >= 3328) {  // LN1 -> xlnH (f16)
    const int row = (blk - 3328) * 4 + ((int)threadIdx.x >> 6);
    const int lane = threadIdx.x & 63;
    const long base = (long)row * 512;
    const int c0 = lane * 4, c1 = 256 + lane * 4;
    float4 a0 = *(const float4*)(x + base + c0);
    float4 a1 = *(const float4*)(x + base + c1);
    float v[8] = {a0.x, a0.y, a0.z, a0.w, a1.x, a1.y, a1.z, a1.w};
    float s = 0.f;
#pragma unroll
    for (int k = 0; k < 8; k++) s += v[k];
    s = wave_red_sum64(s);
    const float mean = s * (1.f / 512.f);
    float vs = 0.f;
#pragma unroll
    for (int k = 0; k < 8; k++) { float dd = v[k] - mean; vs += dd * dd; }
    vs = wave_red_sum64(vs);
    const float rstd = rsqrtf(vs * (1.f / 512.f) + 1e-5f);
    float4 g0 = *(const float4*)(ln1g + c0), g1 = *(const float4*)(ln1g + c1);
    float4 p0 = *(const float4*)(ln1b + c0), p1 = *(const float4*)(ln1b + c1);
    const float gg[8] = {g0.x, g0.y, g0.z, g0.w, g1.x, g1.y, g1.z, g1.w};
    const float bv[8] = {p0.x, p0.y, p0.z, p0.w, p1.x, p1.y, p1.z, p1.w};
    float y[8];
#pragma unroll
    for (int k = 0; k < 8; k++) y[k] = (v[k] - mean) * rstd * gg[k] + bv[k];
    f16x4 o0 = {(f16)y[0], (f16)y[1], (f16)y[2], (f16)y[3]};
    f16x4 o1 = {(f16)y[4], (f16)y[5], (f16)y[6], (f16)y[7]};
    *(f16x4*)(xlnH + base + c0) = o0;
    *(f16x4*)(xlnH + base + c1) = o1;
    return;
  }
  const float* s; long dofs; int local;
  if (blk < 256)       { s = s0; dofs = 0;       local = blk; }
  else if (blk < 512)  { s = s1; dofs = 262144;  local = blk - 256; }
  else if (blk < 768)  { s = s2; dofs = 524288;  local = blk - 512; }
  else if (blk < 1024) { s = s3; dofs = 786432;  local = blk - 768; }
  else if (blk < 1280) { s = s4; dofs = 1048576; local = blk - 1024; }
  else if (blk < 2304) { s = s5; dofs = 1310720; local = blk - 1280; }
  else                 { s = s6; dofs = 2359296; local = blk - 2304; }
  const long i = (long)local * 1024 + threadIdx.x * 4;
  float4 v = *(const float4*)(s + i);
  f16x4 o = {(f16)v.x, (f16)v.y, (f16)v.z, (f16)v.w};
  *(f16x4*)(d + dofs + i) = o;
}

// ------------------------------ LayerNorm D=512 ------------------------------
__global__ void ln_kernel(const float* __restrict__ in, const float* __restrict__ add,
                          const float* __restrict__ g, const float* __restrict__ b,
                          float* __restrict__ sumout, float* __restrict__ lnf,
                          f16* __restrict__ lnh) {
  const int row = blockIdx.x * 4 + (threadIdx.x >> 6);
  const int lane = threadIdx.x & 63;
  const long base = (long)row * 512;
  const int c0 = lane * 4, c1 = 256 + lane * 4;
  float4 a0 = *(const float4*)(in + base + c0);
  float4 a1 = *(const float4*)(in + base + c1);
  if (add) {
    float4 d0 = *(const float4*)(add + base + c0);
    float4 d1 = *(const float4*)(add + base + c1);
    a0.x += d0.x; a0.y += d0.y; a0.z += d0.z; a0.w += d0.w;
    a1.x += d1.x; a1.y += d1.y; a1.z += d1.z; a1.w += d1.w;
  }
  if (sumout) {
    *(float4*)(sumout + base + c0) = a0;
    *(float4*)(sumout + base + c1) = a1;
  }
  float v[8] = {a0.x, a0.y, a0.z, a0.w, a1.x, a1.y, a1.z, a1.w};
  float s = 0.f;
#pragma unroll
  for (int k = 0; k < 8; k++) s += v[k];
  s = wave_red_sum64(s);
  const float mean = s * (1.f / 512.f);
  float vs = 0.f;
#pragma unroll
  for (int k = 0; k < 8; k++) { float d = v[k] - mean; vs += d * d; }
  vs = wave_red_sum64(vs);
  const float rstd = rsqrtf(vs * (1.f / 512.f) + 1e-5f);
  float4 g0 = *(const float4*)(g + c0), g1 = *(const float4*)(g + c1);
  float4 p0 = *(const float4*)(b + c0), p1 = *(const float4*)(b + c1);
  const float gg[8] = {g0.x, g0.y, g0.z, g0.w, g1.x, g1.y, g1.z, g1.w};
  const float bv[8] = {p0.x, p0.y, p0.z, p0.w, p1.x, p1.y, p1.z, p1.w};
  float y[8];
#pragma unroll
  for (int k = 0; k < 8; k++) y[k] = (v[k] - mean) * rstd * gg[k] + bv[k];
  if (lnf) {
    float4 o0 = {y[0], y[1], y[2], y[3]}, o1 = {y[4], y[5], y[6], y[7]};
    *(float4*)(lnf + base + c0) = o0;
    *(float4*)(lnf + base + c1) = o1;
  }
  if (lnh) {
    f16x4 o0 = {(f16)y[0], (f16)y[1], (f16)y[2], (f16)y[3]};
    f16x4 o1 = {(f16)y[4], (f16)y[5], (f16)y[6], (f16)y[7]};
    *(f16x4*)(lnh + base + c0) = o0;
    *(f16x4*)(lnh + base + c1) = o1;
  }
}

// ---------- fused split-K(8) reduce + residual + LayerNorm (WO path) ---------
__global__ void red8ln_kernel(const float* __restrict__ parts, const float* __restrict__ xres,
                              const float* __restrict__ g, const float* __restrict__ b,
                              float* __restrict__ h1, float* __restrict__ x2out) {
  const int row = blockIdx.x * 4 + (threadIdx.x >> 6);
  const int lane = threadIdx.x & 63;
  const long base = (long)row * 512;
  const int c0 = lane * 4, c1 = 256 + lane * 4;
  float4 a0, a1;
  {
    float4 r = *(const float4*)(xres + base + c0);
    float sx = r.x, sy = r.y, sz = r.z, sw = r.w;
#pragma unroll
    for (int sl = 0; sl < 8; sl++) {
      float4 p = *(const float4*)(parts + (long)sl * 524288 + base + c0);
      sx += p.x; sy += p.y; sz += p.z; sw += p.w;
    }
    a0 = (float4){sx, sy, sz, sw};
  }
  {
    float4 r = *(const float4*)(xres + base + c1);
    float sx = r.x, sy = r.y, sz = r.z, sw = r.w;
#pragma unroll
    for (int sl = 0; sl < 8; sl++) {
      float4 p = *(const float4*)(parts + (long)sl * 524288 + base + c1);
      sx += p.x; sy += p.y; sz += p.z; sw += p.w;
    }
    a1 = (float4){sx, sy, sz, sw};
  }
  *(float4*)(h1 + base + c0) = a0;
  *(float4*)(h1 + base + c1) = a1;
  float v[8] = {a0.x, a0.y, a0.z, a0.w, a1.x, a1.y, a1.z, a1.w};
  float s = 0.f;
#pragma unroll
  for (int k = 0; k < 8; k++) s += v[k];
  s = wave_red_sum64(s);
  const float mean = s * (1.f / 512.f);
  float vs = 0.f;
#pragma unroll
  for (int k = 0; k < 8; k++) { float d = v[k] - mean; vs += d * d; }
  vs = wave_red_sum64(vs);
  const float rstd = rsqrtf(vs * (1.f / 512.f) + 1e-5f);
  float4 g0 = *(const float4*)(g + c0), g1 = *(const float4*)(g + c1);
  float4 p0 = *(const float4*)(b + c0), p1 = *(const float4*)(b + c1);
  const float gg[8] = {g0.x, g0.y, g0.z, g0.w, g1.x, g1.y, g1.z, g1.w};
  const float bv[8] = {p0.x, p0.y, p0.z, p0.w, p1.x, p1.y, p1.z, p1.w};
  float y[8];
#pragma unroll
  for (int k = 0; k < 8; k++) y[k] = (v[k] - mean) * rstd * gg[k] + bv[k];
  float4 o0 = {y[0], y[1], y[2], y[3]}, o1 = {y[4], y[5], y[6], y[7]};
  *(float4*)(x2out + base + c0) = o0;
  *(float4*)(x2out + base + c1) = o1;
}

// ------------------------------ generic fp16 MFMA GEMM, C = A(MxK) * W(NxK)^T
// EPI_PART: z = K-slice (Az/Wz = per-z k-offset), f32 partials [z][m][512].
// EPI_QKVPART: z = ks*4+widx; partials [z][m][512]; A k-offset Az, W stride Wz.
// EPI_GPART: like PART but N=2048 partial stride.
enum { EPI_SCORES = 2, EPI_PV = 3, EPI_PART = 7, EPI_QKVPART = 8, EPI_GPART = 9 };

template <int EPI>
__launch_bounds__(256, 1) __global__
void gemm_bt(const f16* __restrict__ A, const f16* __restrict__ W, int lda, int ldw,
             long Az, long Wz, void* __restrict__ dst, const float* __restrict__ bias,
             const float* __restrict__ resid, int K, float scale, int zofs, int hcp) {
  if (EPI == EPI_SCORES && blockIdx.x > blockIdx.y) return;  // causal tile skip
  __shared__ f16 lA[128 * 64];
  __shared__ f16 lB[128 * 64];
  const int tid = threadIdx.x;
  const int wave = tid >> 6, lane = tid & 63;
  const int z = blockIdx.z;
  const f16* Ab;
  const f16* Wb;
  if (EPI == EPI_SCORES) {
    const int v_ = (z >= hcp) ? 1 : 0, head = z - v_ * hcp;
    Ab = A + (long)head * 32768 + (long)blockIdx.y * 128 * lda;
    Wb = W + (long)v_ * 524288 + (long)head * 32768 + (long)blockIdx.x * 128 * ldw;
  } else if (EPI == EPI_QKVPART) {
    const int widx = z & 3, ks = z >> 2;
    Ab = A + (long)blockIdx.y * 128 * lda + (long)ks * Az;
    Wb = W + (long)widx * Wz + (long)blockIdx.x * 128 * ldw + (long)ks * Az;
  } else {
    Ab = A + (long)z * Az + (long)blockIdx.y * 128 * lda;
    Wb = W + (long)z * Wz + (long)blockIdx.x * 128 * ldw;
  }

  f32x4 acc[4][4];
#pragma unroll
  for (int a = 0; a < 4; a++)
#pragma unroll
    for (int q = 0; q < 4; q++) acc[a][q] = (f32x4){0.f, 0.f, 0.f, 0.f};

  int srow[4], scol[4];
#pragma unroll
  for (int i = 0; i < 4; i++) {
    int c = i * 256 + tid;
    int row = c >> 3;
    int colb = (c & 7) << 4;
    srow[i] = row;
    scol[i] = (colb ^ ((row & 7) << 4)) >> 1;
  }

  for (int k0 = 0; k0 < K; k0 += 64) {
    __syncthreads();
#pragma unroll
    for (int i = 0; i < 4; i++) {
      const int le = (i * 256 + wave * 64) * 8;
      gload_lds16(Ab + (long)srow[i] * lda + k0 + scol[i], lA + le);
      gload_lds16(Wb + (long)srow[i] * ldw + k0 + scol[i], lB + le);
    }
    __syncthreads();
    const int wm = (wave >> 1) * 64, wn = (wave & 1) * 64;
#pragma unroll
    for (int km = 0; km < 2; km++) {
      const int kb = km * 64 + ((lane >> 4) << 4);
      f16x8 af[4], bfv[4];
#pragma unroll
      for (int mf = 0; mf < 4; mf++) {
        int r = wm + mf * 16 + (lane & 15);
        af[mf] = *(const f16x8*)((const char*)lA + r * 128 + (kb ^ ((r & 7) << 4)));
      }
#pragma unroll
      for (int nf = 0; nf < 4; nf++) {
        int r = wn + nf * 16 + (lane & 15);
        bfv[nf] = *(const f16x8*)((const char*)lB + r * 128 + (kb ^ ((r & 7) << 4)));
      }
#pragma unroll
      for (int mf = 0; mf < 4; mf++)
#pragma unroll
        for (int nf = 0; nf < 4; nf++)
          acc[mf][nf] = __builtin_amdgcn_mfma_f32_16x16x32_f16(af[mf], bfv[nf], acc[mf][nf], 0, 0, 0);
    }
  }

  const int wm = (wave >> 1) * 64, wn = (wave & 1) * 64;
  const int rbase = blockIdx.y * 128 + wm + ((lane >> 4) << 2);
  const int cbase = blockIdx.x * 128 + wn + (lane & 15);
#pragma unroll
  for (int mf = 0; mf < 4; mf++)
#pragma unroll
    for (int nf = 0; nf < 4; nf++)
#pragma unroll
      for (int j = 0; j < 4; j++) {
        const int m = rbase + mf * 16 + j;
        const int n = cbase + nf * 16;
        const float v = acc[mf][nf][j];
        if (EPI == EPI_SCORES) {
          ((float*)dst)[(long)z * 262144 + (long)m * 512 + n] = v * scale;
        } else if (EPI == EPI_PV) {
          if (n < 64) {
            const int hh = z + zofs;
            ((f16*)dst)[(long)((hh >> 3) * 512 + m) * 512 + (hh & 7) * 64 + n] = (f16)v;
          }
        } else if (EPI == EPI_GPART) {
          ((float*)dst)[(long)z * 2097152 + (long)m * 2048 + n] = v;
        } else {  // EPI_PART / EPI_QKVPART (N=512)
          ((float*)dst)[(long)z * 524288 + (long)m * 512 + n] = v;
        }
      }
}

// -------- QKV split-K(2) reduce + scatter to heads / vT layouts --------------
__global__ void qkv_red_kernel(const float* __restrict__ parts, f16* __restrict__ qkv) {
  const int idx = blockIdx.x * 256 + threadIdx.x;  // 524288 tasks (4 elems each)
  const int w = idx >> 17;        // weight 0..3
  const int r = idx & 131071;
  const int m = r >> 7;
  const int n4 = (r & 127) << 2;
  const float* p0 = parts + (long)w * 524288 + (long)m * 512 + n4;
  float4 a = *(const float4*)p0;
  float4 b = *(const float4*)(p0 + 4l * 524288);
  const float s0 = a.x + b.x, s1 = a.y + b.y, s2 = a.z + b.z, s3 = a.w + b.w;
  const int mb = (m >> 9) * 8 + (n4 >> 6);
  if (w < 3) {
    f16* d = qkv + (long)w * 524288;
    f16x4 o = {(f16)s0, (f16)s1, (f16)s2, (f16)s3};
    *(f16x4*)(d + (long)mb * 32768 + (m & 511) * 64 + (n4 & 63)) = o;
  } else {  // v transposed
    f16* d = qkv + 3l * 524288;
    const long bb = (long)mb * 32768 + (m & 511);
    d[bb + (long)(n4 & 63) * 512]       = (f16)s0;
    d[bb + (long)((n4 & 63) + 1) * 512] = (f16)s1;
    d[bb + (long)((n4 & 63) + 2) * 512] = (f16)s2;
    d[bb + (long)((n4 & 63) + 3) * 512] = (f16)s3;
  }
}

// -------- GELU split-K(2) reduce + bias + exact GELU -> f16 ------------------
__global__ void red2gelu_kernel(const float* __restrict__ parts, const float* __restrict__ bias,
                                f16* __restrict__ zh) {
  const long i = ((long)blockIdx.x * 256 + threadIdx.x) * 4;  // over 1024*2048
  float4 a = *(const float4*)(parts + i);
  float4 b = *(const float4*)(parts + 2097152 + i);
  const int n = (int)(i & 2047);
  float4 bb = *(const float4*)(bias + n);
  float u0 = a.x + b.x + bb.x, u1 = a.y + b.y + bb.y;
  float u2 = a.z + b.z + bb.z, u3 = a.w + b.w + bb.w;
  f16x4 o = {(f16)(0.5f * u0 * (1.f + erff(u0 * 0.70710678118f))),
             (f16)(0.5f * u1 * (1.f + erff(u1 * 0.70710678118f))),
             (f16)(0.5f * u2 * (1.f + erff(u2 * 0.70710678118f))),
             (f16)(0.5f * u3 * (1.f + erff(u3 * 0.70710678118f)))};
  *(f16x4*)(zh + i) = o;
}

// -------- split-K(8) reduce + resid + bias (OUT path) ------------------------
__global__ void red8_kernel(const float* __restrict__ parts, const float* __restrict__ resid,
                            const float* __restrict__ bias, float* __restrict__ dst) {
  const long i = ((long)blockIdx.x * 256 + threadIdx.x) * 4;  // over 1024*512
  float4 r = *(const float4*)(resid + i);
  float sx = r.x, sy = r.y, sz = r.z, sw = r.w;
#pragma unroll
  for (int sl = 0; sl < 8; sl++) {
    float4 p = *(const float4*)(parts + (long)sl * 524288 + i);
    sx += p.x; sy += p.y; sz += p.z; sw += p.w;
  }
  const int n = (int)(i & 511);
  float4 b = *(const float4*)(bias + n);
  float4 o = {sx + b.x, sy + b.y, sz + b.z, sw + b.w};
  *(float4*)(dst + i) = o;
}

// ------------------------------ softmax-diff-L1, one wave per row ------------
__global__ void softmax_diff_kernel(const float* __restrict__ S1, const float* __restrict__ S2,
                                    const float* __restrict__ lamlog, f16* __restrict__ attn,
                                    int zofs) {
  const int rid = blockIdx.x * 4 + (threadIdx.x >> 6);
  const int lane = threadIdx.x & 63;
  const int z = rid >> 9, i = rid & 511;
  const float lam = 1.f / (1.f + __expf(-lamlog[(z + zofs) & 7]));
  const long base = (long)z * 262144 + (long)i * 512;
  const int c0 = lane * 4, c1 = 256 + lane * 4;
  float4 xa = *(const float4*)(S1 + base + c0);
  float4 xb = *(const float4*)(S1 + base + c1);
  float4 ya = *(const float4*)(S2 + base + c0);
  float4 yb = *(const float4*)(S2 + base + c1);
  float s1v[8] = {xa.x, xa.y, xa.z, xa.w, xb.x, xb.y, xb.z, xb.w};
  float s2v[8] = {ya.x, ya.y, ya.z, ya.w, yb.x, yb.y, yb.z, yb.w};
  int cols[8];
#pragma unroll
  for (int k = 0; k < 8; k++) cols[k] = (k < 4) ? (c0 + k) : (c1 + k - 4);
  float m1 = -3.0e38f, m2 = -3.0e38f;
#pragma unroll
  for (int k = 0; k < 8; k++)
    if (cols[k] <= i) { m1 = fmaxf(m1, s1v[k]); m2 = fmaxf(m2, s2v[k]); }
  m1 = wave_red_max64(m1);
  m2 = wave_red_max64(m2);
  float z1 = 0.f, z2 = 0.f, e1[8], e2[8];
#pragma unroll
  for (int k = 0; k < 8; k++) {
    const bool valid = cols[k] <= i;
    e1[k] = valid ? __expf(s1v[k] - m1) : 0.f;
    e2[k] = valid ? __expf(s2v[k] - m2) : 0.f;
    z1 += e1[k]; z2 += e2[k];
  }
  z1 = wave_red_sum64(z1);
  z2 = wave_red_sum64(z2);
  const float r1 = 1.f / z1, r2 = lam / z2;
  float p[8], l1 = 0.f;
#pragma unroll
  for (int k = 0; k < 8; k++) { p[k] = e1[k] * r1 - e2[k] * r2; l1 += fabsf(p[k]); }
  l1 = wave_red_sum64(l1);
  const float rn = 1.f / fmaxf(l1, 1e-6f);
  f16x4 o0 = {(f16)(p[0] * rn), (f16)(p[1] * rn), (f16)(p[2] * rn), (f16)(p[3] * rn)};
  f16x4 o1 = {(f16)(p[4] * rn), (f16)(p[5] * rn), (f16)(p[6] * rn), (f16)(p[7] * rn)};
  *(f16x4*)(attn + base + c0) = o0;
  *(f16x4*)(attn + base + c1) = o1;
}

// ---- inline-asm load + counted-wait primitives (vmcnt counts LOADS AND STORES) ----
#define ALD4(dst, p) asm volatile("global_load_dwordx4 %0, %1, off" : "=&v"(dst) : "v"(p) : "memory")
#define ALD1(dst, p) asm volatile("global_load_dword %0, %1, off" : "=&v"(dst) : "v"(p) : "memory")
#define VMWAIT(N)                                                             \
  {                                                                           \
    asm volatile("s_waitcnt vmcnt(" #N ")" ::: "memory");                     \
    __builtin_amdgcn_sched_barrier(0);                                        \
  }

// ------------------------------ eta precompute, 3 stages ---------------------
#define EISSUE(X)                                                             \
  {                                                                           \
    ALD1(X[0], pe);        ALD1(X[1], pe + 512);                              \
    ALD1(X[2], pe + 1024); ALD1(X[3], pe + 1536);                             \
    ALD1(X[4], pe + 2048); ALD1(X[5], pe + 2560);                             \
    ALD1(X[6], pe + 3072); ALD1(X[7], pe + 3584);                             \
    pe += 4096;                                                               \
  }
#define ESTEP(V, T)                                                           \
  {                                                                           \
    dp[(long)(T) * 512] = fabsf((V) - ema);                                   \
    ema = fmaf(0.95f, ema, 0.05f * (V));                                      \
  }

__launch_bounds__(64, 1) __global__
void eta_diff_kernel(const float* __restrict__ x2, float* __restrict__ diff) {
  const int blk = blockIdx.x;  // 16: b = blk>>3, col group = blk&7
  const int b = blk >> 3;
  const int col = (blk & 7) * 64 + threadIdx.x;
  const float* pe = x2 + (long)b * 262144 + col;
  float* dp = diff + (long)b * 262144 + col;
  float ema = 0.f;
  float EA[8], EB[8];
  EISSUE(EA);
  EISSUE(EB);
  VMWAIT(8);
#pragma unroll 1
  for (int t = 0; t < 512; t += 16) {
    ESTEP(EA[0], t + 0); ESTEP(EA[1], t + 1); ESTEP(EA[2], t + 2); ESTEP(EA[3], t + 3);
    ESTEP(EA[4], t + 4); ESTEP(EA[5], t + 5); ESTEP(EA[6], t + 6); ESTEP(EA[7], t + 7);
    EISSUE(EA);
    VMWAIT(16);
    ESTEP(EB[0], t + 8);  ESTEP(EB[1], t + 9);  ESTEP(EB[2], t + 10); ESTEP(EB[3], t + 11);
    ESTEP(EB[4], t + 12); ESTEP(EB[5], t + 13); ESTEP(EB[6], t + 14); ESTEP(EB[7], t + 15);
    EISSUE(EB);
    VMWAIT(16);
  }
  asm volatile("s_waitcnt vmcnt(0)" ::: "memory");
}

// also zeroes the fallback flag (replaces a hipMemsetAsync dispatch)
__global__ void eta_nov_kernel(const float* __restrict__ diff, float* __restrict__ nov,
                               int* __restrict__ flag) {
  if (blockIdx.x == 0 && threadIdx.x == 0) flag[0] = 0;
  const int row = blockIdx.x * 4 + (threadIdx.x >> 6);  // row = b*512+t
  const int lane = threadIdx.x & 63;
  const float* dp = diff + (long)row * 512 + lane * 4;
  float4 a0 = *(const float4*)dp;
  float4 a1 = *(const float4*)(dp + 256);
  float s = ((a0.x + a0.y) + (a0.z + a0.w)) + ((a1.x + a1.y) + (a1.z + a1.w));
  s = wave_red_sum64(s);
  if (lane == 0) nov[row] = s * (1.f / 512.f);
}

__global__ void eta_scan_kernel(const float* __restrict__ nov, const float* __restrict__ loglr,
                                float* __restrict__ eta) {
  if (threadIdx.x != 0) return;
  const int b = blockIdx.x;
  float ilr = expf(loglr[0]);
  ilr = fminf(fmaxf(ilr, 1e-5f), 1.f);
  float lrm = 1.f;
  const float* pb = nov + (long)b * 512;
#pragma unroll 8
  for (int t = 0; t < 512; t++) {
    const float ls = fminf(fmaxf(fmaf(3.f, pb[t], 1.f), 0.5f), 3.f);
    lrm = fmaf(0.95f, lrm, 0.05f * ls);
    eta[b * 512 + t] = ilr * lrm;
  }
}

// ------------------------------ TTT fast path (r11-proven, EXACT) ------------
DEVI float dot8(const f32x4 F0, const f32x4 F1, const f32x4 X0, const f32x4 X1) {
  float a0 = F0.x * X0.x, a1 = F0.y * X0.y, a2 = F0.z * X0.z, a3 = F0.w * X0.w;
  a0 = fmaf(F1.x, X1.x, a0); a1 = fmaf(F1.y, X1.y, a1);
  a2 = fmaf(F1.z, X1.z, a2); a3 = fmaf(F1.w, X1.w, a3);
  return (a0 + a1) + (a2 + a3);
}
DEVI void upd8(f32x4& M0, f32x4& M1, f32x4& F0, f32x4& F1, float c1, float e,
               const f32x4 X0, const f32x4 X1, float& ns) {
  M0.x = fmaf(0.9f, M0.x, c1 * X0.x); F0.x = fmaf(-e, M0.x, F0.x); ns = fmaf(F0.x, F0.x, ns);
  M0.y = fmaf(0.9f, M0.y, c1 * X0.y); F0.y = fmaf(-e, M0.y, F0.y); ns = fmaf(F0.y, F0.y, ns);
  M0.z = fmaf(0.9f, M0.z, c1 * X0.z); F0.z = fmaf(-e, M0.z, F0.z); ns = fmaf(F0.z, F0.z, ns);
  M0.w = fmaf(0.9f, M0.w, c1 * X0.w); F0.w = fmaf(-e, M0.w, F0.w); ns = fmaf(F0.w, F0.w, ns);
  M1.x = fmaf(0.9f, M1.x, c1 * X1.x); F1.x = fmaf(-e, M1.x, F1.x); ns = fmaf(F1.x, F1.x, ns);
  M1.y = fmaf(0.9f, M1.y, c1 * X1.y); F1.y = fmaf(-e, M1.y, F1.y); ns = fmaf(F1.y, F1.y, ns);
  M1.z = fmaf(0.9f, M1.z, c1 * X1.z); F1.z = fmaf(-e, M1.z, F1.z); ns = fmaf(F1.z, F1.z, ns);
  M1.w = fmaf(0.9f, M1.w, c1 * X1.w); F1.w = fmaf(-e, M1.w, F1.w); ns = fmaf(F1.w, F1.w, ns);
}

#define TISSUE2(X, RA, RB, ET)                                                \
  {                                                                           \
    ALD4(X[0], pxc);        ALD4(X[1], pxc + 4);                              \
    ALD4(X[2], pxc + 512);  ALD4(X[3], pxc + 516);                            \
    ALD4(X[4], pxc + 1024); ALD4(X[5], pxc + 1028);                           \
    ALD4(X[6], pxc + 1536); ALD4(X[7], pxc + 1540);                           \
    ALD1(RA[0], pxra);        ALD1(RA[1], pxra + 512);                        \
    ALD1(RA[2], pxra + 1024); ALD1(RA[3], pxra + 1536);                       \
    ALD1(RB[0], pxrb);        ALD1(RB[1], pxrb + 512);                        \
    ALD1(RB[2], pxrb + 1024); ALD1(RB[3], pxrb + 1536);                       \
    ALD4(ET, per);                                                            \
    pxc += 2048; pxra += 2048; pxrb += 2048; per += 4;                        \
  }

#define TSTEP2(X0v, X1v, rAv, rBv, ev, K)                                     \
  {                                                                           \
    const float pA_ = redsum64(dot8(fA0, fA1, X0v, X1v));                     \
    const float pB_ = redsum64(dot8(fB0, fB1, X0v, X1v));                     \
    const float yA_ = pA_ + biasA, yB_ = pB_ + biasB;                         \
    ysA[K] = yA_; ysB[K] = yB_;                                               \
    const float c1A_ = (yA_ - (rAv)) * (0.1f / 512.f);                        \
    const float c1B_ = (yB_ - (rBv)) * (0.1f / 512.f);                        \
    const float e_ = (ev);                                                    \
    float ns_ = 0.f;                                                          \
    upd8(mA0, mA1, fA0, fA1, c1A_, e_, X0v, X1v, ns_);                        \
    upd8(mB0, mB1, fB0, fB1, c1B_, e_, X0v, X1v, ns_);                        \
    nsmax = fmaxf(nsmax, ns_);                                                \
  }

__launch_bounds__(64, 1) __global__
void ttt_fast_kernel(const float* __restrict__ x2, const float* __restrict__ base_w,
                     const float* __restrict__ tbias, const float* __restrict__ eta,
                     float* __restrict__ yT, float* __restrict__ npB) {
  const int blk = blockIdx.x;   // 512
  const int b = blk >> 8;
  const int rA = blk & 255;     // row A; row B = rA + 256
  const int lane = threadIdx.x;
  const float* xb = x2 + (long)b * 262144;

  f32x4 fA0, fA1, fB0, fB1;
  float biasA, biasB;
  ALD4(fA0, base_w + (long)rA * 512 + lane * 8);
  ALD4(fA1, base_w + (long)rA * 512 + lane * 8 + 4);
  ALD4(fB0, base_w + (long)(rA + 256) * 512 + lane * 8);
  ALD4(fB1, base_w + (long)(rA + 256) * 512 + lane * 8 + 4);
  ALD1(biasA, tbias + rA);
  ALD1(biasB, tbias + rA + 256);

  f32x4 mA0 = {0.f, 0.f, 0.f, 0.f}, mA1 = mA0, mB0 = mA0, mB1 = mA0;
  float ysA[8], ysB[8];
  float nsmax = 0.f;

  const float* pxc = xb + lane * 8;
  const float* pxra = xb + rA;
  const float* pxrb = xb + rA + 256;
  const float* per = eta + b * 512;
  float* pyA = yT + (long)(b * 512 + rA) * 512;
  float* pyB = yT + (long)(b * 512 + rA + 256) * 512;

  f32x4 XA[8], XB[8], EA, EB;
  float RA0[4], RB0[4], RA1[4], RB1[4];
  TISSUE2(XA, RA0, RB0, EA);
  TISSUE2(XB, RA1, RB1, EB);
  VMWAIT(17);  // drains 6 param loads + group A's 17

#pragma unroll 1
  for (int T = 0; T < 512; T += 8) {
    TSTEP2(XA[0], XA[1], RA0[0], RB0[0], EA.x, 0);
    TSTEP2(XA[2], XA[3], RA0[1], RB0[1], EA.y, 1);
    TSTEP2(XA[4], XA[5], RA0[2], RB0[2], EA.z, 2);
    TSTEP2(XA[6], XA[7], RA0[3], RB0[3], EA.w, 3);
    TISSUE2(XA, RA0, RB0, EA);
    VMWAIT(17);  // drain group B (stores long retired)
    TSTEP2(XB[0], XB[1], RA1[0], RB1[0], EB.x, 4);
    TSTEP2(XB[2], XB[3], RA1[1], RB1[1], EB.y, 5);
    TSTEP2(XB[4], XB[5], RA1[2], RB1[2], EB.z, 6);
    TSTEP2(XB[6], XB[7], RA1[3], RB1[3], EB.w, 7);
    if (lane == 0) {
      *(float4*)(pyA + T)     = (float4){ysA[0], ysA[1], ysA[2], ysA[3]};
      *(float4*)(pyA + T + 4) = (float4){ysA[4], ysA[5], ysA[6], ysA[7]};
      *(float4*)(pyB + T)     = (float4){ysB[0], ysB[1], ysB[2], ysB[3]};
      *(float4*)(pyB + T + 4) = (float4){ysB[4], ysB[5], ysB[6], ysB[7]};
    }
    TISSUE2(XB, RA1, RB1, EB);
    VMWAIT(21);  // queue = [A'17][4st][B'17]; drain A' only
  }
  asm volatile("s_waitcnt vmcnt(0)" ::: "memory");
  const float tot = redsum64(nsmax);
  if (lane == 0) npB[blk] = tot;
}

// -------- 2-slice 512x512 f32 transpose + fused conservative norm check -----
__global__ void transpose2v_kernel(const float* __restrict__ yT, float* __restrict__ ysb,
                                   const float* __restrict__ npB, int* __restrict__ flag) {
  const int s = blockIdx.z;
  if (s == 2) {
    if (blockIdx.x != 0 || blockIdx.y != 0) return;
    const int tid = threadIdx.x;  // 256
    const int wave = tid >> 6, lane = tid & 63;
    float a = npB[tid];        // batch 0: blocks 0..255
    float c = npB[tid + 256];  // batch 1
    a = wave_red_sum64(a);
    c = wave_red_sum64(c);
    __shared__ float pa[4], pc[4];
    if (lane == 0) { pa[wave] = a; pc[wave] = c; }
    __syncthreads();
    if (tid == 0) {
      const float s0 = (pa[0] + pa[1]) + (pa[2] + pa[3]);
      const float s1 = (pc[0] + pc[1]) + (pc[2] + pc[3]);
      if (s0 > 1000.f || s1 > 1000.f) atomicOr(flag, 1);  // margin under 32^2=1024
    }
    return;
  }
  __shared__ float tile[64][65];
  const float* src = yT + (long)s * 262144;
  float* dst = ysb + (long)s * 262144;
  const int ti = blockIdx.y, tj = blockIdx.x;
  const int tr = threadIdx.x >> 4;
  const int tc = (threadIdx.x & 15) * 4;
#pragma unroll
  for (int p = 0; p < 4; p++) {
    const int r = tr + p * 16;
    float4 v = *(const float4*)(src + (long)(ti * 64 + r) * 512 + tj * 64 + tc);
    tile[r][tc] = v.x; tile[r][tc + 1] = v.y; tile[r][tc + 2] = v.z; tile[r][tc + 3] = v.w;
  }
  __syncthreads();
#pragma unroll
  for (int p = 0; p < 4; p++) {
    const int j = tr + p * 16;
    float4 v = {tile[tc][j], tile[tc + 1][j], tile[tc + 2][j], tile[tc + 3][j]};
    *(float4*)(dst + (long)(tj * 64 + j) * 512 + ti * 64 + tc) = v;
  }
}

// ------------------------------ TTT fallback (exact, with clip) --------------
__launch_bounds__(1024, 1) __global__
void ttt_fallback_kernel(const int* __restrict__ flag, const float* __restrict__ x2,
                         const float* __restrict__ base_w, const float* __restrict__ tbias,
                         const float* __restrict__ eta, float* __restrict__ ys,
                         float* __restrict__ fwg, float* __restrict__ momg) {
  if (flag[0] == 0) return;
  const int b = blockIdx.x;
  const int tid = threadIdx.x;
  const int wave = tid >> 6, lane = tid & 63;
  float* fw = fwg + (long)b * 262144;
  float* mm = momg + (long)b * 262144;
  for (int e = tid; e < 262144; e += 1024) { fw[e] = base_w[e]; mm[e] = 0.f; }
  __shared__ float xs[512], errs[512], red[16];
  const float* xb = x2 + (long)b * 262144;
  for (int t = 0; t < 512; t++) {
    __syncthreads();
    if (tid < 512) xs[tid] = xb[t * 512 + tid];
    __syncthreads();
    if (tid < 512) {
      float acc = 0.f;
      for (int c = 0; c < 512; c++) acc = fmaf(fw[(long)tid * 512 + c], xs[c], acc);
      const float y = acc + tbias[tid];
      ys[((long)b * 512 + t) * 512 + tid] = y;
      errs[tid] = (y - xs[tid]) * (1.f / 512.f);
    }
    __syncthreads();
    const float eta_t = eta[b * 512 + t];
    float nsq = 0.f;
    for (int e = tid; e < 262144; e += 1024) {
      const int r = e >> 9, c = e & 511;
      const float m2 = fmaf(0.9f, mm[e], 0.1f * errs[r] * xs[c]);
      mm[e] = m2;
      const float f2 = fmaf(-eta_t, m2, fw[e]);
      fw[e] = f2;
      nsq = fmaf(f2, f2, nsq);
    }
    nsq = wave_red_sum64(nsq);
    if (lane == 0) red[wave] = nsq;
    __syncthreads();
    if (tid == 0) {
      float s = 0.f;
      for (int w = 0; w < 16; w++) s += red[w];
      red[0] = s;
    }
    __syncthreads();
    const float norm = fmaxf(sqrtf(red[0]), 1e-6f);
    const float sc = fminf(32.f / norm, 1.f);
    if (sc < 1.f)
      for (int e = tid; e < 262144; e += 1024) fw[e] *= sc;
  }
}

// ------------------------------ host launch ------------------------------
extern "C" void kernel_launch(void* const* d_in, const int* in_sizes, int n_in,
                              void* d_out, int out_size, void* d_ws, size_t ws_size,
                              hipStream_t stream) {
  (void)in_sizes; (void)n_in; (void)out_size;
  const float* x      = (const float*)d_in[0];
  const float* Wq     = (const float*)d_in[1];
  const float* Wk1    = (const float*)d_in[2];
  const float* Wk2    = (const float*)d_in[3];
  const float* Wv     = (const float*)d_in[4];
  const float* Wo     = (const float*)d_in[5];
  const float* lamlog = (const float*)d_in[6];
  const float* ln1g   = (const float*)d_in[7];
  const float* ln1b   = (const float*)d_in[8];
  const float* basew  = (const float*)d_in[9];
  const float* tttb   = (const float*)d_in[10];
  const float* loglr  = (const float*)d_in[11];
  const float* ln2g   = (const float*)d_in[12];
  const float* ln2b   = (const float*)d_in[13];
  const float* W1     = (const float*)d_in[14];
  const float* b1     = (const float*)d_in[15];
  const float* W2     = (const float*)d_in[16];
  const float* b2     = (const float*)d_in[17];
  const float* ln3g   = (const float*)d_in[18];
  const float* ln3b   = (const float*)d_in[19];
  float* out = (float*)d_out;

  char* ws = (char*)d_ws;
  size_t off = 0;
  auto alloc = [&](size_t bytes) {
    size_t o = off;
    off += (bytes + 255) & ~(size_t)255;
    return o;
  };
  f16* WqH   = (f16*)(ws + alloc(262144 * 2));
  f16* Wk1H  = (f16*)(ws + alloc(262144 * 2));
  f16* Wk2H  = (f16*)(ws + alloc(262144 * 2));
  f16* WvH   = (f16*)(ws + alloc(262144 * 2));
  f16* WoH   = (f16*)(ws + alloc(262144 * 2));
  f16* W1H   = (f16*)(ws + alloc(1048576 * 2));
  f16* W2H   = (f16*)(ws + alloc(1048576 * 2));
  (void)Wk1H; (void)Wk2H; (void)WvH; (void)W1H;
  f16* xlnH  = (f16*)(ws + alloc(524288 * 2));
  f16* qh    = (f16*)(ws + alloc(524288 * 2));
  f16* k1h   = (f16*)(ws + alloc(524288 * 2));
  f16* k2h   = (f16*)(ws + alloc(524288 * 2));
  f16* vTh   = (f16*)(ws + alloc(524288 * 2));
  (void)k2h;
  f16* obtd  = (f16*)(ws + alloc(524288 * 2));
  f16* x3h   = (f16*)(ws + alloc(524288 * 2));
  f16* zh    = (f16*)(ws + alloc(2097152 * 2));
  float* h1  = (float*)(ws + alloc(524288 * 4));
  float* x2  = (float*)(ws + alloc(524288 * 4));
  float* ysb = (float*)(ws + alloc(524288 * 4));  // ttt x-overread lands here (benign)
  float* h2  = (float*)(ws + alloc(524288 * 4));
  float* eta = (float*)(ws + alloc(1024 * 4));
  float* npB = (float*)(ws + alloc(512 * 4));
  float* nov = (float*)(ws + alloc(1024 * 4));
  int* flag  = (int*)(ws + alloc(256));
  // 16MB shared scratch: used SEQUENTIALLY by (1) QKV partials, (2) WO partials,
  // (3) TTT-phase aliases below, (4) GELU partials, (5) OUT partials.
  float* parts16 = (float*)(ws + alloc((size_t)16 * 1024 * 1024));
  float* yT    = parts16;                 // [2MB] ys transposed (TTT phase)
  float* nvd   = parts16 + 524288;        // [2MB] eta diffs
  float* fwfb  = parts16 + 1048576;       // [2MB] fallback fw scratch
  float* momfb = parts16 + 1572864;       // [2MB] fallback mom scratch

  int hc = 16;
  while (hc > 1 && off + (size_t)hc * (262144ull * 4 * 2 + 262144ull * 2) > ws_size) hc >>= 1;
  float* S1  = (float*)(ws + alloc((size_t)hc * 262144 * 4));  // S2 = S1 + hc*262144
  float* S2  = (float*)(ws + alloc((size_t)hc * 262144 * 4));
  f16* attnb = (f16*)(ws + alloc((size_t)hc * 262144 * 2));
  (void)S2;

  // ---- weight casts + LN1 in one launch ----
  cvt_all_kernel<<<3584, 256, 0, stream>>>(Wq, Wk1, Wk2, Wv, Wo, W1, W2, WqH,
                                           x, ln1g, ln1b, xlnH);

  // ---- q/k1/k2/vT: split-K x2 (256 blocks) + reduce/scatter ----
  gemm_bt<EPI_QKVPART><<<dim3(4, 8, 8), 256, 0, stream>>>(
      xlnH, WqH, 512, 512, 256, 262144, parts16, nullptr, nullptr, 256, 1.f, 0, 0);
  qkv_red_kernel<<<2048, 256, 0, stream>>>(parts16, qh);

  // ---- attention ----
  const int nc = 16 / hc;
  for (int c = 0; c < nc; c++) {
    const int cs = c * hc;
    gemm_bt<EPI_SCORES><<<dim3(4, 4, 2 * hc), 256, 0, stream>>>(
        qh + (long)cs * 32768, k1h + (long)cs * 32768, 64, 64, 0, 0, S1,
        nullptr, nullptr, 64, 0.125f, 0, hc);
    softmax_diff_kernel<<<hc * 128, 256, 0, stream>>>(S1, S2, lamlog, attnb, cs);
    gemm_bt<EPI_PV><<<dim3(1, 4, hc), 256, 0, stream>>>(
        attnb, vTh + (long)cs * 32768, 512, 512, 262144, 32768, obtd,
        nullptr, nullptr, 512, 1.f, cs, 0);
  }

  // ---- Wo projection (split-K x8, 256 blocks) + fused reduce+resid+LN2 ----
  gemm_bt<EPI_PART><<<dim3(4, 8, 8), 256, 0, stream>>>(
      obtd, WoH, 512, 512, 64, 64, parts16, nullptr, nullptr, 64, 1.f, 0, 0);
  red8ln_kernel<<<256, 256, 0, stream>>>(parts16, x, ln2g, ln2b, h1, x2);

  // ---- TTT (r11-proven cluster) ----
  eta_diff_kernel<<<16, 64, 0, stream>>>(x2, nvd);
  eta_nov_kernel<<<256, 256, 0, stream>>>(nvd, nov, flag);
  eta_scan_kernel<<<2, 64, 0, stream>>>(nov, loglr, eta);
  ttt_fast_kernel<<<512, 64, 0, stream>>>(x2, basew, tttb, eta, yT, npB);
  transpose2v_kernel<<<dim3(8, 8, 3), 256, 0, stream>>>(yT, ysb, npB, flag);
  ttt_fallback_kernel<<<2, 1024, 0, stream>>>(flag, x2, basew, tttb, eta, ysb, fwfb, momfb);

  // ---- h2 = h1 + ys ; LN3 -> x3 (fp16) ----
  ln_kernel<<<256, 256, 0, stream>>>(h1, ysb, ln3g, ln3b, h2, nullptr, x3h);

  // ---- FFN: GELU gemm split-K x2 (256 blocks) + red2gelu; W2 split-K x8 + red8 ----
  gemm_bt<EPI_GPART><<<dim3(16, 8, 2), 256, 0, stream>>>(
      x3h, W1H, 512, 512, 256, 256, parts16, nullptr, nullptr, 256, 1.f, 0, 0);
  red2gelu_kernel<<<2048, 256, 0, stream>>>(parts16, b1, zh);
  gemm_bt<EPI_PART><<<dim3(4, 8, 8), 256, 0, stream>>>(
      zh, W2H, 2048, 2048, 256, 256, parts16, nullptr, nullptr, 256, 1.f, 0, 0);
  red8_kernel<<<512, 256, 0, stream>>>(parts16, h2, b2, out);
}